// Round 7
// baseline (681.081 us; speedup 1.0000x reference)
//
#include <hip/hip_runtime.h>
#include <math.h>

#define NB 8
#define NC 64
#define NL 4096
#define NDI 128
#define NN 16
#define CHUNK 32
#define NKCH 128   // NL / CHUNK

// ---------------- workspace layout (float offsets) ----------------
#define OFF_FEATS 0ull          // 6291456 (dead after K2 -> reused by AC/BC/HINIT)
#define OFF_AC    0ull          // 2097152
#define OFF_BC    2097152ull    // 2097152
#define OFF_HINIT 4194304ull    // 2097152
#define OFF_XF    6291456ull    // 2097152 (dead after K3 -> reused by BMAT/CMAT)
#define OFF_BMAT  6291456ull    // 524288
#define OFF_CMAT  6815744ull    // 524288
#define OFF_X1    8388608ull    // 2097152 (live to the end)
#define OFF_XMRAW 10485760ull   // 4194304 (dead after K5 -> reused by G)
#define OFF_G     10485760ull   // 4194304
#define OFF_Z     14680064ull   // 4194304 (z dead after K9 -> low half reused by YC)
#define OFF_YC    14680064ull   // 2097152
#define OFF_PART  16777216ull   // 32768
#define OFF_STATS 16809984ull   // 1024
#define OFF_XMC   18874368ull   // 4194304
#define OFF_DTM   23068672ull   // 131072 (old DELTA region)
#define OFF_WF    27262976ull   // 55552 f32 weights
#define OFF_NSTAT (OFF_WF + 55552ull)   // 3072
#define OFF_WCOMB (OFF_WF + 58624ull)   // 8192 (cf_w @ op_w)
#define WS_NEED_FLOATS (OFF_WF + 66816ull)

// weight sub-offsets inside WF (floats)
#define WF_DW3    0
#define WF_DW5    576
#define WF_DW7    2176
#define WF_B3     5312
#define WF_B5     5376
#define WF_B7     5440
#define WF_FUSE   5504
#define WF_FUSEB  17792
#define WF_C2W    17856
#define WF_C2B    19008
#define WF_XPW    19136
#define WF_DTW    23744
#define WF_DTB    24256
#define WF_A      24384
#define WF_DP     26432
#define WF_ONW    26560
#define WF_ONB    26688
#define WF_OPW    26816
#define WF_CFW    35008
#define WF_CFB    39104
#define WF_INPJ   39168

// ---------------- K0: weights->f32 (A = -exp(A_log)); tail blocks compute W_comb ----------------
struct Cvt { const float* src; float* dst; int n; int op; };
struct CvtArgs { Cvt d[22]; int ncvt; const float* cfw; const float* opw; float* wcomb; };

__global__ __launch_bounds__(256) void k0_cvt(CvtArgs a){
  if ((int)blockIdx.x < a.ncvt){
    Cvt c = a.d[blockIdx.x];
    for (int i = threadIdx.x; i < c.n; i += 256){
      float v = c.src[i];
      c.dst[i] = c.op ? -expf(v) : v;
    }
  } else {
    int idx = (blockIdx.x - a.ncvt)*256 + threadIdx.x;   // 8192 outputs
    int c = idx >> 7, kk = idx & 127;
    float s = 0.f;
    #pragma unroll
    for (int j=0;j<64;j++) s += a.cfw[c*64+j] * a.opw[j*128+kk];
    a.wcomb[idx] = s;
  }
}

// ---------------- K1: 3 depthwise convs (3/5/7) raw + per-plane stats ----------------
__global__ __launch_bounds__(256) void k1_dw(const float* __restrict__ x, const float* __restrict__ wf,
                                             float* __restrict__ feats, float* __restrict__ nstat){
  const int b = blockIdx.x >> 6, c = blockIdx.x & 63;
  const int tid = threadIdx.x;
  __shared__ float xs[70*72];          // zero-padded (3 each side), row stride 72
  __shared__ float red[4][6];
  for (int i = tid; i < 70*72; i += 256) xs[i] = 0.f;
  __syncthreads();
  const float* xp = x + (size_t)blockIdx.x * NL;
  for (int i = tid; i < NL; i += 256){
    int h = i >> 6, w = i & 63;
    xs[(h+3)*72 + (w+3)] = xp[i];
  }
  float w3r[9], w5r[25], w7r[49];
  #pragma unroll
  for (int i=0;i<9;i++)  w3r[i] = wf[WF_DW3 + c*9 + i];
  #pragma unroll
  for (int i=0;i<25;i++) w5r[i] = wf[WF_DW5 + c*25 + i];
  #pragma unroll
  for (int i=0;i<49;i++) w7r[i] = wf[WF_DW7 + c*49 + i];
  float b3 = wf[WF_B3+c], b5 = wf[WF_B5+c], b7 = wf[WF_B7+c];
  __syncthreads();
  float s3=0,q3=0,s5=0,q5=0,s7=0,q7=0;
  float* f3 = feats + ((size_t)b*192 + c) * NL;
  float* f5 = f3 + (size_t)64*NL;
  float* f7 = f3 + (size_t)128*NL;
  #pragma unroll
  for (int g=0; g<4; g++){
    int p = g*1024 + tid*4;
    int h = p >> 6, w0 = p & 63;
    float a3[4], a5[4], a7[4];
    #pragma unroll
    for (int i=0;i<4;i++){ a3[i]=b3; a5[i]=b5; a7[i]=b7; }
    #pragma unroll
    for (int dy=0; dy<7; dy++){
      float s[10];
      #pragma unroll
      for (int j=0;j<10;j++) s[j] = xs[(h+dy)*72 + w0 + j];
      #pragma unroll
      for (int dx=0;dx<7;dx++){
        float wv = w7r[dy*7+dx];
        #pragma unroll
        for (int i=0;i<4;i++) a7[i] += s[dx+i]*wv;
      }
      if (dy>=1 && dy<=5){
        #pragma unroll
        for (int dx=0;dx<5;dx++){
          float wv = w5r[(dy-1)*5+dx];
          #pragma unroll
          for (int i=0;i<4;i++) a5[i] += s[dx+1+i]*wv;
        }
      }
      if (dy>=2 && dy<=4){
        #pragma unroll
        for (int dx=0;dx<3;dx++){
          float wv = w3r[(dy-2)*3+dx];
          #pragma unroll
          for (int i=0;i<4;i++) a3[i] += s[dx+2+i]*wv;
        }
      }
    }
    *(float4*)(f3+p) = make_float4(a3[0],a3[1],a3[2],a3[3]);
    *(float4*)(f5+p) = make_float4(a5[0],a5[1],a5[2],a5[3]);
    *(float4*)(f7+p) = make_float4(a7[0],a7[1],a7[2],a7[3]);
    #pragma unroll
    for (int i=0;i<4;i++){
      s3+=a3[i]; q3+=a3[i]*a3[i];
      s5+=a5[i]; q5+=a5[i]*a5[i];
      s7+=a7[i]; q7+=a7[i]*a7[i];
    }
  }
  int wid = tid>>6, lane = tid&63;
  float v6[6]={s3,q3,s5,q5,s7,q7};
  #pragma unroll
  for (int j=0;j<6;j++){
    float t = v6[j];
    #pragma unroll
    for (int o=32;o>0;o>>=1) t += __shfl_down(t,o);
    if (!lane) red[wid][j]=t;
  }
  __syncthreads();
  if (tid < 3){
    float su = red[0][tid*2]+red[1][tid*2]+red[2][tid*2]+red[3][tid*2];
    float sq = red[0][tid*2+1]+red[1][tid*2+1]+red[2][tid*2+1]+red[3][tid*2+1];
    float m  = su*(1.f/NL);
    float va = sq*(1.f/NL) - m*m;
    int k = b*192 + tid*64 + c;
    nstat[k*2]   = m;
    nstat[k*2+1] = rsqrtf(va + 1e-5f);
  }
}

// ---------------- K2: fuse 1x1 (192->64). 8og x 8b x 32pt = 2048 blocks; 128px tiles ----------------
__global__ __launch_bounds__(256) void k2_fuse(const float* __restrict__ feats, const float* __restrict__ nstat,
                                               const float* __restrict__ wf, float* __restrict__ xf){
  int og = blockIdx.x >> 8, rem = blockIdx.x & 255;
  int b = rem >> 5, pt = rem & 31;
  int px = threadIdx.x & 127, jh = threadIdx.x >> 7;
  __shared__ float wlds[8*192];     // 6 KB
  __shared__ float xs[32*128];      // 16 KB (normalized+lrelu'd chunk)
  __shared__ float msl[192], rsl[192];
  for (int i = threadIdx.x; i < 192; i += 256){
    msl[i] = nstat[(b*192+i)*2];
    rsl[i] = nstat[(b*192+i)*2+1];
  }
  {
    const float4* Wg = (const float4*)(wf + WF_FUSE + og*8*192);
    float4* Wl = (float4*)wlds;
    for (int i = threadIdx.x; i < 384; i += 256) Wl[i] = Wg[i];
  }
  float acc[4] = {0.f,0.f,0.f,0.f};
  const float* fbase = feats + (size_t)b*192*NL + pt*128;
  for (int ch = 0; ch < 6; ch++){
    __syncthreads();
    for (int i = threadIdx.x; i < 1024; i += 256){
      int r = i >> 5, c4 = i & 31;
      int k = ch*32 + r;
      float4 f = *(const float4*)(fbase + (size_t)k*NL + c4*4);
      float m = msl[k], rs = rsl[k];
      float v0=(f.x-m)*rs, v1=(f.y-m)*rs, v2=(f.z-m)*rs, v3=(f.w-m)*rs;
      v0 = v0>0.f?v0:0.01f*v0; v1 = v1>0.f?v1:0.01f*v1;
      v2 = v2>0.f?v2:0.01f*v2; v3 = v3>0.f?v3:0.01f*v3;
      ((float4*)xs)[r*32 + c4] = make_float4(v0,v1,v2,v3);
    }
    __syncthreads();
    #pragma unroll
    for (int c = 0; c < 32; c++){
      float a = xs[c*128 + px];
      #pragma unroll
      for (int j=0;j<4;j++) acc[j] += wlds[(jh*4+j)*192 + ch*32 + c]*a;
    }
  }
  #pragma unroll
  for (int j=0;j<4;j++){
    int o = og*8 + jh*4 + j;
    float* dp = xf + (size_t)b*64*NL + (size_t)o*NL + pt*128;
    dp[px] = acc[j] + wf[WF_FUSEB + o];
  }
}

// ---------------- K3: inorm(xf)+lrelu + x -> x1 ----------------
__global__ __launch_bounds__(256) void k3_norm(const float* __restrict__ xf, const float* __restrict__ x,
                                               float* __restrict__ x1){
  const int tid = threadIdx.x;
  const size_t base = (size_t)blockIdx.x * NL;
  float loc[16]; float s=0.f, q=0.f;
  #pragma unroll
  for (int i=0;i<16;i++){ float v = xf[base + tid + i*256]; loc[i]=v; s+=v; q+=v*v; }
  __shared__ float red[4][2];
  int wid = tid>>6, lane = tid&63;
  #pragma unroll
  for (int o=32;o>0;o>>=1){ s += __shfl_down(s,o); q += __shfl_down(q,o); }
  if (!lane){ red[wid][0]=s; red[wid][1]=q; }
  __syncthreads();
  s = red[0][0]+red[1][0]+red[2][0]+red[3][0];
  q = red[0][1]+red[1][1]+red[2][1]+red[3][1];
  float m = s*(1.f/NL), va = q*(1.f/NL)-m*m, rs = rsqrtf(va+1e-5f);
  #pragma unroll
  for (int i=0;i<16;i++){
    int idx = tid + i*256;
    float v = (loc[i]-m)*rs;
    v = v>0.f ? v : 0.01f*v;
    x1[base+idx] = v + x[base+idx];
  }
}

// ---------------- K4: in_proj (64->256). 16og x 8b x 32pt = 4096 blocks; 128px tiles ----------------
__global__ __launch_bounds__(256) void k4_inproj(const float* __restrict__ x1, const float* __restrict__ wf,
                                                 float* __restrict__ xmraw, float* __restrict__ z){
  int og = blockIdx.x >> 8, rem = blockIdx.x & 255;
  int b = rem >> 5, pt = rem & 31;
  int px = threadIdx.x & 127, jh = threadIdx.x >> 7;
  __shared__ float wlds[16*64];     // 4 KB
  __shared__ float xs[32*128];      // 16 KB
  {
    const float4* Wg = (const float4*)(wf + WF_INPJ + og*16*64);
    float4* Wl = (float4*)wlds;
    if (threadIdx.x < 256) Wl[threadIdx.x] = Wg[threadIdx.x];
  }
  float acc[8];
  #pragma unroll
  for (int j=0;j<8;j++) acc[j]=0.f;
  const float* xbase = x1 + (size_t)b*64*NL + pt*128;
  for (int ch = 0; ch < 2; ch++){
    __syncthreads();
    for (int i = threadIdx.x; i < 1024; i += 256){
      int r = i >> 5, c4 = i & 31;
      ((float4*)xs)[r*32 + c4] = *(const float4*)(xbase + (size_t)(ch*32+r)*NL + c4*4);
    }
    __syncthreads();
    #pragma unroll
    for (int c = 0; c < 32; c++){
      float a = xs[c*128 + px];
      #pragma unroll
      for (int j=0;j<8;j++) acc[j] += wlds[(jh*8+j)*64 + ch*32 + c]*a;
    }
  }
  #pragma unroll
  for (int j=0;j<8;j++){
    int o = og*16 + jh*8 + j;
    float* dp = (o < 128 ? xmraw + ((size_t)b*128 + o)*NL
                         : z     + ((size_t)b*128 + (o-128))*NL) + pt*128;
    dp[px] = acc[j];
  }
}

// ---------------- K5: depthwise 3x3 + silu ----------------
__global__ __launch_bounds__(256) void k5_dw3(const float* __restrict__ xmraw, const float* __restrict__ wf,
                                              float* __restrict__ xmc){
  const int d = blockIdx.x & 127;
  const int tid = threadIdx.x;
  __shared__ float xs[66*68];
  for (int i=tid;i<66*68;i+=256) xs[i]=0.f;
  __syncthreads();
  const float* xp = xmraw + (size_t)blockIdx.x * NL;
  for (int i=tid;i<NL;i+=256){ int h=i>>6, w=i&63; xs[(h+1)*68 + (w+1)] = xp[i]; }
  float wr[9];
  #pragma unroll
  for (int i=0;i<9;i++) wr[i] = wf[WF_C2W + d*9 + i];
  float bb = wf[WF_C2B + d];
  __syncthreads();
  float* op = xmc + (size_t)blockIdx.x * NL;
  #pragma unroll
  for (int g=0; g<4; g++){
    int p = g*1024 + tid*4;
    int h = p>>6, w0 = p&63;
    float a[4];
    #pragma unroll
    for (int i=0;i<4;i++) a[i]=bb;
    #pragma unroll
    for (int dy=0; dy<3; dy++){
      float s[6];
      #pragma unroll
      for (int j=0;j<6;j++) s[j] = xs[(h+dy)*68 + w0 + j];
      #pragma unroll
      for (int dx=0;dx<3;dx++){
        float wv = wr[dy*3+dx];
        #pragma unroll
        for (int i=0;i<4;i++) a[i] += s[dx+i]*wv;
      }
    }
    float4 o;
    o.x = a[0]/(1.f+__expf(-a[0]));
    o.y = a[1]/(1.f+__expf(-a[1]));
    o.z = a[2]/(1.f+__expf(-a[2]));
    o.w = a[3]/(1.f+__expf(-a[3]));
    *(float4*)(op+p) = o;
  }
}

// ---------------- K6 (slim): x_proj (128->36): dt(4)+B(16)+C(16). 6og x 8b x 32pt = 1536 blocks ----------------
__global__ __launch_bounds__(256) void k6_xproj(const float* __restrict__ xmc, const float* __restrict__ wf,
                                                float* __restrict__ Bm, float* __restrict__ Cm,
                                                float* __restrict__ dtm){
  int og = blockIdx.x >> 8, rem = blockIdx.x & 255;
  int b = rem >> 5, pt = rem & 31;
  int px = threadIdx.x & 127, jh = threadIdx.x >> 7;
  __shared__ float wlds[6*128];     // 3 KB
  __shared__ float xs[32*128];      // 16 KB
  {
    const float4* Wg = (const float4*)(wf + WF_XPW + og*6*128);
    float4* Wl = (float4*)wlds;
    if (threadIdx.x < 192) Wl[threadIdx.x] = Wg[threadIdx.x];
  }
  float acc[3] = {0.f,0.f,0.f};
  const float* ubase = xmc + (size_t)b*128*NL + pt*128;
  for (int ch = 0; ch < 4; ch++){
    __syncthreads();
    for (int i = threadIdx.x; i < 1024; i += 256){
      int r = i >> 5, c4 = i & 31;
      ((float4*)xs)[r*32 + c4] = *(const float4*)(ubase + (size_t)(ch*32+r)*NL + c4*4);
    }
    __syncthreads();
    #pragma unroll
    for (int c = 0; c < 32; c++){
      float a = xs[c*128 + px];
      #pragma unroll
      for (int j=0;j<3;j++) acc[j] += wlds[(jh*3+j)*128 + ch*32 + c]*a;
    }
  }
  #pragma unroll
  for (int j=0;j<3;j++){
    int o = og*6 + jh*3 + j;
    float* dp;
    if (o < 4)       dp = dtm + ((size_t)b*16 + o)*NL/4;      // dtm is (B,4,L): ((b*4+o)*NL)
    else if (o < 20) dp = Bm  + ((size_t)b*16 + (o-4))*NL;
    else             dp = Cm  + ((size_t)b*16 + (o-20))*NL;
    if (o < 4) dp = dtm + ((size_t)b*4 + o)*NL;               // (overrides; keep simple & correct)
    dp[pt*128 + px] = acc[j];
  }
}

// ---------------- K7: scan pass1 — stage u/B/dt in LDS, delta on the fly ----------------
__global__ __launch_bounds__(128) void k7_scan1(const float* __restrict__ xmc, const float* __restrict__ Bm,
                                                const float* __restrict__ dtm, const float* __restrict__ wf,
                                                float* __restrict__ Ac, float* __restrict__ Bc){
  int k = blockIdx.x & (NKCH-1), b = blockIdx.x >> 7;
  int d = threadIdx.x;
  int l0 = k*CHUNK;
  __shared__ float xs[128*33];      // u, padded
  __shared__ float Bl[16*32];
  __shared__ float dtl[4*32];
  for (int i = d; i < 4096; i += 128){
    int ch = i >> 5, px = i & 31;
    xs[ch*33+px] = xmc[((size_t)b*128+ch)*NL + l0 + px];
  }
  for (int i = d; i < 512; i += 128){
    int n = i >> 5, li = i & 31;
    Bl[i] = Bm[((size_t)b*16+n)*NL + l0 + li];
  }
  if (d < 128){
    int n = d >> 5, li = d & 31;
    dtl[d] = dtm[((size_t)b*4+n)*NL + l0 + li];
  }
  float A[16], P[16], Q[16];
  const float* Af = wf + WF_A + d*16;
  #pragma unroll
  for (int n=0;n<16;n++){ A[n]=Af[n]; P[n]=1.f; Q[n]=0.f; }
  float w0 = wf[WF_DTW+d*4], w1 = wf[WF_DTW+d*4+1], w2 = wf[WF_DTW+d*4+2], w3 = wf[WF_DTW+d*4+3];
  float db2 = 2.f*wf[WF_DTB+d];
  __syncthreads();
  for (int l=0; l<CHUNK; l++){
    float tt = w0*dtl[l] + w1*dtl[32+l] + w2*dtl[64+l] + w3*dtl[96+l] + db2;
    float de = tt > 20.f ? tt : __logf(1.f+__expf(tt));   // softplus (double bias, faithful)
    float du = de * xs[d*33+l];
    #pragma unroll
    for (int n=0;n<16;n++){
      float a = __expf(de*A[n]);
      P[n] *= a;
      Q[n] = a*Q[n] + du*Bl[n*32+l];
    }
  }
  size_t base = (((size_t)k*NB + b)*128 + d)*16;
  #pragma unroll
  for (int i=0;i<4;i++){
    ((float4*)(Ac+base))[i] = make_float4(P[i*4],P[i*4+1],P[i*4+2],P[i*4+3]);
    ((float4*)(Bc+base))[i] = make_float4(Q[i*4],Q[i*4+1],Q[i*4+2],Q[i*4+3]);
  }
}

// ---------------- K8: middle scan over chunk aggregates; unroll 16 for load ILP ----------------
__global__ __launch_bounds__(256) void k8_mid(const float* __restrict__ Ac, const float* __restrict__ Bc,
                                              float* __restrict__ Hi){
  int idx = blockIdx.x*256 + threadIdx.x;   // (b*128+d)*16+n, 16384 total
  float h = 0.f;
  for (int k0=0;k0<NKCH;k0+=16){
    float av[16], bv[16];
    #pragma unroll
    for (int j=0;j<16;j++){
      size_t o = (size_t)(k0+j)*16384 + idx;
      av[j]=Ac[o]; bv[j]=Bc[o];
    }
    #pragma unroll
    for (int j=0;j<16;j++){
      size_t o = (size_t)(k0+j)*16384 + idx;
      Hi[o] = h;
      h = av[j]*h + bv[j];
    }
  }
}

// ---------------- K9: scan pass2 + fused LN*silu(z) gate -> G ----------------
__global__ __launch_bounds__(128) void k9_scan2(const float* __restrict__ xmc, const float* __restrict__ Bm,
                                                const float* __restrict__ Cm, const float* __restrict__ dtm,
                                                const float* __restrict__ z, const float* __restrict__ wf,
                                                const float* __restrict__ Hi, float* __restrict__ G){
  int k = blockIdx.x & (NKCH-1), b = blockIdx.x >> 7;
  int d = threadIdx.x;
  int l0 = k*CHUNK;
  __shared__ float xs[128*33];      // u, then y in place
  __shared__ float Bl[16*32], Cl[16*32];
  __shared__ float dtl[4*32];
  __shared__ float red[4][32][2];
  __shared__ float mstat[32], rstat[32];
  for (int i = d; i < 4096; i += 128){
    int ch = i >> 5, px = i & 31;
    xs[ch*33+px] = xmc[((size_t)b*128+ch)*NL + l0 + px];
  }
  for (int i = d; i < 512; i += 128){
    int n = i >> 5, li = i & 31;
    Bl[i] = Bm[((size_t)b*16+n)*NL + l0 + li];
    Cl[i] = Cm[((size_t)b*16+n)*NL + l0 + li];
  }
  if (d < 128){
    int n = d >> 5, li = d & 31;
    dtl[d] = dtm[((size_t)b*4+n)*NL + l0 + li];
  }
  float A[16], h[16];
  const float* Af = wf + WF_A + d*16;
  size_t hb = (((size_t)k*NB + b)*128 + d)*16;
  #pragma unroll
  for (int n=0;n<16;n++){ A[n]=Af[n]; h[n]=Hi[hb+n]; }
  float Dv = wf[WF_DP + d];
  float w0 = wf[WF_DTW+d*4], w1 = wf[WF_DTW+d*4+1], w2 = wf[WF_DTW+d*4+2], w3 = wf[WF_DTW+d*4+3];
  float db2 = 2.f*wf[WF_DTB+d];
  __syncthreads();
  for (int l=0; l<CHUNK; l++){
    float tt = w0*dtl[l] + w1*dtl[32+l] + w2*dtl[64+l] + w3*dtl[96+l] + db2;
    float de = tt > 20.f ? tt : __logf(1.f+__expf(tt));
    float uu = xs[d*33+l];
    float du = de * uu;
    float yv = uu * Dv;
    #pragma unroll
    for (int n=0;n<16;n++){
      float a = __expf(de*A[n]);
      h[n] = a*h[n] + du*Bl[n*32+l];
      yv  += h[n]*Cl[n*32+l];
    }
    xs[d*33+l] = yv;    // y overwrites u (row d private to this thread)
  }
  __syncthreads();
  // LayerNorm over d (128) per pixel l
  {
    int px = d & 31, q = d >> 5;
    float s=0.f, qq=0.f;
    #pragma unroll
    for (int j=0;j<32;j++){ float v = xs[(q*32+j)*33+px]; s+=v; qq+=v*v; }
    red[q][px][0]=s; red[q][px][1]=qq;
  }
  __syncthreads();
  if (d < 32){
    float ss = red[0][d][0]+red[1][d][0]+red[2][d][0]+red[3][d][0];
    float sq = red[0][d][1]+red[1][d][1]+red[2][d][1]+red[3][d][1];
    float m = ss*(1.f/128.f);
    mstat[d] = m;
    rstat[d] = rsqrtf(sq*(1.f/128.f) - m*m + 1e-5f);
  }
  __syncthreads();
  float ow = wf[WF_ONW+d], ob = wf[WF_ONB+d];
  const float* zp = z + ((size_t)b*128+d)*NL + l0;
  float* gp = G + ((size_t)b*128+d)*NL + l0;
  #pragma unroll
  for (int l4=0; l4<CHUNK/4; l4++){
    float4 zv4 = ((const float4*)zp)[l4];
    float zv[4] = {zv4.x, zv4.y, zv4.z, zv4.w};
    float out[4];
    #pragma unroll
    for (int j=0;j<4;j++){
      int l = l4*4+j;
      float t = (xs[d*33+l]-mstat[l])*rstat[l]*ow + ob;
      out[j] = t * (zv[j]/(1.f+__expf(-zv[j])));
    }
    ((float4*)gp)[l4] = make_float4(out[0],out[1],out[2],out[3]);
  }
}

// ---------------- K11A: yc = W_comb @ G + cf_b. 8og x 8b x 32pt = 2048; + partial stats ----------------
__global__ __launch_bounds__(256) void k11A_proj(const float* __restrict__ G, const float* __restrict__ wf,
                                                 const float* __restrict__ wcomb,
                                                 float* __restrict__ yc, float* __restrict__ part){
  int og = blockIdx.x >> 8, rem = blockIdx.x & 255;
  int b = rem >> 5, pt = rem & 31;
  int px = threadIdx.x & 127, jh = threadIdx.x >> 7;
  __shared__ float wlds[8*128];     // 4 KB
  __shared__ float xs[32*128];      // 16 KB
  __shared__ float red[4][4][2];
  {
    const float4* Wg = (const float4*)(wcomb + og*8*128);
    float4* Wl = (float4*)wlds;
    if (threadIdx.x < 256) Wl[threadIdx.x] = Wg[threadIdx.x];
  }
  float acc[4] = {0.f,0.f,0.f,0.f};
  const float* gbase = G + (size_t)b*128*NL + pt*128;
  for (int ch = 0; ch < 4; ch++){
    __syncthreads();
    for (int i = threadIdx.x; i < 1024; i += 256){
      int r = i >> 5, c4 = i & 31;
      ((float4*)xs)[r*32 + c4] = *(const float4*)(gbase + (size_t)(ch*32+r)*NL + c4*4);
    }
    __syncthreads();
    #pragma unroll
    for (int c = 0; c < 32; c++){
      float a = xs[c*128 + px];
      #pragma unroll
      for (int j=0;j<4;j++) acc[j] += wlds[(jh*4+j)*128 + ch*32 + c]*a;
    }
  }
  int wid = threadIdx.x >> 6, lane = threadIdx.x & 63;
  #pragma unroll
  for (int j=0;j<4;j++){
    int cc = og*8 + jh*4 + j;
    float t = acc[j] + wf[WF_CFB + cc];
    float* dp = yc + (size_t)b*64*NL + (size_t)cc*NL + pt*128;
    dp[px] = t;
    float sv = t, qv = t*t;
    #pragma unroll
    for (int o=32;o>0;o>>=1){ sv += __shfl_down(sv,o); qv += __shfl_down(qv,o); }
    if (!lane){ red[wid][j][0]=sv; red[wid][j][1]=qv; }
  }
  __syncthreads();
  if (threadIdx.x < 8){
    int j = threadIdx.x & 3, grp = threadIdx.x >> 2;   // grp: 0 -> waves 0,1 (jh=0); 1 -> waves 2,3 (jh=1)
    float sv = red[grp*2][j][0] + red[grp*2+1][j][0];
    float qv = red[grp*2][j][1] + red[grp*2+1][j][1];
    int cc = og*8 + grp*4 + j;
    size_t pidx = (((size_t)b*64 + cc)*32 + pt)*2;
    part[pidx] = sv; part[pidx+1] = qv;
  }
}

// ---------------- K11b: finalize per-(b,c) mean/rsqrt (32 partials each) ----------------
__global__ __launch_bounds__(256) void k11b_stats(const float* __restrict__ part, float* __restrict__ stats){
  int i = blockIdx.x*256 + threadIdx.x;
  if (i >= 512) return;
  float s=0.f, q=0.f;
  #pragma unroll
  for (int t2=0;t2<32;t2++){ s += part[((size_t)i*32+t2)*2]; q += part[((size_t)i*32+t2)*2+1]; }
  float m = s*(1.f/NL), va = q*(1.f/NL) - m*m;
  stats[i*2] = m; stats[i*2+1] = rsqrtf(va+1e-5f);
}

// ---------------- K11c: out = x1 + inorm(yc), write f32 ----------------
__global__ __launch_bounds__(256) void k11c_final(const float* __restrict__ yc, const float* __restrict__ stats,
                                                  const float* __restrict__ x1, float* __restrict__ out){
  int bc = blockIdx.x;
  float m = stats[bc*2], rs = stats[bc*2+1];
  size_t base = (size_t)bc*NL;
  for (int i=threadIdx.x;i<NL;i+=256){
    float v = (yc[base+i]-m)*rs;
    out[base+i] = x1[base+i] + v;
  }
}

// ---------------- host ----------------
extern "C" void kernel_launch(void* const* d_in, const int* in_sizes, int n_in,
                              void* d_out, int out_size, void* d_ws, size_t ws_size,
                              hipStream_t stream) {
  if (ws_size < WS_NEED_FLOATS * sizeof(float)) return;  // insufficient scratch; bail cleanly
  const float* x     = (const float*)d_in[0];
  const float* dw3w  = (const float*)d_in[1];
  const float* dw3b  = (const float*)d_in[2];
  const float* dw5w  = (const float*)d_in[3];
  const float* dw5b  = (const float*)d_in[4];
  const float* dw7w  = (const float*)d_in[5];
  const float* dw7b  = (const float*)d_in[6];
  const float* fusew = (const float*)d_in[7];
  const float* fuseb = (const float*)d_in[8];
  const float* inpjw = (const float*)d_in[9];
  const float* c2w   = (const float*)d_in[10];
  const float* c2b   = (const float*)d_in[11];
  const float* xpw   = (const float*)d_in[12];
  const float* dtw   = (const float*)d_in[13];
  const float* dtb   = (const float*)d_in[14];
  const float* alog  = (const float*)d_in[15];
  const float* dpv   = (const float*)d_in[16];
  const float* onw   = (const float*)d_in[17];
  const float* onb   = (const float*)d_in[18];
  const float* opw   = (const float*)d_in[19];
  const float* cfw   = (const float*)d_in[20];
  const float* cfb   = (const float*)d_in[21];

  float* ws    = (float*)d_ws;
  float* wf    = ws + OFF_WF;
  float* wcomb = ws + OFF_WCOMB;
  float* feats = ws + OFF_FEATS;
  float* nstat = ws + OFF_NSTAT;
  float* xf    = ws + OFF_XF;
  float* x1    = ws + OFF_X1;
  float* xmraw = ws + OFF_XMRAW;
  float* z     = ws + OFF_Z;
  float* xmc   = ws + OFF_XMC;
  float* Bmw   = ws + OFF_BMAT;
  float* Cmw   = ws + OFF_CMAT;
  float* dtm   = ws + OFF_DTM;
  float* Acb   = ws + OFF_AC;
  float* Bcb   = ws + OFF_BC;
  float* Hi    = ws + OFF_HINIT;
  float* G     = ws + OFF_G;
  float* yc    = ws + OFF_YC;
  float* part  = ws + OFF_PART;
  float* stats = ws + OFF_STATS;

  CvtArgs ca; int ns = 0;
  auto add = [&](const float* s, int off, int n, int op){
    ca.d[ns].src = s; ca.d[ns].dst = wf + off; ca.d[ns].n = n; ca.d[ns].op = op; ns++;
  };
  add(dw3w, WF_DW3, 576, 0);   add(dw5w, WF_DW5, 1600, 0);  add(dw7w, WF_DW7, 3136, 0);
  add(dw3b, WF_B3, 64, 0);     add(dw5b, WF_B5, 64, 0);     add(dw7b, WF_B7, 64, 0);
  add(fusew, WF_FUSE, 12288, 0); add(fuseb, WF_FUSEB, 64, 0);
  add(c2w, WF_C2W, 1152, 0);   add(c2b, WF_C2B, 128, 0);
  add(xpw, WF_XPW, 4608, 0);   add(dtw, WF_DTW, 512, 0);    add(dtb, WF_DTB, 128, 0);
  add(alog, WF_A, 2048, 1);    // A = -exp(A_log)
  add(dpv, WF_DP, 128, 0);
  add(onw, WF_ONW, 128, 0);    add(onb, WF_ONB, 128, 0);
  add(opw, WF_OPW, 8192, 0);
  add(cfw, WF_CFW, 4096, 0);   add(cfb, WF_CFB, 64, 0);
  add(inpjw, WF_INPJ, 16384, 0);
  ca.ncvt = ns; ca.cfw = cfw; ca.opw = opw; ca.wcomb = wcomb;

  k0_cvt<<<ns + 32, 256, 0, stream>>>(ca);
  k1_dw<<<512, 256, 0, stream>>>(x, wf, feats, nstat);
  k2_fuse<<<2048, 256, 0, stream>>>(feats, nstat, wf, xf);
  k3_norm<<<512, 256, 0, stream>>>(xf, x, x1);
  k4_inproj<<<4096, 256, 0, stream>>>(x1, wf, xmraw, z);
  k5_dw3<<<1024, 256, 0, stream>>>(xmraw, wf, xmc);
  k6_xproj<<<1536, 256, 0, stream>>>(xmc, wf, Bmw, Cmw, dtm);
  k7_scan1<<<1024, 128, 0, stream>>>(xmc, Bmw, dtm, wf, Acb, Bcb);
  k8_mid<<<64, 256, 0, stream>>>(Acb, Bcb, Hi);
  k9_scan2<<<1024, 128, 0, stream>>>(xmc, Bmw, Cmw, dtm, z, wf, Hi, G);
  k11A_proj<<<2048, 256, 0, stream>>>(G, wf, wcomb, yc, part);
  k11b_stats<<<2, 256, 0, stream>>>(part, stats);
  k11c_final<<<512, 256, 0, stream>>>(yc, stats, x1, (float*)d_out);
}

// Round 8
// 470.277 us; speedup vs baseline: 1.4483x; 1.4483x over previous
//
#include <hip/hip_runtime.h>
#include <math.h>

#define NB 8
#define NC 64
#define NL 4096
#define NDI 128
#define NN 16
#define CHUNK 32
#define NKCH 128   // NL / CHUNK

// ---------------- workspace layout (float offsets) ----------------
#define OFF_FEATS 0ull          // 6291456 (dead after K2 -> reused by AC/BC/HINIT)
#define OFF_AC    0ull          // 2097152
#define OFF_BC    2097152ull    // 2097152
#define OFF_HINIT 4194304ull    // 2097152
#define OFF_XF    6291456ull    // 2097152 (dead after K3 -> reused by BMAT/CMAT)
#define OFF_BMAT  6291456ull    // 524288
#define OFF_CMAT  6815744ull    // 524288
#define OFF_X1    8388608ull    // 2097152 (live to the end)
#define OFF_XMRAW 10485760ull   // 4194304 (dead after K5 -> reused by G)
#define OFF_G     10485760ull   // 4194304
#define OFF_Z     14680064ull   // 4194304 (z dead after K9 -> low half reused by YC)
#define OFF_YC    14680064ull   // 2097152
#define OFF_PART  16777216ull   // 16384
#define OFF_STATS 16809984ull   // 1024
#define OFF_XMC   18874368ull   // 4194304
#define OFF_DTM   23068672ull   // 131072
#define OFF_WF    27262976ull   // 55552 f32 weights
#define OFF_NSTAT (OFF_WF + 55552ull)   // 3072
#define OFF_WCOMB (OFF_WF + 58624ull)   // 8192 (cf_w @ op_w)
#define WS_NEED_FLOATS (OFF_WF + 66816ull)

// weight sub-offsets inside WF (floats)
#define WF_DW3    0
#define WF_DW5    576
#define WF_DW7    2176
#define WF_B3     5312
#define WF_B5     5376
#define WF_B7     5440
#define WF_FUSE   5504
#define WF_FUSEB  17792
#define WF_C2W    17856
#define WF_C2B    19008
#define WF_XPW    19136
#define WF_DTW    23744
#define WF_DTB    24256
#define WF_A      24384
#define WF_DP     26432
#define WF_ONW    26560
#define WF_ONB    26688
#define WF_OPW    26816
#define WF_CFW    35008
#define WF_CFB    39104
#define WF_INPJ   39168

// ---------------- K0: weights->f32 (A = -exp(A_log)); tail blocks compute W_comb ----------------
struct Cvt { const float* src; float* dst; int n; int op; };
struct CvtArgs { Cvt d[22]; int ncvt; const float* cfw; const float* opw; float* wcomb; };

__global__ __launch_bounds__(256) void k0_cvt(CvtArgs a){
  if ((int)blockIdx.x < a.ncvt){
    Cvt c = a.d[blockIdx.x];
    for (int i = threadIdx.x; i < c.n; i += 256){
      float v = c.src[i];
      c.dst[i] = c.op ? -expf(v) : v;
    }
  } else {
    int idx = (blockIdx.x - a.ncvt)*256 + threadIdx.x;   // 8192 outputs
    int c = idx >> 7, kk = idx & 127;
    float s = 0.f;
    #pragma unroll
    for (int j=0;j<64;j++) s += a.cfw[c*64+j] * a.opw[j*128+kk];
    a.wcomb[idx] = s;
  }
}

// ---------------- K1: 3 depthwise convs (3/5/7) raw + per-plane stats ----------------
__global__ __launch_bounds__(256) void k1_dw(const float* __restrict__ x, const float* __restrict__ wf,
                                             float* __restrict__ feats, float* __restrict__ nstat){
  const int b = blockIdx.x >> 6, c = blockIdx.x & 63;
  const int tid = threadIdx.x;
  __shared__ float xs[70*72];          // zero-padded (3 each side), row stride 72
  __shared__ float red[4][6];
  for (int i = tid; i < 70*72; i += 256) xs[i] = 0.f;
  __syncthreads();
  const float* xp = x + (size_t)blockIdx.x * NL;
  for (int i = tid; i < NL; i += 256){
    int h = i >> 6, w = i & 63;
    xs[(h+3)*72 + (w+3)] = xp[i];
  }
  float w3r[9], w5r[25], w7r[49];
  #pragma unroll
  for (int i=0;i<9;i++)  w3r[i] = wf[WF_DW3 + c*9 + i];
  #pragma unroll
  for (int i=0;i<25;i++) w5r[i] = wf[WF_DW5 + c*25 + i];
  #pragma unroll
  for (int i=0;i<49;i++) w7r[i] = wf[WF_DW7 + c*49 + i];
  float b3 = wf[WF_B3+c], b5 = wf[WF_B5+c], b7 = wf[WF_B7+c];
  __syncthreads();
  float s3=0,q3=0,s5=0,q5=0,s7=0,q7=0;
  float* f3 = feats + ((size_t)b*192 + c) * NL;
  float* f5 = f3 + (size_t)64*NL;
  float* f7 = f3 + (size_t)128*NL;
  #pragma unroll
  for (int g=0; g<4; g++){
    int p = g*1024 + tid*4;
    int h = p >> 6, w0 = p & 63;
    float a3[4], a5[4], a7[4];
    #pragma unroll
    for (int i=0;i<4;i++){ a3[i]=b3; a5[i]=b5; a7[i]=b7; }
    #pragma unroll
    for (int dy=0; dy<7; dy++){
      float s[10];
      #pragma unroll
      for (int j=0;j<10;j++) s[j] = xs[(h+dy)*72 + w0 + j];
      #pragma unroll
      for (int dx=0;dx<7;dx++){
        float wv = w7r[dy*7+dx];
        #pragma unroll
        for (int i=0;i<4;i++) a7[i] += s[dx+i]*wv;
      }
      if (dy>=1 && dy<=5){
        #pragma unroll
        for (int dx=0;dx<5;dx++){
          float wv = w5r[(dy-1)*5+dx];
          #pragma unroll
          for (int i=0;i<4;i++) a5[i] += s[dx+1+i]*wv;
        }
      }
      if (dy>=2 && dy<=4){
        #pragma unroll
        for (int dx=0;dx<3;dx++){
          float wv = w3r[(dy-2)*3+dx];
          #pragma unroll
          for (int i=0;i<4;i++) a3[i] += s[dx+2+i]*wv;
        }
      }
    }
    *(float4*)(f3+p) = make_float4(a3[0],a3[1],a3[2],a3[3]);
    *(float4*)(f5+p) = make_float4(a5[0],a5[1],a5[2],a5[3]);
    *(float4*)(f7+p) = make_float4(a7[0],a7[1],a7[2],a7[3]);
    #pragma unroll
    for (int i=0;i<4;i++){
      s3+=a3[i]; q3+=a3[i]*a3[i];
      s5+=a5[i]; q5+=a5[i]*a5[i];
      s7+=a7[i]; q7+=a7[i]*a7[i];
    }
  }
  int wid = tid>>6, lane = tid&63;
  float v6[6]={s3,q3,s5,q5,s7,q7};
  #pragma unroll
  for (int j=0;j<6;j++){
    float t = v6[j];
    #pragma unroll
    for (int o=32;o>0;o>>=1) t += __shfl_down(t,o);
    if (!lane) red[wid][j]=t;
  }
  __syncthreads();
  if (tid < 3){
    float su = red[0][tid*2]+red[1][tid*2]+red[2][tid*2]+red[3][tid*2];
    float sq = red[0][tid*2+1]+red[1][tid*2+1]+red[2][tid*2+1]+red[3][tid*2+1];
    float m  = su*(1.f/NL);
    float va = sq*(1.f/NL) - m*m;
    int k = b*192 + tid*64 + c;
    nstat[k*2]   = m;
    nstat[k*2+1] = rsqrtf(va + 1e-5f);
  }
}

// ---------------- K2: fuse 1x1 (192->64). LDS-GEMM: 2 og x 128 tiles; J=4, P=8 (R6 form) ----------------
__global__ __launch_bounds__(256) void k2_fuse(const float* __restrict__ feats, const float* __restrict__ nstat,
                                               const float* __restrict__ wf, float* __restrict__ xf){
  int og = blockIdx.x >> 7, tile = blockIdx.x & 127;
  int b = tile >> 4, pt = tile & 15;
  int jslot = threadIdx.x >> 5, pxslot = threadIdx.x & 31;
  __shared__ float wlds[32][192];   // 24 KB
  __shared__ float xs[32][256];     // 32 KB
  __shared__ float msl[192], rsl[192];
  for (int i = threadIdx.x; i < 192; i += 256){
    msl[i] = nstat[(b*192+i)*2];
    rsl[i] = nstat[(b*192+i)*2+1];
  }
  {
    const float4* Wg = (const float4*)(wf + WF_FUSE + og*32*192);
    float4* Wl = (float4*)&wlds[0][0];
    for (int i = threadIdx.x; i < 1536; i += 256) Wl[i] = Wg[i];
  }
  float acc[4][8];
  #pragma unroll
  for (int j=0;j<4;j++)
    #pragma unroll
    for (int p=0;p<8;p++) acc[j][p]=0.f;
  const float* fbase = feats + (size_t)b*192*NL + pt*256;
  for (int ch = 0; ch < 6; ch++){
    __syncthreads();
    for (int i = threadIdx.x; i < 2048; i += 256){
      int r = i >> 6, c4 = i & 63;
      int k = ch*32 + r;
      float4 f = *(const float4*)(fbase + (size_t)k*NL + c4*4);
      float m = msl[k], rs = rsl[k];
      float v0=(f.x-m)*rs, v1=(f.y-m)*rs, v2=(f.z-m)*rs, v3=(f.w-m)*rs;
      v0 = v0>0.f?v0:0.01f*v0; v1 = v1>0.f?v1:0.01f*v1;
      v2 = v2>0.f?v2:0.01f*v2; v3 = v3>0.f?v3:0.01f*v3;
      ((float4*)&xs[r][0])[c4] = make_float4(v0,v1,v2,v3);
    }
    __syncthreads();
    for (int c = 0; c < 32; c++){
      float a[8];
      #pragma unroll
      for (int p=0;p<8;p++) a[p] = xs[c][pxslot + 32*p];
      #pragma unroll
      for (int jj=0;jj<4;jj++){
        float w = wlds[jslot*4+jj][ch*32+c];
        #pragma unroll
        for (int p=0;p<8;p++) acc[jj][p] += w*a[p];
      }
    }
  }
  #pragma unroll
  for (int jj=0;jj<4;jj++){
    int o = og*32 + jslot*4 + jj;
    float bias = wf[WF_FUSEB + o];
    float* dp = xf + (size_t)b*64*NL + (size_t)o*NL + pt*256;
    #pragma unroll
    for (int p=0;p<8;p++) dp[pxslot + 32*p] = acc[jj][p] + bias;
  }
}

// ---------------- K3: inorm(xf)+lrelu + x -> x1 ----------------
__global__ __launch_bounds__(256) void k3_norm(const float* __restrict__ xf, const float* __restrict__ x,
                                               float* __restrict__ x1){
  const int tid = threadIdx.x;
  const size_t base = (size_t)blockIdx.x * NL;
  float loc[16]; float s=0.f, q=0.f;
  #pragma unroll
  for (int i=0;i<16;i++){ float v = xf[base + tid + i*256]; loc[i]=v; s+=v; q+=v*v; }
  __shared__ float red[4][2];
  int wid = tid>>6, lane = tid&63;
  #pragma unroll
  for (int o=32;o>0;o>>=1){ s += __shfl_down(s,o); q += __shfl_down(q,o); }
  if (!lane){ red[wid][0]=s; red[wid][1]=q; }
  __syncthreads();
  s = red[0][0]+red[1][0]+red[2][0]+red[3][0];
  q = red[0][1]+red[1][1]+red[2][1]+red[3][1];
  float m = s*(1.f/NL), va = q*(1.f/NL)-m*m, rs = rsqrtf(va+1e-5f);
  #pragma unroll
  for (int i=0;i<16;i++){
    int idx = tid + i*256;
    float v = (loc[i]-m)*rs;
    v = v>0.f ? v : 0.01f*v;
    x1[base+idx] = v + x[base+idx];
  }
}

// ---------------- K4: in_proj (64->256). LDS-GEMM: 4 og x 128 tiles; J=8, P=8 (R6 form) ----------------
__global__ __launch_bounds__(256) void k4_inproj(const float* __restrict__ x1, const float* __restrict__ wf,
                                                 float* __restrict__ xmraw, float* __restrict__ z){
  int og = blockIdx.x >> 7, tile = blockIdx.x & 127;
  int b = tile >> 4, pt = tile & 15;
  int jslot = threadIdx.x >> 5, pxslot = threadIdx.x & 31;
  __shared__ float wlds[64][64];    // 16 KB
  __shared__ float xs[32][256];     // 32 KB
  {
    const float4* Wg = (const float4*)(wf + WF_INPJ + og*64*64);
    float4* Wl = (float4*)&wlds[0][0];
    for (int i = threadIdx.x; i < 1024; i += 256) Wl[i] = Wg[i];
  }
  float acc[8][8];
  #pragma unroll
  for (int j=0;j<8;j++)
    #pragma unroll
    for (int p=0;p<8;p++) acc[j][p]=0.f;
  const float* xbase = x1 + (size_t)b*64*NL + pt*256;
  for (int ch = 0; ch < 2; ch++){
    __syncthreads();
    for (int i = threadIdx.x; i < 2048; i += 256){
      int r = i >> 6, c4 = i & 63;
      ((float4*)&xs[r][0])[c4] = *(const float4*)(xbase + (size_t)(ch*32+r)*NL + c4*4);
    }
    __syncthreads();
    for (int c = 0; c < 32; c++){
      float a[8];
      #pragma unroll
      for (int p=0;p<8;p++) a[p] = xs[c][pxslot + 32*p];
      #pragma unroll
      for (int jj=0;jj<8;jj++){
        float w = wlds[jslot*8+jj][ch*32+c];
        #pragma unroll
        for (int p=0;p<8;p++) acc[jj][p] += w*a[p];
      }
    }
  }
  float* dstbase = (og < 2 ? xmraw + (size_t)b*128*NL + (size_t)(og*64)*NL
                           : z     + (size_t)b*128*NL + (size_t)((og-2)*64)*NL) + pt*256;
  #pragma unroll
  for (int jj=0;jj<8;jj++){
    float* dp = dstbase + (size_t)(jslot*8+jj)*NL;
    #pragma unroll
    for (int p=0;p<8;p++) dp[pxslot + 32*p] = acc[jj][p];
  }
}

// ---------------- K5: depthwise 3x3 + silu ----------------
__global__ __launch_bounds__(256) void k5_dw3(const float* __restrict__ xmraw, const float* __restrict__ wf,
                                              float* __restrict__ xmc){
  const int d = blockIdx.x & 127;
  const int tid = threadIdx.x;
  __shared__ float xs[66*68];
  for (int i=tid;i<66*68;i+=256) xs[i]=0.f;
  __syncthreads();
  const float* xp = xmraw + (size_t)blockIdx.x * NL;
  for (int i=tid;i<NL;i+=256){ int h=i>>6, w=i&63; xs[(h+1)*68 + (w+1)] = xp[i]; }
  float wr[9];
  #pragma unroll
  for (int i=0;i<9;i++) wr[i] = wf[WF_C2W + d*9 + i];
  float bb = wf[WF_C2B + d];
  __syncthreads();
  float* op = xmc + (size_t)blockIdx.x * NL;
  #pragma unroll
  for (int g=0; g<4; g++){
    int p = g*1024 + tid*4;
    int h = p>>6, w0 = p&63;
    float a[4];
    #pragma unroll
    for (int i=0;i<4;i++) a[i]=bb;
    #pragma unroll
    for (int dy=0; dy<3; dy++){
      float s[6];
      #pragma unroll
      for (int j=0;j<6;j++) s[j] = xs[(h+dy)*68 + w0 + j];
      #pragma unroll
      for (int dx=0;dx<3;dx++){
        float wv = wr[dy*3+dx];
        #pragma unroll
        for (int i=0;i<4;i++) a[i] += s[dx+i]*wv;
      }
    }
    float4 o;
    o.x = a[0]/(1.f+__expf(-a[0]));
    o.y = a[1]/(1.f+__expf(-a[1]));
    o.z = a[2]/(1.f+__expf(-a[2]));
    o.w = a[3]/(1.f+__expf(-a[3]));
    *(float4*)(op+p) = o;
  }
}

// ---------------- K6 (slim): x_proj (128->36), one pass; grid 256; J=9, P=2 ----------------
__global__ __launch_bounds__(256) void k6_xproj(const float* __restrict__ xmc, const float* __restrict__ wf,
                                                float* __restrict__ Bm, float* __restrict__ Cm,
                                                float* __restrict__ dtm){
  int b = blockIdx.x >> 5, pt = blockIdx.x & 31;       // 128-px tiles
  int jslot = threadIdx.x >> 6, pxslot = threadIdx.x & 63;
  __shared__ float wlds[36*128];    // 18 KB
  __shared__ float xs[32*128];      // 16 KB
  {
    const float4* Wg = (const float4*)(wf + WF_XPW);
    float4* Wl = (float4*)wlds;
    for (int i = threadIdx.x; i < 1152; i += 256) Wl[i] = Wg[i];
  }
  float acc[9][2];
  #pragma unroll
  for (int j=0;j<9;j++){ acc[j][0]=0.f; acc[j][1]=0.f; }
  const float* ubase = xmc + (size_t)b*128*NL + pt*128;
  for (int ch = 0; ch < 4; ch++){
    __syncthreads();
    for (int i = threadIdx.x; i < 1024; i += 256){
      int r = i >> 5, c4 = i & 31;
      ((float4*)xs)[r*32 + c4] = *(const float4*)(ubase + (size_t)(ch*32+r)*NL + c4*4);
    }
    __syncthreads();
    for (int c = 0; c < 32; c++){
      float a0 = xs[c*128 + pxslot];
      float a1 = xs[c*128 + pxslot + 64];
      #pragma unroll
      for (int j=0;j<9;j++){
        float w = wlds[(jslot*9+j)*128 + ch*32 + c];
        acc[j][0] += w*a0;
        acc[j][1] += w*a1;
      }
    }
  }
  #pragma unroll
  for (int j=0;j<9;j++){
    int o = jslot*9 + j;
    float* dp;
    if (o < 4)       dp = dtm + ((size_t)b*4 + o)*NL;
    else if (o < 20) dp = Bm  + ((size_t)b*16 + (o-4))*NL;
    else             dp = Cm  + ((size_t)b*16 + (o-20))*NL;
    dp[pt*128 + pxslot]      = acc[j][0];
    dp[pt*128 + pxslot + 64] = acc[j][1];
  }
}

// ---------------- K7: scan pass1 — stage u/B/dt in LDS, delta on the fly ----------------
__global__ __launch_bounds__(128) void k7_scan1(const float* __restrict__ xmc, const float* __restrict__ Bm,
                                                const float* __restrict__ dtm, const float* __restrict__ wf,
                                                float* __restrict__ Ac, float* __restrict__ Bc){
  int k = blockIdx.x & (NKCH-1), b = blockIdx.x >> 7;
  int d = threadIdx.x;
  int l0 = k*CHUNK;
  __shared__ float xs[128*33];      // u, padded
  __shared__ float Bl[16*32];
  __shared__ float dtl[4*32];
  for (int i = d; i < 4096; i += 128){
    int ch = i >> 5, px = i & 31;
    xs[ch*33+px] = xmc[((size_t)b*128+ch)*NL + l0 + px];
  }
  for (int i = d; i < 512; i += 128){
    int n = i >> 5, li = i & 31;
    Bl[i] = Bm[((size_t)b*16+n)*NL + l0 + li];
  }
  if (d < 128){
    int n = d >> 5, li = d & 31;
    dtl[d] = dtm[((size_t)b*4+n)*NL + l0 + li];
  }
  float A[16], P[16], Q[16];
  const float* Af = wf + WF_A + d*16;
  #pragma unroll
  for (int n=0;n<16;n++){ A[n]=Af[n]; P[n]=1.f; Q[n]=0.f; }
  float w0 = wf[WF_DTW+d*4], w1 = wf[WF_DTW+d*4+1], w2 = wf[WF_DTW+d*4+2], w3 = wf[WF_DTW+d*4+3];
  float db2 = 2.f*wf[WF_DTB+d];
  __syncthreads();
  for (int l=0; l<CHUNK; l++){
    float tt = w0*dtl[l] + w1*dtl[32+l] + w2*dtl[64+l] + w3*dtl[96+l] + db2;
    float de = tt > 20.f ? tt : __logf(1.f+__expf(tt));   // softplus (double bias, faithful)
    float du = de * xs[d*33+l];
    #pragma unroll
    for (int n=0;n<16;n++){
      float a = __expf(de*A[n]);
      P[n] *= a;
      Q[n] = a*Q[n] + du*Bl[n*32+l];
    }
  }
  size_t base = (((size_t)k*NB + b)*128 + d)*16;
  #pragma unroll
  for (int i=0;i<4;i++){
    ((float4*)(Ac+base))[i] = make_float4(P[i*4],P[i*4+1],P[i*4+2],P[i*4+3]);
    ((float4*)(Bc+base))[i] = make_float4(Q[i*4],Q[i*4+1],Q[i*4+2],Q[i*4+3]);
  }
}

// ---------------- K8: middle scan over chunk aggregates; unroll 16 for load ILP ----------------
__global__ __launch_bounds__(256) void k8_mid(const float* __restrict__ Ac, const float* __restrict__ Bc,
                                              float* __restrict__ Hi){
  int idx = blockIdx.x*256 + threadIdx.x;   // (b*128+d)*16+n, 16384 total
  float h = 0.f;
  for (int k0=0;k0<NKCH;k0+=16){
    float av[16], bv[16];
    #pragma unroll
    for (int j=0;j<16;j++){
      size_t o = (size_t)(k0+j)*16384 + idx;
      av[j]=Ac[o]; bv[j]=Bc[o];
    }
    #pragma unroll
    for (int j=0;j<16;j++){
      size_t o = (size_t)(k0+j)*16384 + idx;
      Hi[o] = h;
      h = av[j]*h + bv[j];
    }
  }
}

// ---------------- K9: scan pass2 + fused LN*silu(z) gate -> G ----------------
__global__ __launch_bounds__(128) void k9_scan2(const float* __restrict__ xmc, const float* __restrict__ Bm,
                                                const float* __restrict__ Cm, const float* __restrict__ dtm,
                                                const float* __restrict__ z, const float* __restrict__ wf,
                                                const float* __restrict__ Hi, float* __restrict__ G){
  int k = blockIdx.x & (NKCH-1), b = blockIdx.x >> 7;
  int d = threadIdx.x;
  int l0 = k*CHUNK;
  __shared__ float xs[128*33];      // u, then y in place
  __shared__ float Bl[16*32], Cl[16*32];
  __shared__ float dtl[4*32];
  __shared__ float red[4][32][2];
  __shared__ float mstat[32], rstat[32];
  for (int i = d; i < 4096; i += 128){
    int ch = i >> 5, px = i & 31;
    xs[ch*33+px] = xmc[((size_t)b*128+ch)*NL + l0 + px];
  }
  for (int i = d; i < 512; i += 128){
    int n = i >> 5, li = i & 31;
    Bl[i] = Bm[((size_t)b*16+n)*NL + l0 + li];
    Cl[i] = Cm[((size_t)b*16+n)*NL + l0 + li];
  }
  if (d < 128){
    int n = d >> 5, li = d & 31;
    dtl[d] = dtm[((size_t)b*4+n)*NL + l0 + li];
  }
  float A[16], h[16];
  const float* Af = wf + WF_A + d*16;
  size_t hb = (((size_t)k*NB + b)*128 + d)*16;
  #pragma unroll
  for (int n=0;n<16;n++){ A[n]=Af[n]; h[n]=Hi[hb+n]; }
  float Dv = wf[WF_DP + d];
  float w0 = wf[WF_DTW+d*4], w1 = wf[WF_DTW+d*4+1], w2 = wf[WF_DTW+d*4+2], w3 = wf[WF_DTW+d*4+3];
  float db2 = 2.f*wf[WF_DTB+d];
  __syncthreads();
  for (int l=0; l<CHUNK; l++){
    float tt = w0*dtl[l] + w1*dtl[32+l] + w2*dtl[64+l] + w3*dtl[96+l] + db2;
    float de = tt > 20.f ? tt : __logf(1.f+__expf(tt));
    float uu = xs[d*33+l];
    float du = de * uu;
    float yv = uu * Dv;
    #pragma unroll
    for (int n=0;n<16;n++){
      float a = __expf(de*A[n]);
      h[n] = a*h[n] + du*Bl[n*32+l];
      yv  += h[n]*Cl[n*32+l];
    }
    xs[d*33+l] = yv;    // y overwrites u (row d private to this thread)
  }
  __syncthreads();
  // LayerNorm over d (128) per pixel l
  {
    int px = d & 31, q = d >> 5;
    float s=0.f, qq=0.f;
    #pragma unroll
    for (int j=0;j<32;j++){ float v = xs[(q*32+j)*33+px]; s+=v; qq+=v*v; }
    red[q][px][0]=s; red[q][px][1]=qq;
  }
  __syncthreads();
  if (d < 32){
    float ss = red[0][d][0]+red[1][d][0]+red[2][d][0]+red[3][d][0];
    float sq = red[0][d][1]+red[1][d][1]+red[2][d][1]+red[3][d][1];
    float m = ss*(1.f/128.f);
    mstat[d] = m;
    rstat[d] = rsqrtf(sq*(1.f/128.f) - m*m + 1e-5f);
  }
  __syncthreads();
  float ow = wf[WF_ONW+d], ob = wf[WF_ONB+d];
  const float* zp = z + ((size_t)b*128+d)*NL + l0;
  float* gp = G + ((size_t)b*128+d)*NL + l0;
  #pragma unroll
  for (int l4=0; l4<CHUNK/4; l4++){
    float4 zv4 = ((const float4*)zp)[l4];
    float zv[4] = {zv4.x, zv4.y, zv4.z, zv4.w};
    float out[4];
    #pragma unroll
    for (int j=0;j<4;j++){
      int l = l4*4+j;
      float t = (xs[d*33+l]-mstat[l])*rstat[l]*ow + ob;
      out[j] = t * (zv[j]/(1.f+__expf(-zv[j])));
    }
    ((float4*)gp)[l4] = make_float4(out[0],out[1],out[2],out[3]);
  }
}

// ---------------- K11A: yc = W_comb @ G + cf_b. 2 og x 128 tiles; J=4, P=8; + stats (R6 form) ----------------
__global__ __launch_bounds__(256) void k11A_proj(const float* __restrict__ G, const float* __restrict__ wf,
                                                 const float* __restrict__ wcomb,
                                                 float* __restrict__ yc, float* __restrict__ part){
  int og = blockIdx.x >> 7, tile = blockIdx.x & 127;
  int b = tile >> 4, pt = tile & 15;
  int jslot = threadIdx.x >> 5, pxslot = threadIdx.x & 31;
  __shared__ float wlds[32][128];   // 16 KB
  __shared__ float xs[32][256];     // 32 KB
  {
    const float4* Wg = (const float4*)(wcomb + og*32*128);
    float4* Wl = (float4*)&wlds[0][0];
    for (int i = threadIdx.x; i < 1024; i += 256) Wl[i] = Wg[i];
  }
  float acc[4][8];
  #pragma unroll
  for (int j=0;j<4;j++)
    #pragma unroll
    for (int p=0;p<8;p++) acc[j][p]=0.f;
  const float* gbase = G + (size_t)b*128*NL + pt*256;
  for (int ch = 0; ch < 4; ch++){
    __syncthreads();
    for (int i = threadIdx.x; i < 2048; i += 256){
      int r = i >> 6, c4 = i & 63;
      ((float4*)&xs[r][0])[c4] = *(const float4*)(gbase + (size_t)(ch*32+r)*NL + c4*4);
    }
    __syncthreads();
    for (int c = 0; c < 32; c++){
      float a[8];
      #pragma unroll
      for (int p=0;p<8;p++) a[p] = xs[c][pxslot + 32*p];
      #pragma unroll
      for (int jj=0;jj<4;jj++){
        float w = wlds[jslot*4+jj][ch*32+c];
        #pragma unroll
        for (int p=0;p<8;p++) acc[jj][p] += w*a[p];
      }
    }
  }
  #pragma unroll
  for (int jj=0;jj<4;jj++){
    int cc = og*32 + jslot*4 + jj;
    float bias = wf[WF_CFB + cc];
    float* dp = yc + (size_t)b*64*NL + (size_t)cc*NL + pt*256;
    float sv = 0.f, qv = 0.f;
    #pragma unroll
    for (int p=0;p<8;p++){
      float t = acc[jj][p] + bias;
      dp[pxslot + 32*p] = t;
      sv += t; qv += t*t;
    }
    #pragma unroll
    for (int o=16;o>0;o>>=1){ sv += __shfl_xor(sv,o); qv += __shfl_xor(qv,o); }
    if (pxslot == 0){
      size_t pidx = (((size_t)b*64 + cc)*16 + pt)*2;
      part[pidx] = sv; part[pidx+1] = qv;
    }
  }
}

// ---------------- K11b: finalize per-(b,c) mean/rsqrt (16 partials each) ----------------
__global__ __launch_bounds__(256) void k11b_stats(const float* __restrict__ part, float* __restrict__ stats){
  int i = blockIdx.x*256 + threadIdx.x;
  if (i >= 512) return;
  float s=0.f, q=0.f;
  #pragma unroll
  for (int t2=0;t2<16;t2++){ s += part[((size_t)i*16+t2)*2]; q += part[((size_t)i*16+t2)*2+1]; }
  float m = s*(1.f/NL), va = q*(1.f/NL) - m*m;
  stats[i*2] = m; stats[i*2+1] = rsqrtf(va+1e-5f);
}

// ---------------- K11c: out = x1 + inorm(yc), write f32 ----------------
__global__ __launch_bounds__(256) void k11c_final(const float* __restrict__ yc, const float* __restrict__ stats,
                                                  const float* __restrict__ x1, float* __restrict__ out){
  int bc = blockIdx.x;
  float m = stats[bc*2], rs = stats[bc*2+1];
  size_t base = (size_t)bc*NL;
  for (int i=threadIdx.x;i<NL;i+=256){
    float v = (yc[base+i]-m)*rs;
    out[base+i] = x1[base+i] + v;
  }
}

// ---------------- host ----------------
extern "C" void kernel_launch(void* const* d_in, const int* in_sizes, int n_in,
                              void* d_out, int out_size, void* d_ws, size_t ws_size,
                              hipStream_t stream) {
  if (ws_size < WS_NEED_FLOATS * sizeof(float)) return;  // insufficient scratch; bail cleanly
  const float* x     = (const float*)d_in[0];
  const float* dw3w  = (const float*)d_in[1];
  const float* dw3b  = (const float*)d_in[2];
  const float* dw5w  = (const float*)d_in[3];
  const float* dw5b  = (const float*)d_in[4];
  const float* dw7w  = (const float*)d_in[5];
  const float* dw7b  = (const float*)d_in[6];
  const float* fusew = (const float*)d_in[7];
  const float* fuseb = (const float*)d_in[8];
  const float* inpjw = (const float*)d_in[9];
  const float* c2w   = (const float*)d_in[10];
  const float* c2b   = (const float*)d_in[11];
  const float* xpw   = (const float*)d_in[12];
  const float* dtw   = (const float*)d_in[13];
  const float* dtb   = (const float*)d_in[14];
  const float* alog  = (const float*)d_in[15];
  const float* dpv   = (const float*)d_in[16];
  const float* onw   = (const float*)d_in[17];
  const float* onb   = (const float*)d_in[18];
  const float* opw   = (const float*)d_in[19];
  const float* cfw   = (const float*)d_in[20];
  const float* cfb   = (const float*)d_in[21];

  float* ws    = (float*)d_ws;
  float* wf    = ws + OFF_WF;
  float* wcomb = ws + OFF_WCOMB;
  float* feats = ws + OFF_FEATS;
  float* nstat = ws + OFF_NSTAT;
  float* xf    = ws + OFF_XF;
  float* x1    = ws + OFF_X1;
  float* xmraw = ws + OFF_XMRAW;
  float* z     = ws + OFF_Z;
  float* xmc   = ws + OFF_XMC;
  float* Bmw   = ws + OFF_BMAT;
  float* Cmw   = ws + OFF_CMAT;
  float* dtm   = ws + OFF_DTM;
  float* Acb   = ws + OFF_AC;
  float* Bcb   = ws + OFF_BC;
  float* Hi    = ws + OFF_HINIT;
  float* G     = ws + OFF_G;
  float* yc    = ws + OFF_YC;
  float* part  = ws + OFF_PART;
  float* stats = ws + OFF_STATS;

  CvtArgs ca; int ns = 0;
  auto add = [&](const float* s, int off, int n, int op){
    ca.d[ns].src = s; ca.d[ns].dst = wf + off; ca.d[ns].n = n; ca.d[ns].op = op; ns++;
  };
  add(dw3w, WF_DW3, 576, 0);   add(dw5w, WF_DW5, 1600, 0);  add(dw7w, WF_DW7, 3136, 0);
  add(dw3b, WF_B3, 64, 0);     add(dw5b, WF_B5, 64, 0);     add(dw7b, WF_B7, 64, 0);
  add(fusew, WF_FUSE, 12288, 0); add(fuseb, WF_FUSEB, 64, 0);
  add(c2w, WF_C2W, 1152, 0);   add(c2b, WF_C2B, 128, 0);
  add(xpw, WF_XPW, 4608, 0);   add(dtw, WF_DTW, 512, 0);    add(dtb, WF_DTB, 128, 0);
  add(alog, WF_A, 2048, 1);    // A = -exp(A_log)
  add(dpv, WF_DP, 128, 0);
  add(onw, WF_ONW, 128, 0);    add(onb, WF_ONB, 128, 0);
  add(opw, WF_OPW, 8192, 0);
  add(cfw, WF_CFW, 4096, 0);   add(cfb, WF_CFB, 64, 0);
  add(inpjw, WF_INPJ, 16384, 0);
  ca.ncvt = ns; ca.cfw = cfw; ca.opw = opw; ca.wcomb = wcomb;

  k0_cvt<<<ns + 32, 256, 0, stream>>>(ca);
  k1_dw<<<512, 256, 0, stream>>>(x, wf, feats, nstat);
  k2_fuse<<<256, 256, 0, stream>>>(feats, nstat, wf, xf);
  k3_norm<<<512, 256, 0, stream>>>(xf, x, x1);
  k4_inproj<<<512, 256, 0, stream>>>(x1, wf, xmraw, z);
  k5_dw3<<<1024, 256, 0, stream>>>(xmraw, wf, xmc);
  k6_xproj<<<256, 256, 0, stream>>>(xmc, wf, Bmw, Cmw, dtm);
  k7_scan1<<<1024, 128, 0, stream>>>(xmc, Bmw, dtm, wf, Acb, Bcb);
  k8_mid<<<64, 256, 0, stream>>>(Acb, Bcb, Hi);
  k9_scan2<<<1024, 128, 0, stream>>>(xmc, Bmw, Cmw, dtm, z, wf, Hi, G);
  k11A_proj<<<256, 256, 0, stream>>>(G, wf, wcomb, yc, part);
  k11b_stats<<<2, 256, 0, stream>>>(part, stats);
  k11c_final<<<512, 256, 0, stream>>>(yc, stats, x1, (float*)d_out);
}

// Round 9
// 235.644 us; speedup vs baseline: 2.8903x; 1.9957x over previous
//
#include <hip/hip_runtime.h>
#include <math.h>

#define NB 8
#define NC 64
#define NL 4096
#define NDI 128
#define NN 16
#define CHUNK 32
#define NKCH 128   // NL / CHUNK

// ---------------- workspace layout (float offsets) ----------------
#define OFF_FEATS 0ull          // 6291456 (dead after K2 -> reused by AC/BC/HINIT)
#define OFF_AC    0ull          // 2097152
#define OFF_BC    2097152ull    // 2097152
#define OFF_HINIT 4194304ull    // 2097152
#define OFF_XF    6291456ull    // 2097152 (dead after K3 -> reused by BMAT/CMAT)
#define OFF_BMAT  6291456ull    // 524288
#define OFF_CMAT  6815744ull    // 524288
#define OFF_X1    8388608ull    // 2097152 (live to the end)
#define OFF_XMRAW 10485760ull   // 4194304 (dead after K5 -> reused by G)
#define OFF_G     10485760ull   // 4194304
#define OFF_Z     14680064ull   // 4194304 (z dead after K9 -> low half reused by YC)
#define OFF_YC    14680064ull   // 2097152
#define OFF_PART  16777216ull   // 16384
#define OFF_STATS 16809984ull   // 1024
#define OFF_XMC   18874368ull   // 4194304
#define OFF_DTM   23068672ull   // 131072
#define OFF_WF    27262976ull   // 55552 f32 weights
#define OFF_NSTAT (OFF_WF + 55552ull)   // 3072
#define OFF_WCOMB (OFF_WF + 58624ull)   // 8192 (cf_w @ op_w)
#define WS_NEED_FLOATS (OFF_WF + 66816ull)

// weight sub-offsets inside WF (floats)
#define WF_DW3    0
#define WF_DW5    576
#define WF_DW7    2176
#define WF_B3     5312
#define WF_B5     5376
#define WF_B7     5440
#define WF_FUSE   5504
#define WF_FUSEB  17792
#define WF_C2W    17856
#define WF_C2B    19008
#define WF_XPW    19136
#define WF_DTW    23744
#define WF_DTB    24256
#define WF_A      24384
#define WF_DP     26432
#define WF_ONW    26560
#define WF_ONB    26688
#define WF_OPW    26816
#define WF_CFW    35008
#define WF_CFB    39104
#define WF_INPJ   39168

// ---------------- K0: weights->f32 (A = -exp(A_log)); tail blocks compute W_comb ----------------
struct Cvt { const float* src; float* dst; int n; int op; };
struct CvtArgs { Cvt d[22]; int ncvt; const float* cfw; const float* opw; float* wcomb; };

__global__ __launch_bounds__(256) void k0_cvt(CvtArgs a){
  if ((int)blockIdx.x < a.ncvt){
    Cvt c = a.d[blockIdx.x];
    for (int i = threadIdx.x; i < c.n; i += 256){
      float v = c.src[i];
      c.dst[i] = c.op ? -expf(v) : v;
    }
  } else {
    int idx = (blockIdx.x - a.ncvt)*256 + threadIdx.x;   // 8192 outputs
    int c = idx >> 7, kk = idx & 127;
    float s = 0.f;
    #pragma unroll
    for (int j=0;j<64;j++) s += a.cfw[c*64+j] * a.opw[j*128+kk];
    a.wcomb[idx] = s;
  }
}

// ---------------- K1: 3 depthwise convs (3/5/7) raw + per-plane stats ----------------
__global__ __launch_bounds__(256) void k1_dw(const float* __restrict__ x, const float* __restrict__ wf,
                                             float* __restrict__ feats, float* __restrict__ nstat){
  const int b = blockIdx.x >> 6, c = blockIdx.x & 63;
  const int tid = threadIdx.x;
  __shared__ float xs[70*72];          // zero-padded (3 each side), row stride 72
  __shared__ float red[4][6];
  for (int i = tid; i < 70*72; i += 256) xs[i] = 0.f;
  __syncthreads();
  const float* xp = x + (size_t)blockIdx.x * NL;
  for (int i = tid; i < NL; i += 256){
    int h = i >> 6, w = i & 63;
    xs[(h+3)*72 + (w+3)] = xp[i];
  }
  float w3r[9], w5r[25], w7r[49];
  #pragma unroll
  for (int i=0;i<9;i++)  w3r[i] = wf[WF_DW3 + c*9 + i];
  #pragma unroll
  for (int i=0;i<25;i++) w5r[i] = wf[WF_DW5 + c*25 + i];
  #pragma unroll
  for (int i=0;i<49;i++) w7r[i] = wf[WF_DW7 + c*49 + i];
  float b3 = wf[WF_B3+c], b5 = wf[WF_B5+c], b7 = wf[WF_B7+c];
  __syncthreads();
  float s3=0,q3=0,s5=0,q5=0,s7=0,q7=0;
  float* f3 = feats + ((size_t)b*192 + c) * NL;
  float* f5 = f3 + (size_t)64*NL;
  float* f7 = f3 + (size_t)128*NL;
  #pragma unroll
  for (int g=0; g<4; g++){
    int p = g*1024 + tid*4;
    int h = p >> 6, w0 = p & 63;
    float a3[4], a5[4], a7[4];
    #pragma unroll
    for (int i=0;i<4;i++){ a3[i]=b3; a5[i]=b5; a7[i]=b7; }
    #pragma unroll
    for (int dy=0; dy<7; dy++){
      float s[10];
      #pragma unroll
      for (int j=0;j<10;j++) s[j] = xs[(h+dy)*72 + w0 + j];
      #pragma unroll
      for (int dx=0;dx<7;dx++){
        float wv = w7r[dy*7+dx];
        #pragma unroll
        for (int i=0;i<4;i++) a7[i] += s[dx+i]*wv;
      }
      if (dy>=1 && dy<=5){
        #pragma unroll
        for (int dx=0;dx<5;dx++){
          float wv = w5r[(dy-1)*5+dx];
          #pragma unroll
          for (int i=0;i<4;i++) a5[i] += s[dx+1+i]*wv;
        }
      }
      if (dy>=2 && dy<=4){
        #pragma unroll
        for (int dx=0;dx<3;dx++){
          float wv = w3r[(dy-2)*3+dx];
          #pragma unroll
          for (int i=0;i<4;i++) a3[i] += s[dx+2+i]*wv;
        }
      }
    }
    *(float4*)(f3+p) = make_float4(a3[0],a3[1],a3[2],a3[3]);
    *(float4*)(f5+p) = make_float4(a5[0],a5[1],a5[2],a5[3]);
    *(float4*)(f7+p) = make_float4(a7[0],a7[1],a7[2],a7[3]);
    #pragma unroll
    for (int i=0;i<4;i++){
      s3+=a3[i]; q3+=a3[i]*a3[i];
      s5+=a5[i]; q5+=a5[i]*a5[i];
      s7+=a7[i]; q7+=a7[i]*a7[i];
    }
  }
  int wid = tid>>6, lane = tid&63;
  float v6[6]={s3,q3,s5,q5,s7,q7};
  #pragma unroll
  for (int j=0;j<6;j++){
    float t = v6[j];
    #pragma unroll
    for (int o=32;o>0;o>>=1) t += __shfl_down(t,o);
    if (!lane) red[wid][j]=t;
  }
  __syncthreads();
  if (tid < 3){
    float su = red[0][tid*2]+red[1][tid*2]+red[2][tid*2]+red[3][tid*2];
    float sq = red[0][tid*2+1]+red[1][tid*2+1]+red[2][tid*2+1]+red[3][tid*2+1];
    float m  = su*(1.f/NL);
    float va = sq*(1.f/NL) - m*m;
    int k = b*192 + tid*64 + c;
    nstat[k*2]   = m;
    nstat[k*2+1] = rsqrtf(va + 1e-5f);
  }
}

// ---------------- K2: fuse 1x1 (192->64). LDS-GEMM: 2 og x 128 tiles; J=4, P=8 (pinned rolled) ----------------
__global__ __launch_bounds__(256) void k2_fuse(const float* __restrict__ feats, const float* __restrict__ nstat,
                                               const float* __restrict__ wf, float* __restrict__ xf){
  int og = blockIdx.x >> 7, tile = blockIdx.x & 127;
  int b = tile >> 4, pt = tile & 15;
  int jslot = threadIdx.x >> 5, pxslot = threadIdx.x & 31;
  __shared__ float wlds[32][192];   // 24 KB
  __shared__ float xs[32][256];     // 32 KB
  __shared__ float msl[192], rsl[192];
  for (int i = threadIdx.x; i < 192; i += 256){
    msl[i] = nstat[(b*192+i)*2];
    rsl[i] = nstat[(b*192+i)*2+1];
  }
  {
    const float4* Wg = (const float4*)(wf + WF_FUSE + og*32*192);
    float4* Wl = (float4*)&wlds[0][0];
    for (int i = threadIdx.x; i < 1536; i += 256) Wl[i] = Wg[i];
  }
  float acc[4][8];
  #pragma unroll
  for (int j=0;j<4;j++)
    #pragma unroll
    for (int p=0;p<8;p++) acc[j][p]=0.f;
  const float* fbase = feats + (size_t)b*192*NL + pt*256;
  for (int ch = 0; ch < 6; ch++){
    __syncthreads();
    for (int i = threadIdx.x; i < 2048; i += 256){
      int r = i >> 6, c4 = i & 63;
      int k = ch*32 + r;
      float4 f = *(const float4*)(fbase + (size_t)k*NL + c4*4);
      float m = msl[k], rs = rsl[k];
      float v0=(f.x-m)*rs, v1=(f.y-m)*rs, v2=(f.z-m)*rs, v3=(f.w-m)*rs;
      v0 = v0>0.f?v0:0.01f*v0; v1 = v1>0.f?v1:0.01f*v1;
      v2 = v2>0.f?v2:0.01f*v2; v3 = v3>0.f?v3:0.01f*v3;
      ((float4*)&xs[r][0])[c4] = make_float4(v0,v1,v2,v3);
    }
    __syncthreads();
    #pragma unroll 1
    for (int c = 0; c < 32; c++){
      float a[8];
      #pragma unroll
      for (int p=0;p<8;p++) a[p] = xs[c][pxslot + 32*p];
      #pragma unroll
      for (int jj=0;jj<4;jj++){
        float w = wlds[jslot*4+jj][ch*32+c];
        #pragma unroll
        for (int p=0;p<8;p++) acc[jj][p] += w*a[p];
      }
    }
  }
  #pragma unroll
  for (int jj=0;jj<4;jj++){
    int o = og*32 + jslot*4 + jj;
    float bias = wf[WF_FUSEB + o];
    float* dp = xf + (size_t)b*64*NL + (size_t)o*NL + pt*256;
    #pragma unroll
    for (int p=0;p<8;p++) dp[pxslot + 32*p] = acc[jj][p] + bias;
  }
}

// ---------------- K3: inorm(xf)+lrelu + x -> x1 ----------------
__global__ __launch_bounds__(256) void k3_norm(const float* __restrict__ xf, const float* __restrict__ x,
                                               float* __restrict__ x1){
  const int tid = threadIdx.x;
  const size_t base = (size_t)blockIdx.x * NL;
  float loc[16]; float s=0.f, q=0.f;
  #pragma unroll
  for (int i=0;i<16;i++){ float v = xf[base + tid + i*256]; loc[i]=v; s+=v; q+=v*v; }
  __shared__ float red[4][2];
  int wid = tid>>6, lane = tid&63;
  #pragma unroll
  for (int o=32;o>0;o>>=1){ s += __shfl_down(s,o); q += __shfl_down(q,o); }
  if (!lane){ red[wid][0]=s; red[wid][1]=q; }
  __syncthreads();
  s = red[0][0]+red[1][0]+red[2][0]+red[3][0];
  q = red[0][1]+red[1][1]+red[2][1]+red[3][1];
  float m = s*(1.f/NL), va = q*(1.f/NL)-m*m, rs = rsqrtf(va+1e-5f);
  #pragma unroll
  for (int i=0;i<16;i++){
    int idx = tid + i*256;
    float v = (loc[i]-m)*rs;
    v = v>0.f ? v : 0.01f*v;
    x1[base+idx] = v + x[base+idx];
  }
}

// ---------------- K4: in_proj (64->256). LDS-GEMM: 4 og x 128 tiles; J=8, P=8 (pinned rolled) ----------------
__global__ __launch_bounds__(256) void k4_inproj(const float* __restrict__ x1, const float* __restrict__ wf,
                                                 float* __restrict__ xmraw, float* __restrict__ z){
  int og = blockIdx.x >> 7, tile = blockIdx.x & 127;
  int b = tile >> 4, pt = tile & 15;
  int jslot = threadIdx.x >> 5, pxslot = threadIdx.x & 31;
  __shared__ float wlds[64][64];    // 16 KB
  __shared__ float xs[32][256];     // 32 KB
  {
    const float4* Wg = (const float4*)(wf + WF_INPJ + og*64*64);
    float4* Wl = (float4*)&wlds[0][0];
    for (int i = threadIdx.x; i < 1024; i += 256) Wl[i] = Wg[i];
  }
  float acc[8][8];
  #pragma unroll
  for (int j=0;j<8;j++)
    #pragma unroll
    for (int p=0;p<8;p++) acc[j][p]=0.f;
  const float* xbase = x1 + (size_t)b*64*NL + pt*256;
  for (int ch = 0; ch < 2; ch++){
    __syncthreads();
    for (int i = threadIdx.x; i < 2048; i += 256){
      int r = i >> 6, c4 = i & 63;
      ((float4*)&xs[r][0])[c4] = *(const float4*)(xbase + (size_t)(ch*32+r)*NL + c4*4);
    }
    __syncthreads();
    #pragma unroll 1
    for (int c = 0; c < 32; c++){
      float a[8];
      #pragma unroll
      for (int p=0;p<8;p++) a[p] = xs[c][pxslot + 32*p];
      #pragma unroll
      for (int jj=0;jj<8;jj++){
        float w = wlds[jslot*8+jj][ch*32+c];
        #pragma unroll
        for (int p=0;p<8;p++) acc[jj][p] += w*a[p];
      }
    }
  }
  float* dstbase = (og < 2 ? xmraw + (size_t)b*128*NL + (size_t)(og*64)*NL
                           : z     + (size_t)b*128*NL + (size_t)((og-2)*64)*NL) + pt*256;
  #pragma unroll
  for (int jj=0;jj<8;jj++){
    float* dp = dstbase + (size_t)(jslot*8+jj)*NL;
    #pragma unroll
    for (int p=0;p<8;p++) dp[pxslot + 32*p] = acc[jj][p];
  }
}

// ---------------- K5: depthwise 3x3 + silu ----------------
__global__ __launch_bounds__(256) void k5_dw3(const float* __restrict__ xmraw, const float* __restrict__ wf,
                                              float* __restrict__ xmc){
  const int d = blockIdx.x & 127;
  const int tid = threadIdx.x;
  __shared__ float xs[66*68];
  for (int i=tid;i<66*68;i+=256) xs[i]=0.f;
  __syncthreads();
  const float* xp = xmraw + (size_t)blockIdx.x * NL;
  for (int i=tid;i<NL;i+=256){ int h=i>>6, w=i&63; xs[(h+1)*68 + (w+1)] = xp[i]; }
  float wr[9];
  #pragma unroll
  for (int i=0;i<9;i++) wr[i] = wf[WF_C2W + d*9 + i];
  float bb = wf[WF_C2B + d];
  __syncthreads();
  float* op = xmc + (size_t)blockIdx.x * NL;
  #pragma unroll
  for (int g=0; g<4; g++){
    int p = g*1024 + tid*4;
    int h = p>>6, w0 = p&63;
    float a[4];
    #pragma unroll
    for (int i=0;i<4;i++) a[i]=bb;
    #pragma unroll
    for (int dy=0; dy<3; dy++){
      float s[6];
      #pragma unroll
      for (int j=0;j<6;j++) s[j] = xs[(h+dy)*68 + w0 + j];
      #pragma unroll
      for (int dx=0;dx<3;dx++){
        float wv = wr[dy*3+dx];
        #pragma unroll
        for (int i=0;i<4;i++) a[i] += s[dx+i]*wv;
      }
    }
    float4 o;
    o.x = a[0]/(1.f+__expf(-a[0]));
    o.y = a[1]/(1.f+__expf(-a[1]));
    o.z = a[2]/(1.f+__expf(-a[2]));
    o.w = a[3]/(1.f+__expf(-a[3]));
    *(float4*)(op+p) = o;
  }
}

// ---------------- K6 (slim): x_proj (128->36); grid 256; J=9, P=2; c-loop pinned rolled ----------------
__global__ __launch_bounds__(256) void k6_xproj(const float* __restrict__ xmc, const float* __restrict__ wf,
                                                float* __restrict__ Bm, float* __restrict__ Cm,
                                                float* __restrict__ dtm){
  int b = blockIdx.x >> 5, pt = blockIdx.x & 31;       // 128-px tiles
  int jslot = threadIdx.x >> 6, pxslot = threadIdx.x & 63;
  __shared__ float wlds[36][128];   // 18 KB
  __shared__ float xs[32][128];     // 16 KB
  {
    const float4* Wg = (const float4*)(wf + WF_XPW);
    float4* Wl = (float4*)&wlds[0][0];
    for (int i = threadIdx.x; i < 1152; i += 256) Wl[i] = Wg[i];
  }
  float acc[9][2];
  #pragma unroll
  for (int j=0;j<9;j++){ acc[j][0]=0.f; acc[j][1]=0.f; }
  const float* ubase = xmc + (size_t)b*128*NL + pt*128;
  for (int ch = 0; ch < 4; ch++){
    __syncthreads();
    for (int i = threadIdx.x; i < 1024; i += 256){
      int r = i >> 5, c4 = i & 31;
      ((float4*)&xs[r][0])[c4] = *(const float4*)(ubase + (size_t)(ch*32+r)*NL + c4*4);
    }
    __syncthreads();
    #pragma unroll 1
    for (int c = 0; c < 32; c++){
      float a0 = xs[c][pxslot];
      float a1 = xs[c][pxslot + 64];
      #pragma unroll
      for (int j=0;j<9;j++){
        float w = wlds[jslot*9+j][ch*32+c];
        acc[j][0] += w*a0;
        acc[j][1] += w*a1;
      }
    }
  }
  #pragma unroll
  for (int j=0;j<9;j++){
    int o = jslot*9 + j;
    float* dp;
    if (o < 4)       dp = dtm + ((size_t)b*4 + o)*NL;
    else if (o < 20) dp = Bm  + ((size_t)b*16 + (o-4))*NL;
    else             dp = Cm  + ((size_t)b*16 + (o-20))*NL;
    dp[pt*128 + pxslot]      = acc[j][0];
    dp[pt*128 + pxslot + 64] = acc[j][1];
  }
}

// ---------------- K7: scan pass1 — stage u/B/dt in LDS, delta on the fly ----------------
__global__ __launch_bounds__(128) void k7_scan1(const float* __restrict__ xmc, const float* __restrict__ Bm,
                                                const float* __restrict__ dtm, const float* __restrict__ wf,
                                                float* __restrict__ Ac, float* __restrict__ Bc){
  int k = blockIdx.x & (NKCH-1), b = blockIdx.x >> 7;
  int d = threadIdx.x;
  int l0 = k*CHUNK;
  __shared__ float xs[128*33];      // u, padded
  __shared__ float Bl[16*32];
  __shared__ float dtl[4*32];
  for (int i = d; i < 4096; i += 128){
    int ch = i >> 5, px = i & 31;
    xs[ch*33+px] = xmc[((size_t)b*128+ch)*NL + l0 + px];
  }
  for (int i = d; i < 512; i += 128){
    int n = i >> 5, li = i & 31;
    Bl[i] = Bm[((size_t)b*16+n)*NL + l0 + li];
  }
  if (d < 128){
    int n = d >> 5, li = d & 31;
    dtl[d] = dtm[((size_t)b*4+n)*NL + l0 + li];
  }
  float A[16], P[16], Q[16];
  const float* Af = wf + WF_A + d*16;
  #pragma unroll
  for (int n=0;n<16;n++){ A[n]=Af[n]; P[n]=1.f; Q[n]=0.f; }
  float w0 = wf[WF_DTW+d*4], w1 = wf[WF_DTW+d*4+1], w2 = wf[WF_DTW+d*4+2], w3 = wf[WF_DTW+d*4+3];
  float db2 = 2.f*wf[WF_DTB+d];
  __syncthreads();
  for (int l=0; l<CHUNK; l++){
    float tt = w0*dtl[l] + w1*dtl[32+l] + w2*dtl[64+l] + w3*dtl[96+l] + db2;
    float de = tt > 20.f ? tt : __logf(1.f+__expf(tt));   // softplus (double bias, faithful)
    float du = de * xs[d*33+l];
    #pragma unroll
    for (int n=0;n<16;n++){
      float a = __expf(de*A[n]);
      P[n] *= a;
      Q[n] = a*Q[n] + du*Bl[n*32+l];
    }
  }
  size_t base = (((size_t)k*NB + b)*128 + d)*16;
  #pragma unroll
  for (int i=0;i<4;i++){
    ((float4*)(Ac+base))[i] = make_float4(P[i*4],P[i*4+1],P[i*4+2],P[i*4+3]);
    ((float4*)(Bc+base))[i] = make_float4(Q[i*4],Q[i*4+1],Q[i*4+2],Q[i*4+3]);
  }
}

// ---------------- K8: middle scan over chunk aggregates; unroll 16 for load ILP ----------------
__global__ __launch_bounds__(256) void k8_mid(const float* __restrict__ Ac, const float* __restrict__ Bc,
                                              float* __restrict__ Hi){
  int idx = blockIdx.x*256 + threadIdx.x;   // (b*128+d)*16+n, 16384 total
  float h = 0.f;
  for (int k0=0;k0<NKCH;k0+=16){
    float av[16], bv[16];
    #pragma unroll
    for (int j=0;j<16;j++){
      size_t o = (size_t)(k0+j)*16384 + idx;
      av[j]=Ac[o]; bv[j]=Bc[o];
    }
    #pragma unroll
    for (int j=0;j<16;j++){
      size_t o = (size_t)(k0+j)*16384 + idx;
      Hi[o] = h;
      h = av[j]*h + bv[j];
    }
  }
}

// ---------------- K9: scan pass2 + fused LN*silu(z) gate -> G ----------------
__global__ __launch_bounds__(128) void k9_scan2(const float* __restrict__ xmc, const float* __restrict__ Bm,
                                                const float* __restrict__ Cm, const float* __restrict__ dtm,
                                                const float* __restrict__ z, const float* __restrict__ wf,
                                                const float* __restrict__ Hi, float* __restrict__ G){
  int k = blockIdx.x & (NKCH-1), b = blockIdx.x >> 7;
  int d = threadIdx.x;
  int l0 = k*CHUNK;
  __shared__ float xs[128*33];      // u, then y in place
  __shared__ float Bl[16*32], Cl[16*32];
  __shared__ float dtl[4*32];
  __shared__ float red[4][32][2];
  __shared__ float mstat[32], rstat[32];
  for (int i = d; i < 4096; i += 128){
    int ch = i >> 5, px = i & 31;
    xs[ch*33+px] = xmc[((size_t)b*128+ch)*NL + l0 + px];
  }
  for (int i = d; i < 512; i += 128){
    int n = i >> 5, li = i & 31;
    Bl[i] = Bm[((size_t)b*16+n)*NL + l0 + li];
    Cl[i] = Cm[((size_t)b*16+n)*NL + l0 + li];
  }
  if (d < 128){
    int n = d >> 5, li = d & 31;
    dtl[d] = dtm[((size_t)b*4+n)*NL + l0 + li];
  }
  float A[16], h[16];
  const float* Af = wf + WF_A + d*16;
  size_t hb = (((size_t)k*NB + b)*128 + d)*16;
  #pragma unroll
  for (int n=0;n<16;n++){ A[n]=Af[n]; h[n]=Hi[hb+n]; }
  float Dv = wf[WF_DP + d];
  float w0 = wf[WF_DTW+d*4], w1 = wf[WF_DTW+d*4+1], w2 = wf[WF_DTW+d*4+2], w3 = wf[WF_DTW+d*4+3];
  float db2 = 2.f*wf[WF_DTB+d];
  __syncthreads();
  for (int l=0; l<CHUNK; l++){
    float tt = w0*dtl[l] + w1*dtl[32+l] + w2*dtl[64+l] + w3*dtl[96+l] + db2;
    float de = tt > 20.f ? tt : __logf(1.f+__expf(tt));
    float uu = xs[d*33+l];
    float du = de * uu;
    float yv = uu * Dv;
    #pragma unroll
    for (int n=0;n<16;n++){
      float a = __expf(de*A[n]);
      h[n] = a*h[n] + du*Bl[n*32+l];
      yv  += h[n]*Cl[n*32+l];
    }
    xs[d*33+l] = yv;    // y overwrites u (row d private to this thread)
  }
  __syncthreads();
  // LayerNorm over d (128) per pixel l
  {
    int px = d & 31, q = d >> 5;
    float s=0.f, qq=0.f;
    #pragma unroll
    for (int j=0;j<32;j++){ float v = xs[(q*32+j)*33+px]; s+=v; qq+=v*v; }
    red[q][px][0]=s; red[q][px][1]=qq;
  }
  __syncthreads();
  if (d < 32){
    float ss = red[0][d][0]+red[1][d][0]+red[2][d][0]+red[3][d][0];
    float sq = red[0][d][1]+red[1][d][1]+red[2][d][1]+red[3][d][1];
    float m = ss*(1.f/128.f);
    mstat[d] = m;
    rstat[d] = rsqrtf(sq*(1.f/128.f) - m*m + 1e-5f);
  }
  __syncthreads();
  float ow = wf[WF_ONW+d], ob = wf[WF_ONB+d];
  const float* zp = z + ((size_t)b*128+d)*NL + l0;
  float* gp = G + ((size_t)b*128+d)*NL + l0;
  #pragma unroll
  for (int l4=0; l4<CHUNK/4; l4++){
    float4 zv4 = ((const float4*)zp)[l4];
    float zv[4] = {zv4.x, zv4.y, zv4.z, zv4.w};
    float out[4];
    #pragma unroll
    for (int j=0;j<4;j++){
      int l = l4*4+j;
      float t = (xs[d*33+l]-mstat[l])*rstat[l]*ow + ob;
      out[j] = t * (zv[j]/(1.f+__expf(-zv[j])));
    }
    ((float4*)gp)[l4] = make_float4(out[0],out[1],out[2],out[3]);
  }
}

// ---------------- K11A: yc = W_comb @ G + cf_b. 2 og x 128 tiles; J=4, P=8; + stats (pinned rolled) ----------------
__global__ __launch_bounds__(256) void k11A_proj(const float* __restrict__ G, const float* __restrict__ wf,
                                                 const float* __restrict__ wcomb,
                                                 float* __restrict__ yc, float* __restrict__ part){
  int og = blockIdx.x >> 7, tile = blockIdx.x & 127;
  int b = tile >> 4, pt = tile & 15;
  int jslot = threadIdx.x >> 5, pxslot = threadIdx.x & 31;
  __shared__ float wlds[32][128];   // 16 KB
  __shared__ float xs[32][256];     // 32 KB
  {
    const float4* Wg = (const float4*)(wcomb + og*32*128);
    float4* Wl = (float4*)&wlds[0][0];
    for (int i = threadIdx.x; i < 1024; i += 256) Wl[i] = Wg[i];
  }
  float acc[4][8];
  #pragma unroll
  for (int j=0;j<4;j++)
    #pragma unroll
    for (int p=0;p<8;p++) acc[j][p]=0.f;
  const float* gbase = G + (size_t)b*128*NL + pt*256;
  for (int ch = 0; ch < 4; ch++){
    __syncthreads();
    for (int i = threadIdx.x; i < 2048; i += 256){
      int r = i >> 6, c4 = i & 63;
      ((float4*)&xs[r][0])[c4] = *(const float4*)(gbase + (size_t)(ch*32+r)*NL + c4*4);
    }
    __syncthreads();
    #pragma unroll 1
    for (int c = 0; c < 32; c++){
      float a[8];
      #pragma unroll
      for (int p=0;p<8;p++) a[p] = xs[c][pxslot + 32*p];
      #pragma unroll
      for (int jj=0;jj<4;jj++){
        float w = wlds[jslot*4+jj][ch*32+c];
        #pragma unroll
        for (int p=0;p<8;p++) acc[jj][p] += w*a[p];
      }
    }
  }
  #pragma unroll
  for (int jj=0;jj<4;jj++){
    int cc = og*32 + jslot*4 + jj;
    float bias = wf[WF_CFB + cc];
    float* dp = yc + (size_t)b*64*NL + (size_t)cc*NL + pt*256;
    float sv = 0.f, qv = 0.f;
    #pragma unroll
    for (int p=0;p<8;p++){
      float t = acc[jj][p] + bias;
      dp[pxslot + 32*p] = t;
      sv += t; qv += t*t;
    }
    #pragma unroll
    for (int o=16;o>0;o>>=1){ sv += __shfl_xor(sv,o); qv += __shfl_xor(qv,o); }
    if (pxslot == 0){
      size_t pidx = (((size_t)b*64 + cc)*16 + pt)*2;
      part[pidx] = sv; part[pidx+1] = qv;
    }
  }
}

// ---------------- K11b: finalize per-(b,c) mean/rsqrt (16 partials each) ----------------
__global__ __launch_bounds__(256) void k11b_stats(const float* __restrict__ part, float* __restrict__ stats){
  int i = blockIdx.x*256 + threadIdx.x;
  if (i >= 512) return;
  float s=0.f, q=0.f;
  #pragma unroll
  for (int t2=0;t2<16;t2++){ s += part[((size_t)i*16+t2)*2]; q += part[((size_t)i*16+t2)*2+1]; }
  float m = s*(1.f/NL), va = q*(1.f/NL) - m*m;
  stats[i*2] = m; stats[i*2+1] = rsqrtf(va+1e-5f);
}

// ---------------- K11c: out = x1 + inorm(yc), write f32 ----------------
__global__ __launch_bounds__(256) void k11c_final(const float* __restrict__ yc, const float* __restrict__ stats,
                                                  const float* __restrict__ x1, float* __restrict__ out){
  int bc = blockIdx.x;
  float m = stats[bc*2], rs = stats[bc*2+1];
  size_t base = (size_t)bc*NL;
  for (int i=threadIdx.x;i<NL;i+=256){
    float v = (yc[base+i]-m)*rs;
    out[base+i] = x1[base+i] + v;
  }
}

// ---------------- host ----------------
extern "C" void kernel_launch(void* const* d_in, const int* in_sizes, int n_in,
                              void* d_out, int out_size, void* d_ws, size_t ws_size,
                              hipStream_t stream) {
  if (ws_size < WS_NEED_FLOATS * sizeof(float)) return;  // insufficient scratch; bail cleanly
  const float* x     = (const float*)d_in[0];
  const float* dw3w  = (const float*)d_in[1];
  const float* dw3b  = (const float*)d_in[2];
  const float* dw5w  = (const float*)d_in[3];
  const float* dw5b  = (const float*)d_in[4];
  const float* dw7w  = (const float*)d_in[5];
  const float* dw7b  = (const float*)d_in[6];
  const float* fusew = (const float*)d_in[7];
  const float* fuseb = (const float*)d_in[8];
  const float* inpjw = (const float*)d_in[9];
  const float* c2w   = (const float*)d_in[10];
  const float* c2b   = (const float*)d_in[11];
  const float* xpw   = (const float*)d_in[12];
  const float* dtw   = (const float*)d_in[13];
  const float* dtb   = (const float*)d_in[14];
  const float* alog  = (const float*)d_in[15];
  const float* dpv   = (const float*)d_in[16];
  const float* onw   = (const float*)d_in[17];
  const float* onb   = (const float*)d_in[18];
  const float* opw   = (const float*)d_in[19];
  const float* cfw   = (const float*)d_in[20];
  const float* cfb   = (const float*)d_in[21];

  float* ws    = (float*)d_ws;
  float* wf    = ws + OFF_WF;
  float* wcomb = ws + OFF_WCOMB;
  float* feats = ws + OFF_FEATS;
  float* nstat = ws + OFF_NSTAT;
  float* xf    = ws + OFF_XF;
  float* x1    = ws + OFF_X1;
  float* xmraw = ws + OFF_XMRAW;
  float* z     = ws + OFF_Z;
  float* xmc   = ws + OFF_XMC;
  float* Bmw   = ws + OFF_BMAT;
  float* Cmw   = ws + OFF_CMAT;
  float* dtm   = ws + OFF_DTM;
  float* Acb   = ws + OFF_AC;
  float* Bcb   = ws + OFF_BC;
  float* Hi    = ws + OFF_HINIT;
  float* G     = ws + OFF_G;
  float* yc    = ws + OFF_YC;
  float* part  = ws + OFF_PART;
  float* stats = ws + OFF_STATS;

  CvtArgs ca; int ns = 0;
  auto add = [&](const float* s, int off, int n, int op){
    ca.d[ns].src = s; ca.d[ns].dst = wf + off; ca.d[ns].n = n; ca.d[ns].op = op; ns++;
  };
  add(dw3w, WF_DW3, 576, 0);   add(dw5w, WF_DW5, 1600, 0);  add(dw7w, WF_DW7, 3136, 0);
  add(dw3b, WF_B3, 64, 0);     add(dw5b, WF_B5, 64, 0);     add(dw7b, WF_B7, 64, 0);
  add(fusew, WF_FUSE, 12288, 0); add(fuseb, WF_FUSEB, 64, 0);
  add(c2w, WF_C2W, 1152, 0);   add(c2b, WF_C2B, 128, 0);
  add(xpw, WF_XPW, 4608, 0);   add(dtw, WF_DTW, 512, 0);    add(dtb, WF_DTB, 128, 0);
  add(alog, WF_A, 2048, 1);    // A = -exp(A_log)
  add(dpv, WF_DP, 128, 0);
  add(onw, WF_ONW, 128, 0);    add(onb, WF_ONB, 128, 0);
  add(opw, WF_OPW, 8192, 0);
  add(cfw, WF_CFW, 4096, 0);   add(cfb, WF_CFB, 64, 0);
  add(inpjw, WF_INPJ, 16384, 0);
  ca.ncvt = ns; ca.cfw = cfw; ca.opw = opw; ca.wcomb = wcomb;

  k0_cvt<<<ns + 32, 256, 0, stream>>>(ca);
  k1_dw<<<512, 256, 0, stream>>>(x, wf, feats, nstat);
  k2_fuse<<<256, 256, 0, stream>>>(feats, nstat, wf, xf);
  k3_norm<<<512, 256, 0, stream>>>(xf, x, x1);
  k4_inproj<<<512, 256, 0, stream>>>(x1, wf, xmraw, z);
  k5_dw3<<<1024, 256, 0, stream>>>(xmraw, wf, xmc);
  k6_xproj<<<256, 256, 0, stream>>>(xmc, wf, Bmw, Cmw, dtm);
  k7_scan1<<<1024, 128, 0, stream>>>(xmc, Bmw, dtm, wf, Acb, Bcb);
  k8_mid<<<64, 256, 0, stream>>>(Acb, Bcb, Hi);
  k9_scan2<<<1024, 128, 0, stream>>>(xmc, Bmw, Cmw, dtm, z, wf, Hi, G);
  k11A_proj<<<256, 256, 0, stream>>>(G, wf, wcomb, yc, part);
  k11b_stats<<<2, 256, 0, stream>>>(part, stats);
  k11c_final<<<512, 256, 0, stream>>>(yc, stats, x1, (float*)d_out);
}

// Round 10
// 219.529 us; speedup vs baseline: 3.1025x; 1.0734x over previous
//
#include <hip/hip_runtime.h>
#include <math.h>

#define NB 8
#define NC 64
#define NL 4096
#define NDI 128
#define NN 16
#define CHUNK 32
#define NKCH 128   // NL / CHUNK

// ---------------- workspace layout (float offsets) ----------------
#define OFF_FEATS 0ull          // 6291456 (dead after K2 -> reused by AC/BC/HINIT)
#define OFF_AC    0ull          // 2097152
#define OFF_BC    2097152ull    // 2097152
#define OFF_HINIT 4194304ull    // 2097152
#define OFF_XF    6291456ull    // 2097152 (dead after K3 -> reused by BMAT/CMAT)
#define OFF_BMAT  6291456ull    // 524288
#define OFF_CMAT  6815744ull    // 524288
#define OFF_X1    8388608ull    // 2097152 (live to the end)
#define OFF_XMRAW 10485760ull   // 4194304 (dead after K5 -> reused by G)
#define OFF_G     10485760ull   // 4194304
#define OFF_Z     14680064ull   // 4194304 (z dead after K9 -> low half reused by YC)
#define OFF_YC    14680064ull   // 2097152
#define OFF_PART  16777216ull   // 32768
#define OFF_STATS 16809984ull   // 1024
#define OFF_XMC   18874368ull   // 4194304
#define OFF_DTM   23068672ull   // 131072
#define OFF_WF    27262976ull   // 55552 f32 weights
#define OFF_NSTAT (OFF_WF + 55552ull)   // 3072
#define OFF_WCOMB (OFF_WF + 58624ull)   // 8192 (cf_w @ op_w)
#define WS_NEED_FLOATS (OFF_WF + 66816ull)

// weight sub-offsets inside WF (floats)
#define WF_DW3    0
#define WF_DW5    576
#define WF_DW7    2176
#define WF_B3     5312
#define WF_B5     5376
#define WF_B7     5440
#define WF_FUSE   5504
#define WF_FUSEB  17792
#define WF_C2W    17856
#define WF_C2B    19008
#define WF_XPW    19136
#define WF_DTW    23744
#define WF_DTB    24256
#define WF_A      24384
#define WF_DP     26432
#define WF_ONW    26560
#define WF_ONB    26688
#define WF_OPW    26816
#define WF_CFW    35008
#define WF_CFB    39104
#define WF_INPJ   39168

// ---------------- K0: weights->f32 (A = -exp(A_log)); tail blocks compute W_comb ----------------
struct Cvt { const float* src; float* dst; int n; int op; };
struct CvtArgs { Cvt d[22]; int ncvt; const float* cfw; const float* opw; float* wcomb; };

__global__ __launch_bounds__(256) void k0_cvt(CvtArgs a){
  if ((int)blockIdx.x < a.ncvt){
    Cvt c = a.d[blockIdx.x];
    for (int i = threadIdx.x; i < c.n; i += 256){
      float v = c.src[i];
      c.dst[i] = c.op ? -expf(v) : v;
    }
  } else {
    int idx = (blockIdx.x - a.ncvt)*256 + threadIdx.x;   // 8192 outputs
    int c = idx >> 7, kk = idx & 127;
    float s = 0.f;
    #pragma unroll
    for (int j=0;j<64;j++) s += a.cfw[c*64+j] * a.opw[j*128+kk];
    a.wcomb[idx] = s;
  }
}

// ---------------- K1: 3 depthwise convs (3/5/7) raw + per-plane stats (stride 73: bank-safe) ----------------
__global__ __launch_bounds__(256) void k1_dw(const float* __restrict__ x, const float* __restrict__ wf,
                                             float* __restrict__ feats, float* __restrict__ nstat){
  const int b = blockIdx.x >> 6, c = blockIdx.x & 63;
  const int tid = threadIdx.x;
  __shared__ float xs[70*73];          // zero-padded (3 each side), row stride 73 (odd: 2-way max)
  __shared__ float red[4][6];
  for (int i = tid; i < 70*73; i += 256) xs[i] = 0.f;
  __syncthreads();
  const float* xp = x + (size_t)blockIdx.x * NL;
  for (int i = tid; i < NL; i += 256){
    int h = i >> 6, w = i & 63;
    xs[(h+3)*73 + (w+3)] = xp[i];
  }
  float w3r[9], w5r[25], w7r[49];
  #pragma unroll
  for (int i=0;i<9;i++)  w3r[i] = wf[WF_DW3 + c*9 + i];
  #pragma unroll
  for (int i=0;i<25;i++) w5r[i] = wf[WF_DW5 + c*25 + i];
  #pragma unroll
  for (int i=0;i<49;i++) w7r[i] = wf[WF_DW7 + c*49 + i];
  float b3 = wf[WF_B3+c], b5 = wf[WF_B5+c], b7 = wf[WF_B7+c];
  __syncthreads();
  float s3=0,q3=0,s5=0,q5=0,s7=0,q7=0;
  float* f3 = feats + ((size_t)b*192 + c) * NL;
  float* f5 = f3 + (size_t)64*NL;
  float* f7 = f3 + (size_t)128*NL;
  #pragma unroll
  for (int g=0; g<4; g++){
    int p = g*1024 + tid*4;
    int h = p >> 6, w0 = p & 63;
    float a3[4], a5[4], a7[4];
    #pragma unroll
    for (int i=0;i<4;i++){ a3[i]=b3; a5[i]=b5; a7[i]=b7; }
    #pragma unroll
    for (int dy=0; dy<7; dy++){
      float s[10];
      #pragma unroll
      for (int j=0;j<10;j++) s[j] = xs[(h+dy)*73 + w0 + j];
      #pragma unroll
      for (int dx=0;dx<7;dx++){
        float wv = w7r[dy*7+dx];
        #pragma unroll
        for (int i=0;i<4;i++) a7[i] += s[dx+i]*wv;
      }
      if (dy>=1 && dy<=5){
        #pragma unroll
        for (int dx=0;dx<5;dx++){
          float wv = w5r[(dy-1)*5+dx];
          #pragma unroll
          for (int i=0;i<4;i++) a5[i] += s[dx+1+i]*wv;
        }
      }
      if (dy>=2 && dy<=4){
        #pragma unroll
        for (int dx=0;dx<3;dx++){
          float wv = w3r[(dy-2)*3+dx];
          #pragma unroll
          for (int i=0;i<4;i++) a3[i] += s[dx+2+i]*wv;
        }
      }
    }
    *(float4*)(f3+p) = make_float4(a3[0],a3[1],a3[2],a3[3]);
    *(float4*)(f5+p) = make_float4(a5[0],a5[1],a5[2],a5[3]);
    *(float4*)(f7+p) = make_float4(a7[0],a7[1],a7[2],a7[3]);
    #pragma unroll
    for (int i=0;i<4;i++){
      s3+=a3[i]; q3+=a3[i]*a3[i];
      s5+=a5[i]; q5+=a5[i]*a5[i];
      s7+=a7[i]; q7+=a7[i]*a7[i];
    }
  }
  int wid = tid>>6, lane = tid&63;
  float v6[6]={s3,q3,s5,q5,s7,q7};
  #pragma unroll
  for (int j=0;j<6;j++){
    float t = v6[j];
    #pragma unroll
    for (int o=32;o>0;o>>=1) t += __shfl_down(t,o);
    if (!lane) red[wid][j]=t;
  }
  __syncthreads();
  if (tid < 3){
    float su = red[0][tid*2]+red[1][tid*2]+red[2][tid*2]+red[3][tid*2];
    float sq = red[0][tid*2+1]+red[1][tid*2+1]+red[2][tid*2+1]+red[3][tid*2+1];
    float m  = su*(1.f/NL);
    float va = sq*(1.f/NL) - m*m;
    int k = b*192 + tid*64 + c;
    nstat[k*2]   = m;
    nstat[k*2+1] = rsqrtf(va + 1e-5f);
  }
}

// ---------------- K2: fuse 1x1 (192->64). og2 x b8 x pt32 = 512 blocks; J=4, P=4; 41.5KB LDS ----------------
__global__ __launch_bounds__(256) void k2_fuse(const float* __restrict__ feats, const float* __restrict__ nstat,
                                               const float* __restrict__ wf, float* __restrict__ xf){
  int og = blockIdx.x >> 8, rem = blockIdx.x & 255;
  int b = rem >> 5, pt = rem & 31;
  int jslot = threadIdx.x >> 5, pxslot = threadIdx.x & 31;
  __shared__ float wlds[32][192];   // 24 KB
  __shared__ float xs[32][128];     // 16 KB
  __shared__ float msl[192], rsl[192];
  for (int i = threadIdx.x; i < 192; i += 256){
    msl[i] = nstat[(b*192+i)*2];
    rsl[i] = nstat[(b*192+i)*2+1];
  }
  {
    const float4* Wg = (const float4*)(wf + WF_FUSE + og*32*192);
    float4* Wl = (float4*)&wlds[0][0];
    for (int i = threadIdx.x; i < 1536; i += 256) Wl[i] = Wg[i];
  }
  float acc[4][4];
  #pragma unroll
  for (int j=0;j<4;j++)
    #pragma unroll
    for (int p=0;p<4;p++) acc[j][p]=0.f;
  const float* fbase = feats + (size_t)b*192*NL + pt*128;
  for (int ch = 0; ch < 6; ch++){
    __syncthreads();
    for (int i = threadIdx.x; i < 1024; i += 256){
      int r = i >> 5, c4 = i & 31;
      int k = ch*32 + r;
      float4 f = *(const float4*)(fbase + (size_t)k*NL + c4*4);
      float m = msl[k], rs = rsl[k];
      float v0=(f.x-m)*rs, v1=(f.y-m)*rs, v2=(f.z-m)*rs, v3=(f.w-m)*rs;
      v0 = v0>0.f?v0:0.01f*v0; v1 = v1>0.f?v1:0.01f*v1;
      v2 = v2>0.f?v2:0.01f*v2; v3 = v3>0.f?v3:0.01f*v3;
      ((float4*)&xs[r][0])[c4] = make_float4(v0,v1,v2,v3);
    }
    __syncthreads();
    #pragma unroll 1
    for (int c = 0; c < 32; c++){
      float a[4];
      #pragma unroll
      for (int p=0;p<4;p++) a[p] = xs[c][pxslot + 32*p];
      #pragma unroll
      for (int jj=0;jj<4;jj++){
        float w = wlds[jslot*4+jj][ch*32+c];
        #pragma unroll
        for (int p=0;p<4;p++) acc[jj][p] += w*a[p];
      }
    }
  }
  #pragma unroll
  for (int jj=0;jj<4;jj++){
    int o = og*32 + jslot*4 + jj;
    float bias = wf[WF_FUSEB + o];
    float* dp = xf + (size_t)b*64*NL + (size_t)o*NL + pt*128;
    #pragma unroll
    for (int p=0;p<4;p++) dp[pxslot + 32*p] = acc[jj][p] + bias;
  }
}

// ---------------- K3: inorm(xf)+lrelu + x -> x1 ----------------
__global__ __launch_bounds__(256) void k3_norm(const float* __restrict__ xf, const float* __restrict__ x,
                                               float* __restrict__ x1){
  const int tid = threadIdx.x;
  const size_t base = (size_t)blockIdx.x * NL;
  float loc[16]; float s=0.f, q=0.f;
  #pragma unroll
  for (int i=0;i<16;i++){ float v = xf[base + tid + i*256]; loc[i]=v; s+=v; q+=v*v; }
  __shared__ float red[4][2];
  int wid = tid>>6, lane = tid&63;
  #pragma unroll
  for (int o=32;o>0;o>>=1){ s += __shfl_down(s,o); q += __shfl_down(q,o); }
  if (!lane){ red[wid][0]=s; red[wid][1]=q; }
  __syncthreads();
  s = red[0][0]+red[1][0]+red[2][0]+red[3][0];
  q = red[0][1]+red[1][1]+red[2][1]+red[3][1];
  float m = s*(1.f/NL), va = q*(1.f/NL)-m*m, rs = rsqrtf(va+1e-5f);
  #pragma unroll
  for (int i=0;i<16;i++){
    int idx = tid + i*256;
    float v = (loc[i]-m)*rs;
    v = v>0.f ? v : 0.01f*v;
    x1[base+idx] = v + x[base+idx];
  }
}

// ---------------- K4: in_proj (64->256). og4 x b8 x pt32 = 1024 blocks; J=8, P=4; 32KB LDS ----------------
__global__ __launch_bounds__(256) void k4_inproj(const float* __restrict__ x1, const float* __restrict__ wf,
                                                 float* __restrict__ xmraw, float* __restrict__ z){
  int og = blockIdx.x >> 8, rem = blockIdx.x & 255;
  int b = rem >> 5, pt = rem & 31;
  int jslot = threadIdx.x >> 5, pxslot = threadIdx.x & 31;
  __shared__ float wlds[64][64];    // 16 KB
  __shared__ float xs[32][128];     // 16 KB
  {
    const float4* Wg = (const float4*)(wf + WF_INPJ + og*64*64);
    float4* Wl = (float4*)&wlds[0][0];
    for (int i = threadIdx.x; i < 1024; i += 256) Wl[i] = Wg[i];
  }
  float acc[8][4];
  #pragma unroll
  for (int j=0;j<8;j++)
    #pragma unroll
    for (int p=0;p<4;p++) acc[j][p]=0.f;
  const float* xbase = x1 + (size_t)b*64*NL + pt*128;
  for (int ch = 0; ch < 2; ch++){
    __syncthreads();
    for (int i = threadIdx.x; i < 1024; i += 256){
      int r = i >> 5, c4 = i & 31;
      ((float4*)&xs[r][0])[c4] = *(const float4*)(xbase + (size_t)(ch*32+r)*NL + c4*4);
    }
    __syncthreads();
    #pragma unroll 1
    for (int c = 0; c < 32; c++){
      float a[4];
      #pragma unroll
      for (int p=0;p<4;p++) a[p] = xs[c][pxslot + 32*p];
      #pragma unroll
      for (int jj=0;jj<8;jj++){
        float w = wlds[jslot*8+jj][ch*32+c];
        #pragma unroll
        for (int p=0;p<4;p++) acc[jj][p] += w*a[p];
      }
    }
  }
  float* dstbase = (og < 2 ? xmraw + (size_t)b*128*NL + (size_t)(og*64)*NL
                           : z     + (size_t)b*128*NL + (size_t)((og-2)*64)*NL) + pt*128;
  #pragma unroll
  for (int jj=0;jj<8;jj++){
    float* dp = dstbase + (size_t)(jslot*8+jj)*NL;
    #pragma unroll
    for (int p=0;p<4;p++) dp[pxslot + 32*p] = acc[jj][p];
  }
}

// ---------------- K5: depthwise 3x3 + silu (stride 69: bank-safe) ----------------
__global__ __launch_bounds__(256) void k5_dw3(const float* __restrict__ xmraw, const float* __restrict__ wf,
                                              float* __restrict__ xmc){
  const int d = blockIdx.x & 127;
  const int tid = threadIdx.x;
  __shared__ float xs[66*69];
  for (int i=tid;i<66*69;i+=256) xs[i]=0.f;
  __syncthreads();
  const float* xp = xmraw + (size_t)blockIdx.x * NL;
  for (int i=tid;i<NL;i+=256){ int h=i>>6, w=i&63; xs[(h+1)*69 + (w+1)] = xp[i]; }
  float wr[9];
  #pragma unroll
  for (int i=0;i<9;i++) wr[i] = wf[WF_C2W + d*9 + i];
  float bb = wf[WF_C2B + d];
  __syncthreads();
  float* op = xmc + (size_t)blockIdx.x * NL;
  #pragma unroll
  for (int g=0; g<4; g++){
    int p = g*1024 + tid*4;
    int h = p>>6, w0 = p&63;
    float a[4];
    #pragma unroll
    for (int i=0;i<4;i++) a[i]=bb;
    #pragma unroll
    for (int dy=0; dy<3; dy++){
      float s[6];
      #pragma unroll
      for (int j=0;j<6;j++) s[j] = xs[(h+dy)*69 + w0 + j];
      #pragma unroll
      for (int dx=0;dx<3;dx++){
        float wv = wr[dy*3+dx];
        #pragma unroll
        for (int i=0;i<4;i++) a[i] += s[dx+i]*wv;
      }
    }
    float4 o;
    o.x = a[0]/(1.f+__expf(-a[0]));
    o.y = a[1]/(1.f+__expf(-a[1]));
    o.z = a[2]/(1.f+__expf(-a[2]));
    o.w = a[3]/(1.f+__expf(-a[3]));
    *(float4*)(op+p) = o;
  }
}

// ---------------- K6 (slim): x_proj (128->36); grid 256; J=9, P=2; c-loop pinned rolled ----------------
__global__ __launch_bounds__(256) void k6_xproj(const float* __restrict__ xmc, const float* __restrict__ wf,
                                                float* __restrict__ Bm, float* __restrict__ Cm,
                                                float* __restrict__ dtm){
  int b = blockIdx.x >> 5, pt = blockIdx.x & 31;       // 128-px tiles
  int jslot = threadIdx.x >> 6, pxslot = threadIdx.x & 63;
  __shared__ float wlds[36][128];   // 18 KB
  __shared__ float xs[32][128];     // 16 KB
  {
    const float4* Wg = (const float4*)(wf + WF_XPW);
    float4* Wl = (float4*)&wlds[0][0];
    for (int i = threadIdx.x; i < 1152; i += 256) Wl[i] = Wg[i];
  }
  float acc[9][2];
  #pragma unroll
  for (int j=0;j<9;j++){ acc[j][0]=0.f; acc[j][1]=0.f; }
  const float* ubase = xmc + (size_t)b*128*NL + pt*128;
  for (int ch = 0; ch < 4; ch++){
    __syncthreads();
    for (int i = threadIdx.x; i < 1024; i += 256){
      int r = i >> 5, c4 = i & 31;
      ((float4*)&xs[r][0])[c4] = *(const float4*)(ubase + (size_t)(ch*32+r)*NL + c4*4);
    }
    __syncthreads();
    #pragma unroll 1
    for (int c = 0; c < 32; c++){
      float a0 = xs[c][pxslot];
      float a1 = xs[c][pxslot + 64];
      #pragma unroll
      for (int j=0;j<9;j++){
        float w = wlds[jslot*9+j][ch*32+c];
        acc[j][0] += w*a0;
        acc[j][1] += w*a1;
      }
    }
  }
  #pragma unroll
  for (int j=0;j<9;j++){
    int o = jslot*9 + j;
    float* dp;
    if (o < 4)       dp = dtm + ((size_t)b*4 + o)*NL;
    else if (o < 20) dp = Bm  + ((size_t)b*16 + (o-4))*NL;
    else             dp = Cm  + ((size_t)b*16 + (o-20))*NL;
    dp[pt*128 + pxslot]      = acc[j][0];
    dp[pt*128 + pxslot + 64] = acc[j][1];
  }
}

// ---------------- K7: scan pass1 — stage u/B/dt in LDS, delta on the fly ----------------
__global__ __launch_bounds__(128) void k7_scan1(const float* __restrict__ xmc, const float* __restrict__ Bm,
                                                const float* __restrict__ dtm, const float* __restrict__ wf,
                                                float* __restrict__ Ac, float* __restrict__ Bc){
  int k = blockIdx.x & (NKCH-1), b = blockIdx.x >> 7;
  int d = threadIdx.x;
  int l0 = k*CHUNK;
  __shared__ float xs[128*33];      // u, padded
  __shared__ float Bl[16*32];
  __shared__ float dtl[4*32];
  for (int i = d; i < 4096; i += 128){
    int ch = i >> 5, px = i & 31;
    xs[ch*33+px] = xmc[((size_t)b*128+ch)*NL + l0 + px];
  }
  for (int i = d; i < 512; i += 128){
    int n = i >> 5, li = i & 31;
    Bl[i] = Bm[((size_t)b*16+n)*NL + l0 + li];
  }
  if (d < 128){
    int n = d >> 5, li = d & 31;
    dtl[d] = dtm[((size_t)b*4+n)*NL + l0 + li];
  }
  float A[16], P[16], Q[16];
  const float* Af = wf + WF_A + d*16;
  #pragma unroll
  for (int n=0;n<16;n++){ A[n]=Af[n]; P[n]=1.f; Q[n]=0.f; }
  float w0 = wf[WF_DTW+d*4], w1 = wf[WF_DTW+d*4+1], w2 = wf[WF_DTW+d*4+2], w3 = wf[WF_DTW+d*4+3];
  float db2 = 2.f*wf[WF_DTB+d];
  __syncthreads();
  for (int l=0; l<CHUNK; l++){
    float tt = w0*dtl[l] + w1*dtl[32+l] + w2*dtl[64+l] + w3*dtl[96+l] + db2;
    float de = tt > 20.f ? tt : __logf(1.f+__expf(tt));   // softplus (double bias, faithful)
    float du = de * xs[d*33+l];
    #pragma unroll
    for (int n=0;n<16;n++){
      float a = __expf(de*A[n]);
      P[n] *= a;
      Q[n] = a*Q[n] + du*Bl[n*32+l];
    }
  }
  size_t base = (((size_t)k*NB + b)*128 + d)*16;
  #pragma unroll
  for (int i=0;i<4;i++){
    ((float4*)(Ac+base))[i] = make_float4(P[i*4],P[i*4+1],P[i*4+2],P[i*4+3]);
    ((float4*)(Bc+base))[i] = make_float4(Q[i*4],Q[i*4+1],Q[i*4+2],Q[i*4+3]);
  }
}

// ---------------- K8: middle scan over chunk aggregates; unroll 16 for load ILP ----------------
__global__ __launch_bounds__(256) void k8_mid(const float* __restrict__ Ac, const float* __restrict__ Bc,
                                              float* __restrict__ Hi){
  int idx = blockIdx.x*256 + threadIdx.x;   // (b*128+d)*16+n, 16384 total
  float h = 0.f;
  for (int k0=0;k0<NKCH;k0+=16){
    float av[16], bv[16];
    #pragma unroll
    for (int j=0;j<16;j++){
      size_t o = (size_t)(k0+j)*16384 + idx;
      av[j]=Ac[o]; bv[j]=Bc[o];
    }
    #pragma unroll
    for (int j=0;j<16;j++){
      size_t o = (size_t)(k0+j)*16384 + idx;
      Hi[o] = h;
      h = av[j]*h + bv[j];
    }
  }
}

// ---------------- K9: scan pass2 + fused LN*silu(z) gate -> G ----------------
__global__ __launch_bounds__(128) void k9_scan2(const float* __restrict__ xmc, const float* __restrict__ Bm,
                                                const float* __restrict__ Cm, const float* __restrict__ dtm,
                                                const float* __restrict__ z, const float* __restrict__ wf,
                                                const float* __restrict__ Hi, float* __restrict__ G){
  int k = blockIdx.x & (NKCH-1), b = blockIdx.x >> 7;
  int d = threadIdx.x;
  int l0 = k*CHUNK;
  __shared__ float xs[128*33];      // u, then y in place
  __shared__ float Bl[16*32], Cl[16*32];
  __shared__ float dtl[4*32];
  __shared__ float red[4][32][2];
  __shared__ float mstat[32], rstat[32];
  for (int i = d; i < 4096; i += 128){
    int ch = i >> 5, px = i & 31;
    xs[ch*33+px] = xmc[((size_t)b*128+ch)*NL + l0 + px];
  }
  for (int i = d; i < 512; i += 128){
    int n = i >> 5, li = i & 31;
    Bl[i] = Bm[((size_t)b*16+n)*NL + l0 + li];
    Cl[i] = Cm[((size_t)b*16+n)*NL + l0 + li];
  }
  if (d < 128){
    int n = d >> 5, li = d & 31;
    dtl[d] = dtm[((size_t)b*4+n)*NL + l0 + li];
  }
  float A[16], h[16];
  const float* Af = wf + WF_A + d*16;
  size_t hb = (((size_t)k*NB + b)*128 + d)*16;
  #pragma unroll
  for (int n=0;n<16;n++){ A[n]=Af[n]; h[n]=Hi[hb+n]; }
  float Dv = wf[WF_DP + d];
  float w0 = wf[WF_DTW+d*4], w1 = wf[WF_DTW+d*4+1], w2 = wf[WF_DTW+d*4+2], w3 = wf[WF_DTW+d*4+3];
  float db2 = 2.f*wf[WF_DTB+d];
  __syncthreads();
  for (int l=0; l<CHUNK; l++){
    float tt = w0*dtl[l] + w1*dtl[32+l] + w2*dtl[64+l] + w3*dtl[96+l] + db2;
    float de = tt > 20.f ? tt : __logf(1.f+__expf(tt));
    float uu = xs[d*33+l];
    float du = de * uu;
    float yv = uu * Dv;
    #pragma unroll
    for (int n=0;n<16;n++){
      float a = __expf(de*A[n]);
      h[n] = a*h[n] + du*Bl[n*32+l];
      yv  += h[n]*Cl[n*32+l];
    }
    xs[d*33+l] = yv;    // y overwrites u (row d private to this thread)
  }
  __syncthreads();
  // LayerNorm over d (128) per pixel l
  {
    int px = d & 31, q = d >> 5;
    float s=0.f, qq=0.f;
    #pragma unroll
    for (int j=0;j<32;j++){ float v = xs[(q*32+j)*33+px]; s+=v; qq+=v*v; }
    red[q][px][0]=s; red[q][px][1]=qq;
  }
  __syncthreads();
  if (d < 32){
    float ss = red[0][d][0]+red[1][d][0]+red[2][d][0]+red[3][d][0];
    float sq = red[0][d][1]+red[1][d][1]+red[2][d][1]+red[3][d][1];
    float m = ss*(1.f/128.f);
    mstat[d] = m;
    rstat[d] = rsqrtf(sq*(1.f/128.f) - m*m + 1e-5f);
  }
  __syncthreads();
  float ow = wf[WF_ONW+d], ob = wf[WF_ONB+d];
  const float* zp = z + ((size_t)b*128+d)*NL + l0;
  float* gp = G + ((size_t)b*128+d)*NL + l0;
  #pragma unroll
  for (int l4=0; l4<CHUNK/4; l4++){
    float4 zv4 = ((const float4*)zp)[l4];
    float zv[4] = {zv4.x, zv4.y, zv4.z, zv4.w};
    float out[4];
    #pragma unroll
    for (int j=0;j<4;j++){
      int l = l4*4+j;
      float t = (xs[d*33+l]-mstat[l])*rstat[l]*ow + ob;
      out[j] = t * (zv[j]/(1.f+__expf(-zv[j])));
    }
    ((float4*)gp)[l4] = make_float4(out[0],out[1],out[2],out[3]);
  }
}

// ---------------- K11A: yc = W_comb @ G + cf_b. og2 x b8 x pt32 = 512; J=4, P=4; 32KB LDS ----------------
__global__ __launch_bounds__(256) void k11A_proj(const float* __restrict__ G, const float* __restrict__ wf,
                                                 const float* __restrict__ wcomb,
                                                 float* __restrict__ yc, float* __restrict__ part){
  int og = blockIdx.x >> 8, rem = blockIdx.x & 255;
  int b = rem >> 5, pt = rem & 31;
  int jslot = threadIdx.x >> 5, pxslot = threadIdx.x & 31;
  __shared__ float wlds[32][128];   // 16 KB
  __shared__ float xs[32][128];     // 16 KB
  {
    const float4* Wg = (const float4*)(wcomb + og*32*128);
    float4* Wl = (float4*)&wlds[0][0];
    for (int i = threadIdx.x; i < 1024; i += 256) Wl[i] = Wg[i];
  }
  float acc[4][4];
  #pragma unroll
  for (int j=0;j<4;j++)
    #pragma unroll
    for (int p=0;p<4;p++) acc[j][p]=0.f;
  const float* gbase = G + (size_t)b*128*NL + pt*128;
  for (int ch = 0; ch < 4; ch++){
    __syncthreads();
    for (int i = threadIdx.x; i < 1024; i += 256){
      int r = i >> 5, c4 = i & 31;
      ((float4*)&xs[r][0])[c4] = *(const float4*)(gbase + (size_t)(ch*32+r)*NL + c4*4);
    }
    __syncthreads();
    #pragma unroll 1
    for (int c = 0; c < 32; c++){
      float a[4];
      #pragma unroll
      for (int p=0;p<4;p++) a[p] = xs[c][pxslot + 32*p];
      #pragma unroll
      for (int jj=0;jj<4;jj++){
        float w = wlds[jslot*4+jj][ch*32+c];
        #pragma unroll
        for (int p=0;p<4;p++) acc[jj][p] += w*a[p];
      }
    }
  }
  #pragma unroll
  for (int jj=0;jj<4;jj++){
    int cc = og*32 + jslot*4 + jj;
    float bias = wf[WF_CFB + cc];
    float* dp = yc + (size_t)b*64*NL + (size_t)cc*NL + pt*128;
    float sv = 0.f, qv = 0.f;
    #pragma unroll
    for (int p=0;p<4;p++){
      float t = acc[jj][p] + bias;
      dp[pxslot + 32*p] = t;
      sv += t; qv += t*t;
    }
    #pragma unroll
    for (int o=16;o>0;o>>=1){ sv += __shfl_xor(sv,o); qv += __shfl_xor(qv,o); }
    if (pxslot == 0){
      size_t pidx = (((size_t)b*64 + cc)*32 + pt)*2;
      part[pidx] = sv; part[pidx+1] = qv;
    }
  }
}

// ---------------- K11b: finalize per-(b,c) mean/rsqrt (32 partials each) ----------------
__global__ __launch_bounds__(256) void k11b_stats(const float* __restrict__ part, float* __restrict__ stats){
  int i = blockIdx.x*256 + threadIdx.x;
  if (i >= 512) return;
  float s=0.f, q=0.f;
  #pragma unroll
  for (int t2=0;t2<32;t2++){ s += part[((size_t)i*32+t2)*2]; q += part[((size_t)i*32+t2)*2+1]; }
  float m = s*(1.f/NL), va = q*(1.f/NL) - m*m;
  stats[i*2] = m; stats[i*2+1] = rsqrtf(va+1e-5f);
}

// ---------------- K11c: out = x1 + inorm(yc), write f32 ----------------
__global__ __launch_bounds__(256) void k11c_final(const float* __restrict__ yc, const float* __restrict__ stats,
                                                  const float* __restrict__ x1, float* __restrict__ out){
  int bc = blockIdx.x;
  float m = stats[bc*2], rs = stats[bc*2+1];
  size_t base = (size_t)bc*NL;
  for (int i=threadIdx.x;i<NL;i+=256){
    float v = (yc[base+i]-m)*rs;
    out[base+i] = x1[base+i] + v;
  }
}

// ---------------- host ----------------
extern "C" void kernel_launch(void* const* d_in, const int* in_sizes, int n_in,
                              void* d_out, int out_size, void* d_ws, size_t ws_size,
                              hipStream_t stream) {
  if (ws_size < WS_NEED_FLOATS * sizeof(float)) return;  // insufficient scratch; bail cleanly
  const float* x     = (const float*)d_in[0];
  const float* dw3w  = (const float*)d_in[1];
  const float* dw3b  = (const float*)d_in[2];
  const float* dw5w  = (const float*)d_in[3];
  const float* dw5b  = (const float*)d_in[4];
  const float* dw7w  = (const float*)d_in[5];
  const float* dw7b  = (const float*)d_in[6];
  const float* fusew = (const float*)d_in[7];
  const float* fuseb = (const float*)d_in[8];
  const float* inpjw = (const float*)d_in[9];
  const float* c2w   = (const float*)d_in[10];
  const float* c2b   = (const float*)d_in[11];
  const float* xpw   = (const float*)d_in[12];
  const float* dtw   = (const float*)d_in[13];
  const float* dtb   = (const float*)d_in[14];
  const float* alog  = (const float*)d_in[15];
  const float* dpv   = (const float*)d_in[16];
  const float* onw   = (const float*)d_in[17];
  const float* onb   = (const float*)d_in[18];
  const float* opw   = (const float*)d_in[19];
  const float* cfw   = (const float*)d_in[20];
  const float* cfb   = (const float*)d_in[21];

  float* ws    = (float*)d_ws;
  float* wf    = ws + OFF_WF;
  float* wcomb = ws + OFF_WCOMB;
  float* feats = ws + OFF_FEATS;
  float* nstat = ws + OFF_NSTAT;
  float* xf    = ws + OFF_XF;
  float* x1    = ws + OFF_X1;
  float* xmraw = ws + OFF_XMRAW;
  float* z     = ws + OFF_Z;
  float* xmc   = ws + OFF_XMC;
  float* Bmw   = ws + OFF_BMAT;
  float* Cmw   = ws + OFF_CMAT;
  float* dtm   = ws + OFF_DTM;
  float* Acb   = ws + OFF_AC;
  float* Bcb   = ws + OFF_BC;
  float* Hi    = ws + OFF_HINIT;
  float* G     = ws + OFF_G;
  float* yc    = ws + OFF_YC;
  float* part  = ws + OFF_PART;
  float* stats = ws + OFF_STATS;

  CvtArgs ca; int ns = 0;
  auto add = [&](const float* s, int off, int n, int op){
    ca.d[ns].src = s; ca.d[ns].dst = wf + off; ca.d[ns].n = n; ca.d[ns].op = op; ns++;
  };
  add(dw3w, WF_DW3, 576, 0);   add(dw5w, WF_DW5, 1600, 0);  add(dw7w, WF_DW7, 3136, 0);
  add(dw3b, WF_B3, 64, 0);     add(dw5b, WF_B5, 64, 0);     add(dw7b, WF_B7, 64, 0);
  add(fusew, WF_FUSE, 12288, 0); add(fuseb, WF_FUSEB, 64, 0);
  add(c2w, WF_C2W, 1152, 0);   add(c2b, WF_C2B, 128, 0);
  add(xpw, WF_XPW, 4608, 0);   add(dtw, WF_DTW, 512, 0);    add(dtb, WF_DTB, 128, 0);
  add(alog, WF_A, 2048, 1);    // A = -exp(A_log)
  add(dpv, WF_DP, 128, 0);
  add(onw, WF_ONW, 128, 0);    add(onb, WF_ONB, 128, 0);
  add(opw, WF_OPW, 8192, 0);
  add(cfw, WF_CFW, 4096, 0);   add(cfb, WF_CFB, 64, 0);
  add(inpjw, WF_INPJ, 16384, 0);
  ca.ncvt = ns; ca.cfw = cfw; ca.opw = opw; ca.wcomb = wcomb;

  k0_cvt<<<ns + 32, 256, 0, stream>>>(ca);
  k1_dw<<<512, 256, 0, stream>>>(x, wf, feats, nstat);
  k2_fuse<<<512, 256, 0, stream>>>(feats, nstat, wf, xf);
  k3_norm<<<512, 256, 0, stream>>>(xf, x, x1);
  k4_inproj<<<1024, 256, 0, stream>>>(x1, wf, xmraw, z);
  k5_dw3<<<1024, 256, 0, stream>>>(xmraw, wf, xmc);
  k6_xproj<<<256, 256, 0, stream>>>(xmc, wf, Bmw, Cmw, dtm);
  k7_scan1<<<1024, 128, 0, stream>>>(xmc, Bmw, dtm, wf, Acb, Bcb);
  k8_mid<<<64, 256, 0, stream>>>(Acb, Bcb, Hi);
  k9_scan2<<<1024, 128, 0, stream>>>(xmc, Bmw, Cmw, dtm, z, wf, Hi, G);
  k11A_proj<<<512, 256, 0, stream>>>(G, wf, wcomb, yc, part);
  k11b_stats<<<2, 256, 0, stream>>>(part, stats);
  k11c_final<<<512, 256, 0, stream>>>(yc, stats, x1, (float*)d_out);
}

// Round 11
// 216.743 us; speedup vs baseline: 3.1423x; 1.0129x over previous
//
#include <hip/hip_runtime.h>
#include <math.h>

#define NB 8
#define NC 64
#define NL 4096
#define NDI 128
#define NN 16
#define CHUNK 32
#define NKCH 128   // NL / CHUNK

// ---------------- workspace layout (float offsets) ----------------
#define OFF_FEATS 0ull
#define OFF_AC    0ull
#define OFF_BC    2097152ull
#define OFF_HINIT 4194304ull
#define OFF_XF    6291456ull
#define OFF_BMAT  6291456ull
#define OFF_CMAT  6815744ull
#define OFF_X1    8388608ull
#define OFF_XMRAW 10485760ull
#define OFF_G     10485760ull
#define OFF_Z     14680064ull
#define OFF_YC    14680064ull
#define OFF_PART  16777216ull   // 32768 (nstat partials early, k11A partials late)
#define OFF_STATS 16809984ull
#define OFF_XMC   18874368ull
#define OFF_DTM   23068672ull
#define OFF_WF    27262976ull
#define OFF_NSTAT (OFF_WF + 55552ull)
#define OFF_WCOMB (OFF_WF + 58624ull)
#define WS_NEED_FLOATS (OFF_WF + 66816ull)

// weight sub-offsets inside WF (floats)
#define WF_DW3    0
#define WF_DW5    576
#define WF_DW7    2176
#define WF_B3     5312
#define WF_B5     5376
#define WF_B7     5440
#define WF_FUSE   5504
#define WF_FUSEB  17792
#define WF_C2W    17856
#define WF_C2B    19008
#define WF_XPW    19136
#define WF_DTW    23744
#define WF_DTB    24256
#define WF_A      24384
#define WF_DP     26432
#define WF_ONW    26560
#define WF_ONB    26688
#define WF_OPW    26816
#define WF_CFW    35008
#define WF_CFB    39104
#define WF_INPJ   39168

// ---------------- K0 ----------------
struct Cvt { const float* src; float* dst; int n; int op; };
struct CvtArgs { Cvt d[22]; int ncvt; const float* cfw; const float* opw; float* wcomb; };

__global__ __launch_bounds__(256) void k0_cvt(CvtArgs a){
  if ((int)blockIdx.x < a.ncvt){
    Cvt c = a.d[blockIdx.x];
    for (int i = threadIdx.x; i < c.n; i += 256){
      float v = c.src[i];
      c.dst[i] = c.op ? -expf(v) : v;
    }
  } else {
    int idx = (blockIdx.x - a.ncvt)*256 + threadIdx.x;
    int c = idx >> 7, kk = idx & 127;
    float s = 0.f;
    #pragma unroll
    for (int j=0;j<64;j++) s += a.cfw[c*64+j] * a.opw[j*128+kk];
    a.wcomb[idx] = s;
  }
}

// ---------------- K1: dw convs, 2 row-halves per plane; grid 1024; reg-batched staging ----------------
__global__ __launch_bounds__(256) void k1_dw(const float* __restrict__ x, const float* __restrict__ wf,
                                             float* __restrict__ feats, float* __restrict__ part){
  const int half = blockIdx.x & 1, c = (blockIdx.x >> 1) & 63, b = blockIdx.x >> 7;
  const int tid = threadIdx.x;
  const int r0 = half*32;
  __shared__ float xs[38*73];          // rows r0-3..r0+34, cols pad 3 each side, stride 73
  __shared__ float red[4][6];
  for (int i = tid; i < 38*73; i += 256) xs[i] = 0.f;
  // batched stage: 38 rows x 64 cols = 2432 elements
  const float* xp = x + ((size_t)b*64 + c)*NL;
  float v[10];
  #pragma unroll
  for (int k=0;k<10;k++){
    int idx = tid + k*256;
    int j = idx >> 6, w = idx & 63;
    int gr = r0 - 3 + j;
    bool ok = (idx < 2432) && (gr >= 0) && (gr < 64);
    v[k] = ok ? xp[gr*64 + w] : 0.f;
  }
  float w3r[9], w5r[25], w7r[49];
  #pragma unroll
  for (int i=0;i<9;i++)  w3r[i] = wf[WF_DW3 + c*9 + i];
  #pragma unroll
  for (int i=0;i<25;i++) w5r[i] = wf[WF_DW5 + c*25 + i];
  #pragma unroll
  for (int i=0;i<49;i++) w7r[i] = wf[WF_DW7 + c*49 + i];
  float b3 = wf[WF_B3+c], b5 = wf[WF_B5+c], b7 = wf[WF_B7+c];
  __syncthreads();   // zero-init complete
  #pragma unroll
  for (int k=0;k<10;k++){
    int idx = tid + k*256;
    if (idx < 2432){
      int j = idx >> 6, w = idx & 63;
      xs[j*73 + (w+3)] = v[k];
    }
  }
  __syncthreads();
  float s3=0,q3=0,s5=0,q5=0,s7=0,q7=0;
  float* f3 = feats + ((size_t)b*192 + c) * NL + r0*64;
  float* f5 = f3 + (size_t)64*NL;
  float* f7 = f3 + (size_t)128*NL;
  #pragma unroll
  for (int g=0; g<2; g++){
    int p = g*1024 + tid*4;
    int lh = p >> 6, w0 = p & 63;       // local row 0..31
    float a3[4], a5[4], a7[4];
    #pragma unroll
    for (int i=0;i<4;i++){ a3[i]=b3; a5[i]=b5; a7[i]=b7; }
    #pragma unroll
    for (int dy=0; dy<7; dy++){
      float s[10];
      #pragma unroll
      for (int j=0;j<10;j++) s[j] = xs[(lh+dy)*73 + w0 + j];
      #pragma unroll
      for (int dx=0;dx<7;dx++){
        float wv = w7r[dy*7+dx];
        #pragma unroll
        for (int i=0;i<4;i++) a7[i] += s[dx+i]*wv;
      }
      if (dy>=1 && dy<=5){
        #pragma unroll
        for (int dx=0;dx<5;dx++){
          float wv = w5r[(dy-1)*5+dx];
          #pragma unroll
          for (int i=0;i<4;i++) a5[i] += s[dx+1+i]*wv;
        }
      }
      if (dy>=2 && dy<=4){
        #pragma unroll
        for (int dx=0;dx<3;dx++){
          float wv = w3r[(dy-2)*3+dx];
          #pragma unroll
          for (int i=0;i<4;i++) a3[i] += s[dx+2+i]*wv;
        }
      }
    }
    *(float4*)(f3+p) = make_float4(a3[0],a3[1],a3[2],a3[3]);
    *(float4*)(f5+p) = make_float4(a5[0],a5[1],a5[2],a5[3]);
    *(float4*)(f7+p) = make_float4(a7[0],a7[1],a7[2],a7[3]);
    #pragma unroll
    for (int i=0;i<4;i++){
      s3+=a3[i]; q3+=a3[i]*a3[i];
      s5+=a5[i]; q5+=a5[i]*a5[i];
      s7+=a7[i]; q7+=a7[i]*a7[i];
    }
  }
  int wid = tid>>6, lane = tid&63;
  float v6[6]={s3,q3,s5,q5,s7,q7};
  #pragma unroll
  for (int j=0;j<6;j++){
    float t = v6[j];
    #pragma unroll
    for (int o=32;o>0;o>>=1) t += __shfl_down(t,o);
    if (!lane) red[wid][j]=t;
  }
  __syncthreads();
  if (tid < 3){
    float su = red[0][tid*2]+red[1][tid*2]+red[2][tid*2]+red[3][tid*2];
    float sq = red[0][tid*2+1]+red[1][tid*2+1]+red[2][tid*2+1]+red[3][tid*2+1];
    size_t k = (size_t)(b*192 + tid*64 + c)*4 + half*2;
    part[k]   = su;
    part[k+1] = sq;
  }
}

// ---------------- K2: fuse 1x1 (192->64). og2 x b8 x pt32 = 512; J=4,P=4; stats from partials ----------------
__global__ __launch_bounds__(256) void k2_fuse(const float* __restrict__ feats, const float* __restrict__ npart,
                                               const float* __restrict__ wf, float* __restrict__ xf){
  int og = blockIdx.x >> 8, rem = blockIdx.x & 255;
  int b = rem >> 5, pt = rem & 31;
  int jslot = threadIdx.x >> 5, pxslot = threadIdx.x & 31;
  __shared__ float wlds[32][192];
  __shared__ float xs[32][128];
  __shared__ float msl[192], rsl[192];
  for (int i = threadIdx.x; i < 192; i += 256){
    const float* pp = npart + (size_t)(b*192+i)*4;
    float su = pp[0]+pp[2], sq = pp[1]+pp[3];
    float m = su*(1.f/NL);
    msl[i] = m;
    rsl[i] = rsqrtf(sq*(1.f/NL) - m*m + 1e-5f);
  }
  {
    const float4* Wg = (const float4*)(wf + WF_FUSE + og*32*192);
    float4* Wl = (float4*)&wlds[0][0];
    for (int i = threadIdx.x; i < 1536; i += 256) Wl[i] = Wg[i];
  }
  float acc[4][4];
  #pragma unroll
  for (int j=0;j<4;j++)
    #pragma unroll
    for (int p=0;p<4;p++) acc[j][p]=0.f;
  const float* fbase = feats + (size_t)b*192*NL + pt*128;
  for (int ch = 0; ch < 6; ch++){
    __syncthreads();
    for (int i = threadIdx.x; i < 1024; i += 256){
      int r = i >> 5, c4 = i & 31;
      int k = ch*32 + r;
      float4 f = *(const float4*)(fbase + (size_t)k*NL + c4*4);
      float m = msl[k], rs = rsl[k];
      float v0=(f.x-m)*rs, v1=(f.y-m)*rs, v2=(f.z-m)*rs, v3=(f.w-m)*rs;
      v0 = v0>0.f?v0:0.01f*v0; v1 = v1>0.f?v1:0.01f*v1;
      v2 = v2>0.f?v2:0.01f*v2; v3 = v3>0.f?v3:0.01f*v3;
      ((float4*)&xs[r][0])[c4] = make_float4(v0,v1,v2,v3);
    }
    __syncthreads();
    #pragma unroll 1
    for (int c = 0; c < 32; c++){
      float a[4];
      #pragma unroll
      for (int p=0;p<4;p++) a[p] = xs[c][pxslot + 32*p];
      #pragma unroll
      for (int jj=0;jj<4;jj++){
        float w = wlds[jslot*4+jj][ch*32+c];
        #pragma unroll
        for (int p=0;p<4;p++) acc[jj][p] += w*a[p];
      }
    }
  }
  #pragma unroll
  for (int jj=0;jj<4;jj++){
    int o = og*32 + jslot*4 + jj;
    float bias = wf[WF_FUSEB + o];
    float* dp = xf + (size_t)b*64*NL + (size_t)o*NL + pt*128;
    #pragma unroll
    for (int p=0;p<4;p++) dp[pxslot + 32*p] = acc[jj][p] + bias;
  }
}

// ---------------- K3: inorm(xf)+lrelu + x -> x1 ----------------
__global__ __launch_bounds__(256) void k3_norm(const float* __restrict__ xf, const float* __restrict__ x,
                                               float* __restrict__ x1){
  const int tid = threadIdx.x;
  const size_t base = (size_t)blockIdx.x * NL;
  float loc[16]; float s=0.f, q=0.f;
  #pragma unroll
  for (int i=0;i<16;i++){ float v = xf[base + tid + i*256]; loc[i]=v; s+=v; q+=v*v; }
  __shared__ float red[4][2];
  int wid = tid>>6, lane = tid&63;
  #pragma unroll
  for (int o=32;o>0;o>>=1){ s += __shfl_down(s,o); q += __shfl_down(q,o); }
  if (!lane){ red[wid][0]=s; red[wid][1]=q; }
  __syncthreads();
  s = red[0][0]+red[1][0]+red[2][0]+red[3][0];
  q = red[0][1]+red[1][1]+red[2][1]+red[3][1];
  float m = s*(1.f/NL), va = q*(1.f/NL)-m*m, rs = rsqrtf(va+1e-5f);
  #pragma unroll
  for (int i=0;i<16;i++){
    int idx = tid + i*256;
    float v = (loc[i]-m)*rs;
    v = v>0.f ? v : 0.01f*v;
    x1[base+idx] = v + x[base+idx];
  }
}

// ---------------- K4: in_proj (64->256). og4 x b8 x pt32 = 1024; J=8,P=4 ----------------
__global__ __launch_bounds__(256) void k4_inproj(const float* __restrict__ x1, const float* __restrict__ wf,
                                                 float* __restrict__ xmraw, float* __restrict__ z){
  int og = blockIdx.x >> 8, rem = blockIdx.x & 255;
  int b = rem >> 5, pt = rem & 31;
  int jslot = threadIdx.x >> 5, pxslot = threadIdx.x & 31;
  __shared__ float wlds[64][64];
  __shared__ float xs[32][128];
  {
    const float4* Wg = (const float4*)(wf + WF_INPJ + og*64*64);
    float4* Wl = (float4*)&wlds[0][0];
    for (int i = threadIdx.x; i < 1024; i += 256) Wl[i] = Wg[i];
  }
  float acc[8][4];
  #pragma unroll
  for (int j=0;j<8;j++)
    #pragma unroll
    for (int p=0;p<4;p++) acc[j][p]=0.f;
  const float* xbase = x1 + (size_t)b*64*NL + pt*128;
  for (int ch = 0; ch < 2; ch++){
    __syncthreads();
    for (int i = threadIdx.x; i < 1024; i += 256){
      int r = i >> 5, c4 = i & 31;
      ((float4*)&xs[r][0])[c4] = *(const float4*)(xbase + (size_t)(ch*32+r)*NL + c4*4);
    }
    __syncthreads();
    #pragma unroll 1
    for (int c = 0; c < 32; c++){
      float a[4];
      #pragma unroll
      for (int p=0;p<4;p++) a[p] = xs[c][pxslot + 32*p];
      #pragma unroll
      for (int jj=0;jj<8;jj++){
        float w = wlds[jslot*8+jj][ch*32+c];
        #pragma unroll
        for (int p=0;p<4;p++) acc[jj][p] += w*a[p];
      }
    }
  }
  float* dstbase = (og < 2 ? xmraw + (size_t)b*128*NL + (size_t)(og*64)*NL
                           : z     + (size_t)b*128*NL + (size_t)((og-2)*64)*NL) + pt*128;
  #pragma unroll
  for (int jj=0;jj<8;jj++){
    float* dp = dstbase + (size_t)(jslot*8+jj)*NL;
    #pragma unroll
    for (int p=0;p<4;p++) dp[pxslot + 32*p] = acc[jj][p];
  }
}

// ---------------- K5: depthwise 3x3 + silu (stride 69; reg-batched staging) ----------------
__global__ __launch_bounds__(256) void k5_dw3(const float* __restrict__ xmraw, const float* __restrict__ wf,
                                              float* __restrict__ xmc){
  const int d = blockIdx.x & 127;
  const int tid = threadIdx.x;
  __shared__ float xs[66*69];
  for (int i=tid;i<66*69;i+=256) xs[i]=0.f;
  const float* xp = xmraw + (size_t)blockIdx.x * NL;
  float v[16];
  #pragma unroll
  for (int k=0;k<16;k++) v[k] = xp[tid + k*256];
  float wr[9];
  #pragma unroll
  for (int i=0;i<9;i++) wr[i] = wf[WF_C2W + d*9 + i];
  float bb = wf[WF_C2B + d];
  __syncthreads();
  #pragma unroll
  for (int k=0;k<16;k++){
    int i = tid + k*256;
    int h = i>>6, w = i&63;
    xs[(h+1)*69 + (w+1)] = v[k];
  }
  __syncthreads();
  float* op = xmc + (size_t)blockIdx.x * NL;
  #pragma unroll
  for (int g=0; g<4; g++){
    int p = g*1024 + tid*4;
    int h = p>>6, w0 = p&63;
    float a[4];
    #pragma unroll
    for (int i=0;i<4;i++) a[i]=bb;
    #pragma unroll
    for (int dy=0; dy<3; dy++){
      float s[6];
      #pragma unroll
      for (int j=0;j<6;j++) s[j] = xs[(h+dy)*69 + w0 + j];
      #pragma unroll
      for (int dx=0;dx<3;dx++){
        float wv = wr[dy*3+dx];
        #pragma unroll
        for (int i=0;i<4;i++) a[i] += s[dx+i]*wv;
      }
    }
    float4 o;
    o.x = a[0]/(1.f+__expf(-a[0]));
    o.y = a[1]/(1.f+__expf(-a[1]));
    o.z = a[2]/(1.f+__expf(-a[2]));
    o.w = a[3]/(1.f+__expf(-a[3]));
    *(float4*)(op+p) = o;
  }
}

// ---------------- K6 (slim): x_proj (128->36); grid 256; J=9,P=2 ----------------
__global__ __launch_bounds__(256) void k6_xproj(const float* __restrict__ xmc, const float* __restrict__ wf,
                                                float* __restrict__ Bm, float* __restrict__ Cm,
                                                float* __restrict__ dtm){
  int b = blockIdx.x >> 5, pt = blockIdx.x & 31;
  int jslot = threadIdx.x >> 6, pxslot = threadIdx.x & 63;
  __shared__ float wlds[36][128];
  __shared__ float xs[32][128];
  {
    const float4* Wg = (const float4*)(wf + WF_XPW);
    float4* Wl = (float4*)&wlds[0][0];
    for (int i = threadIdx.x; i < 1152; i += 256) Wl[i] = Wg[i];
  }
  float acc[9][2];
  #pragma unroll
  for (int j=0;j<9;j++){ acc[j][0]=0.f; acc[j][1]=0.f; }
  const float* ubase = xmc + (size_t)b*128*NL + pt*128;
  for (int ch = 0; ch < 4; ch++){
    __syncthreads();
    for (int i = threadIdx.x; i < 1024; i += 256){
      int r = i >> 5, c4 = i & 31;
      ((float4*)&xs[r][0])[c4] = *(const float4*)(ubase + (size_t)(ch*32+r)*NL + c4*4);
    }
    __syncthreads();
    #pragma unroll 1
    for (int c = 0; c < 32; c++){
      float a0 = xs[c][pxslot];
      float a1 = xs[c][pxslot + 64];
      #pragma unroll
      for (int j=0;j<9;j++){
        float w = wlds[jslot*9+j][ch*32+c];
        acc[j][0] += w*a0;
        acc[j][1] += w*a1;
      }
    }
  }
  #pragma unroll
  for (int j=0;j<9;j++){
    int o = jslot*9 + j;
    float* dp;
    if (o < 4)       dp = dtm + ((size_t)b*4 + o)*NL;
    else if (o < 20) dp = Bm  + ((size_t)b*16 + (o-4))*NL;
    else             dp = Cm  + ((size_t)b*16 + (o-20))*NL;
    dp[pt*128 + pxslot]      = acc[j][0];
    dp[pt*128 + pxslot + 64] = acc[j][1];
  }
}

// ---------------- K7: scan pass1 — reg-batched staging, delta on the fly ----------------
__global__ __launch_bounds__(128) void k7_scan1(const float* __restrict__ xmc, const float* __restrict__ Bm,
                                                const float* __restrict__ dtm, const float* __restrict__ wf,
                                                float* __restrict__ Ac, float* __restrict__ Bc){
  int k = blockIdx.x & (NKCH-1), b = blockIdx.x >> 7;
  int d = threadIdx.x;
  int l0 = k*CHUNK;
  __shared__ float xs[128*33];
  __shared__ float Bl[16*32];
  __shared__ float dtl[4*32];
  // batched loads
  float vx[32], vb[4], vd;
  #pragma unroll
  for (int j=0;j<32;j++){
    int i = d + 128*j;
    int ch = i >> 5, px = i & 31;
    vx[j] = xmc[((size_t)b*128+ch)*NL + l0 + px];
  }
  #pragma unroll
  for (int j=0;j<4;j++){
    int i = d + 128*j;
    int n = i >> 5, li = i & 31;
    vb[j] = Bm[((size_t)b*16+n)*NL + l0 + li];
  }
  { int n = d >> 5, li = d & 31; vd = dtm[((size_t)b*4+n)*NL + l0 + li]; }
  #pragma unroll
  for (int j=0;j<32;j++){
    int i = d + 128*j;
    int ch = i >> 5, px = i & 31;
    xs[ch*33+px] = vx[j];
  }
  #pragma unroll
  for (int j=0;j<4;j++) Bl[d + 128*j] = vb[j];
  dtl[d] = vd;
  float A[16], P[16], Q[16];
  const float* Af = wf + WF_A + d*16;
  #pragma unroll
  for (int n=0;n<16;n++){ A[n]=Af[n]; P[n]=1.f; Q[n]=0.f; }
  float w0 = wf[WF_DTW+d*4], w1 = wf[WF_DTW+d*4+1], w2 = wf[WF_DTW+d*4+2], w3 = wf[WF_DTW+d*4+3];
  float db2 = 2.f*wf[WF_DTB+d];
  __syncthreads();
  for (int l=0; l<CHUNK; l++){
    float tt = w0*dtl[l] + w1*dtl[32+l] + w2*dtl[64+l] + w3*dtl[96+l] + db2;
    float de = tt > 20.f ? tt : __logf(1.f+__expf(tt));
    float du = de * xs[d*33+l];
    #pragma unroll
    for (int n=0;n<16;n++){
      float a = __expf(de*A[n]);
      P[n] *= a;
      Q[n] = a*Q[n] + du*Bl[n*32+l];
    }
  }
  size_t base = (((size_t)k*NB + b)*128 + d)*16;
  #pragma unroll
  for (int i=0;i<4;i++){
    ((float4*)(Ac+base))[i] = make_float4(P[i*4],P[i*4+1],P[i*4+2],P[i*4+3]);
    ((float4*)(Bc+base))[i] = make_float4(Q[i*4],Q[i*4+1],Q[i*4+2],Q[i*4+3]);
  }
}

// ---------------- K8: middle scan ----------------
__global__ __launch_bounds__(256) void k8_mid(const float* __restrict__ Ac, const float* __restrict__ Bc,
                                              float* __restrict__ Hi){
  int idx = blockIdx.x*256 + threadIdx.x;
  float h = 0.f;
  for (int k0=0;k0<NKCH;k0+=16){
    float av[16], bv[16];
    #pragma unroll
    for (int j=0;j<16;j++){
      size_t o = (size_t)(k0+j)*16384 + idx;
      av[j]=Ac[o]; bv[j]=Bc[o];
    }
    #pragma unroll
    for (int j=0;j<16;j++){
      size_t o = (size_t)(k0+j)*16384 + idx;
      Hi[o] = h;
      h = av[j]*h + bv[j];
    }
  }
}

// ---------------- K9: scan pass2 + fused LN*silu(z) gate -> G; reg-batched staging ----------------
__global__ __launch_bounds__(128) void k9_scan2(const float* __restrict__ xmc, const float* __restrict__ Bm,
                                                const float* __restrict__ Cm, const float* __restrict__ dtm,
                                                const float* __restrict__ z, const float* __restrict__ wf,
                                                const float* __restrict__ Hi, float* __restrict__ G){
  int k = blockIdx.x & (NKCH-1), b = blockIdx.x >> 7;
  int d = threadIdx.x;
  int l0 = k*CHUNK;
  __shared__ float xs[128*33];
  __shared__ float Bl[16*32], Cl[16*32];
  __shared__ float dtl[4*32];
  __shared__ float red[4][32][2];
  __shared__ float mstat[32], rstat[32];
  float vx[32], vb[4], vc[4], vd;
  #pragma unroll
  for (int j=0;j<32;j++){
    int i = d + 128*j;
    int ch = i >> 5, px = i & 31;
    vx[j] = xmc[((size_t)b*128+ch)*NL + l0 + px];
  }
  #pragma unroll
  for (int j=0;j<4;j++){
    int i = d + 128*j;
    int n = i >> 5, li = i & 31;
    vb[j] = Bm[((size_t)b*16+n)*NL + l0 + li];
    vc[j] = Cm[((size_t)b*16+n)*NL + l0 + li];
  }
  { int n = d >> 5, li = d & 31; vd = dtm[((size_t)b*4+n)*NL + l0 + li]; }
  float A[16], h[16];
  const float* Af = wf + WF_A + d*16;
  size_t hb = (((size_t)k*NB + b)*128 + d)*16;
  #pragma unroll
  for (int n=0;n<16;n++){ A[n]=Af[n]; h[n]=Hi[hb+n]; }
  #pragma unroll
  for (int j=0;j<32;j++){
    int i = d + 128*j;
    int ch = i >> 5, px = i & 31;
    xs[ch*33+px] = vx[j];
  }
  #pragma unroll
  for (int j=0;j<4;j++){ Bl[d+128*j] = vb[j]; Cl[d+128*j] = vc[j]; }
  dtl[d] = vd;
  float Dv = wf[WF_DP + d];
  float w0 = wf[WF_DTW+d*4], w1 = wf[WF_DTW+d*4+1], w2 = wf[WF_DTW+d*4+2], w3 = wf[WF_DTW+d*4+3];
  float db2 = 2.f*wf[WF_DTB+d];
  __syncthreads();
  for (int l=0; l<CHUNK; l++){
    float tt = w0*dtl[l] + w1*dtl[32+l] + w2*dtl[64+l] + w3*dtl[96+l] + db2;
    float de = tt > 20.f ? tt : __logf(1.f+__expf(tt));
    float uu = xs[d*33+l];
    float du = de * uu;
    float yv = uu * Dv;
    #pragma unroll
    for (int n=0;n<16;n++){
      float a = __expf(de*A[n]);
      h[n] = a*h[n] + du*Bl[n*32+l];
      yv  += h[n]*Cl[n*32+l];
    }
    xs[d*33+l] = yv;
  }
  __syncthreads();
  {
    int px = d & 31, q = d >> 5;
    float s=0.f, qq=0.f;
    #pragma unroll
    for (int j=0;j<32;j++){ float v = xs[(q*32+j)*33+px]; s+=v; qq+=v*v; }
    red[q][px][0]=s; red[q][px][1]=qq;
  }
  __syncthreads();
  if (d < 32){
    float ss = red[0][d][0]+red[1][d][0]+red[2][d][0]+red[3][d][0];
    float sq = red[0][d][1]+red[1][d][1]+red[2][d][1]+red[3][d][1];
    float m = ss*(1.f/128.f);
    mstat[d] = m;
    rstat[d] = rsqrtf(sq*(1.f/128.f) - m*m + 1e-5f);
  }
  __syncthreads();
  float ow = wf[WF_ONW+d], ob = wf[WF_ONB+d];
  const float* zp = z + ((size_t)b*128+d)*NL + l0;
  float* gp = G + ((size_t)b*128+d)*NL + l0;
  #pragma unroll
  for (int l4=0; l4<CHUNK/4; l4++){
    float4 zv4 = ((const float4*)zp)[l4];
    float zv[4] = {zv4.x, zv4.y, zv4.z, zv4.w};
    float out[4];
    #pragma unroll
    for (int j=0;j<4;j++){
      int l = l4*4+j;
      float t = (xs[d*33+l]-mstat[l])*rstat[l]*ow + ob;
      out[j] = t * (zv[j]/(1.f+__expf(-zv[j])));
    }
    ((float4*)gp)[l4] = make_float4(out[0],out[1],out[2],out[3]);
  }
}

// ---------------- K11A: yc = W_comb @ G + cf_b. og2 x b8 x pt32 = 512; J=4,P=4; + stats ----------------
__global__ __launch_bounds__(256) void k11A_proj(const float* __restrict__ G, const float* __restrict__ wf,
                                                 const float* __restrict__ wcomb,
                                                 float* __restrict__ yc, float* __restrict__ part){
  int og = blockIdx.x >> 8, rem = blockIdx.x & 255;
  int b = rem >> 5, pt = rem & 31;
  int jslot = threadIdx.x >> 5, pxslot = threadIdx.x & 31;
  __shared__ float wlds[32][128];
  __shared__ float xs[32][128];
  {
    const float4* Wg = (const float4*)(wcomb + og*32*128);
    float4* Wl = (float4*)&wlds[0][0];
    for (int i = threadIdx.x; i < 1024; i += 256) Wl[i] = Wg[i];
  }
  float acc[4][4];
  #pragma unroll
  for (int j=0;j<4;j++)
    #pragma unroll
    for (int p=0;p<4;p++) acc[j][p]=0.f;
  const float* gbase = G + (size_t)b*128*NL + pt*128;
  for (int ch = 0; ch < 4; ch++){
    __syncthreads();
    for (int i = threadIdx.x; i < 1024; i += 256){
      int r = i >> 5, c4 = i & 31;
      ((float4*)&xs[r][0])[c4] = *(const float4*)(gbase + (size_t)(ch*32+r)*NL + c4*4);
    }
    __syncthreads();
    #pragma unroll 1
    for (int c = 0; c < 32; c++){
      float a[4];
      #pragma unroll
      for (int p=0;p<4;p++) a[p] = xs[c][pxslot + 32*p];
      #pragma unroll
      for (int jj=0;jj<4;jj++){
        float w = wlds[jslot*4+jj][ch*32+c];
        #pragma unroll
        for (int p=0;p<4;p++) acc[jj][p] += w*a[p];
      }
    }
  }
  #pragma unroll
  for (int jj=0;jj<4;jj++){
    int cc = og*32 + jslot*4 + jj;
    float bias = wf[WF_CFB + cc];
    float* dp = yc + (size_t)b*64*NL + (size_t)cc*NL + pt*128;
    float sv = 0.f, qv = 0.f;
    #pragma unroll
    for (int p=0;p<4;p++){
      float t = acc[jj][p] + bias;
      dp[pxslot + 32*p] = t;
      sv += t; qv += t*t;
    }
    #pragma unroll
    for (int o=16;o>0;o>>=1){ sv += __shfl_xor(sv,o); qv += __shfl_xor(qv,o); }
    if (pxslot == 0){
      size_t pidx = (((size_t)b*64 + cc)*32 + pt)*2;
      part[pidx] = sv; part[pidx+1] = qv;
    }
  }
}

// ---------------- K11b: finalize per-(b,c) mean/rsqrt (32 partials each) ----------------
__global__ __launch_bounds__(256) void k11b_stats(const float* __restrict__ part, float* __restrict__ stats){
  int i = blockIdx.x*256 + threadIdx.x;
  if (i >= 512) return;
  float s=0.f, q=0.f;
  #pragma unroll
  for (int t2=0;t2<32;t2++){ s += part[((size_t)i*32+t2)*2]; q += part[((size_t)i*32+t2)*2+1]; }
  float m = s*(1.f/NL), va = q*(1.f/NL) - m*m;
  stats[i*2] = m; stats[i*2+1] = rsqrtf(va+1e-5f);
}

// ---------------- K11c: out = x1 + inorm(yc) ----------------
__global__ __launch_bounds__(256) void k11c_final(const float* __restrict__ yc, const float* __restrict__ stats,
                                                  const float* __restrict__ x1, float* __restrict__ out){
  int bc = blockIdx.x;
  float m = stats[bc*2], rs = stats[bc*2+1];
  size_t base = (size_t)bc*NL;
  for (int i=threadIdx.x;i<NL;i+=256){
    float v = (yc[base+i]-m)*rs;
    out[base+i] = x1[base+i] + v;
  }
}

// ---------------- host ----------------
extern "C" void kernel_launch(void* const* d_in, const int* in_sizes, int n_in,
                              void* d_out, int out_size, void* d_ws, size_t ws_size,
                              hipStream_t stream) {
  if (ws_size < WS_NEED_FLOATS * sizeof(float)) return;
  const float* x     = (const float*)d_in[0];
  const float* dw3w  = (const float*)d_in[1];
  const float* dw3b  = (const float*)d_in[2];
  const float* dw5w  = (const float*)d_in[3];
  const float* dw5b  = (const float*)d_in[4];
  const float* dw7w  = (const float*)d_in[5];
  const float* dw7b  = (const float*)d_in[6];
  const float* fusew = (const float*)d_in[7];
  const float* fuseb = (const float*)d_in[8];
  const float* inpjw = (const float*)d_in[9];
  const float* c2w   = (const float*)d_in[10];
  const float* c2b   = (const float*)d_in[11];
  const float* xpw   = (const float*)d_in[12];
  const float* dtw   = (const float*)d_in[13];
  const float* dtb   = (const float*)d_in[14];
  const float* alog  = (const float*)d_in[15];
  const float* dpv   = (const float*)d_in[16];
  const float* onw   = (const float*)d_in[17];
  const float* onb   = (const float*)d_in[18];
  const float* opw   = (const float*)d_in[19];
  const float* cfw   = (const float*)d_in[20];
  const float* cfb   = (const float*)d_in[21];

  float* ws    = (float*)d_ws;
  float* wf    = ws + OFF_WF;
  float* wcomb = ws + OFF_WCOMB;
  float* feats = ws + OFF_FEATS;
  float* xf    = ws + OFF_XF;
  float* x1    = ws + OFF_X1;
  float* xmraw = ws + OFF_XMRAW;
  float* z     = ws + OFF_Z;
  float* xmc   = ws + OFF_XMC;
  float* Bmw   = ws + OFF_BMAT;
  float* Cmw   = ws + OFF_CMAT;
  float* dtm   = ws + OFF_DTM;
  float* Acb   = ws + OFF_AC;
  float* Bcb   = ws + OFF_BC;
  float* Hi    = ws + OFF_HINIT;
  float* G     = ws + OFF_G;
  float* yc    = ws + OFF_YC;
  float* part  = ws + OFF_PART;   // nstat partials (k1/k2), then k11A partials
  float* stats = ws + OFF_STATS;

  CvtArgs ca; int ns = 0;
  auto add = [&](const float* s, int off, int n, int op){
    ca.d[ns].src = s; ca.d[ns].dst = wf + off; ca.d[ns].n = n; ca.d[ns].op = op; ns++;
  };
  add(dw3w, WF_DW3, 576, 0);   add(dw5w, WF_DW5, 1600, 0);  add(dw7w, WF_DW7, 3136, 0);
  add(dw3b, WF_B3, 64, 0);     add(dw5b, WF_B5, 64, 0);     add(dw7b, WF_B7, 64, 0);
  add(fusew, WF_FUSE, 12288, 0); add(fuseb, WF_FUSEB, 64, 0);
  add(c2w, WF_C2W, 1152, 0);   add(c2b, WF_C2B, 128, 0);
  add(xpw, WF_XPW, 4608, 0);   add(dtw, WF_DTW, 512, 0);    add(dtb, WF_DTB, 128, 0);
  add(alog, WF_A, 2048, 1);    // A = -exp(A_log)
  add(dpv, WF_DP, 128, 0);
  add(onw, WF_ONW, 128, 0);    add(onb, WF_ONB, 128, 0);
  add(opw, WF_OPW, 8192, 0);
  add(cfw, WF_CFW, 4096, 0);   add(cfb, WF_CFB, 64, 0);
  add(inpjw, WF_INPJ, 16384, 0);
  ca.ncvt = ns; ca.cfw = cfw; ca.opw = opw; ca.wcomb = wcomb;

  k0_cvt<<<ns + 32, 256, 0, stream>>>(ca);
  k1_dw<<<1024, 256, 0, stream>>>(x, wf, feats, part);
  k2_fuse<<<512, 256, 0, stream>>>(feats, part, wf, xf);
  k3_norm<<<512, 256, 0, stream>>>(xf, x, x1);
  k4_inproj<<<1024, 256, 0, stream>>>(x1, wf, xmraw, z);
  k5_dw3<<<1024, 256, 0, stream>>>(xmraw, wf, xmc);
  k6_xproj<<<256, 256, 0, stream>>>(xmc, wf, Bmw, Cmw, dtm);
  k7_scan1<<<1024, 128, 0, stream>>>(xmc, Bmw, dtm, wf, Acb, Bcb);
  k8_mid<<<64, 256, 0, stream>>>(Acb, Bcb, Hi);
  k9_scan2<<<1024, 128, 0, stream>>>(xmc, Bmw, Cmw, dtm, z, wf, Hi, G);
  k11A_proj<<<512, 256, 0, stream>>>(G, wf, wcomb, yc, part);
  k11b_stats<<<2, 256, 0, stream>>>(part, stats);
  k11c_final<<<512, 256, 0, stream>>>(yc, stats, x1, (float*)d_out);
}

// Round 12
// 213.588 us; speedup vs baseline: 3.1888x; 1.0148x over previous
//
#include <hip/hip_runtime.h>
#include <math.h>

#define NB 8
#define NC 64
#define NL 4096
#define NDI 128
#define NN 16
#define CHUNK 32
#define NKCH 128   // NL / CHUNK

// ---------------- workspace layout (float offsets) ----------------
#define OFF_FEATS 0ull
#define OFF_AC    0ull
#define OFF_BC    2097152ull
#define OFF_HINIT 4194304ull
#define OFF_XF    6291456ull
#define OFF_BMAT  6291456ull
#define OFF_CMAT  6815744ull
#define OFF_X1    8388608ull
#define OFF_XMRAW 10485760ull
#define OFF_G     10485760ull
#define OFF_Z     14680064ull
#define OFF_YC    14680064ull
#define OFF_PART  16777216ull
#define OFF_STATS 16809984ull
#define OFF_XMC   18874368ull
#define OFF_DTM   23068672ull
#define OFF_WF    27262976ull
#define OFF_NSTAT (OFF_WF + 55552ull)
#define OFF_WCOMB (OFF_WF + 58624ull)
#define WS_NEED_FLOATS (OFF_WF + 66816ull)

// weight sub-offsets inside WF (floats)
#define WF_DW3    0
#define WF_DW5    576
#define WF_DW7    2176
#define WF_B3     5312
#define WF_B5     5376
#define WF_B7     5440
#define WF_FUSE   5504
#define WF_FUSEB  17792
#define WF_C2W    17856
#define WF_C2B    19008
#define WF_XPW    19136
#define WF_DTW    23744
#define WF_DTB    24256
#define WF_A      24384
#define WF_DP     26432
#define WF_ONW    26560
#define WF_ONB    26688
#define WF_OPW    26816
#define WF_CFW    35008
#define WF_CFB    39104
#define WF_INPJ   39168

// ---------------- K0 ----------------
struct Cvt { const float* src; float* dst; int n; int op; };
struct CvtArgs { Cvt d[22]; int ncvt; const float* cfw; const float* opw; float* wcomb; };

__global__ __launch_bounds__(256) void k0_cvt(CvtArgs a){
  if ((int)blockIdx.x < a.ncvt){
    Cvt c = a.d[blockIdx.x];
    for (int i = threadIdx.x; i < c.n; i += 256){
      float v = c.src[i];
      c.dst[i] = c.op ? -expf(v) : v;
    }
  } else {
    int idx = (blockIdx.x - a.ncvt)*256 + threadIdx.x;
    int c = idx >> 7, kk = idx & 127;
    float s = 0.f;
    #pragma unroll
    for (int j=0;j<64;j++) s += a.cfw[c*64+j] * a.opw[j*128+kk];
    a.wcomb[idx] = s;
  }
}

// ---------------- K1: dw convs, 2 row-halves per plane; grid 1024; reg-batched staging ----------------
__global__ __launch_bounds__(256) void k1_dw(const float* __restrict__ x, const float* __restrict__ wf,
                                             float* __restrict__ feats, float* __restrict__ part){
  const int half = blockIdx.x & 1, c = (blockIdx.x >> 1) & 63, b = blockIdx.x >> 7;
  const int tid = threadIdx.x;
  const int r0 = half*32;
  __shared__ float xs[38*73];
  __shared__ float red[4][6];
  for (int i = tid; i < 38*73; i += 256) xs[i] = 0.f;
  const float* xp = x + ((size_t)b*64 + c)*NL;
  float v[10];
  #pragma unroll
  for (int k=0;k<10;k++){
    int idx = tid + k*256;
    int j = idx >> 6, w = idx & 63;
    int gr = r0 - 3 + j;
    bool ok = (idx < 2432) && (gr >= 0) && (gr < 64);
    v[k] = ok ? xp[gr*64 + w] : 0.f;
  }
  float w3r[9], w5r[25], w7r[49];
  #pragma unroll
  for (int i=0;i<9;i++)  w3r[i] = wf[WF_DW3 + c*9 + i];
  #pragma unroll
  for (int i=0;i<25;i++) w5r[i] = wf[WF_DW5 + c*25 + i];
  #pragma unroll
  for (int i=0;i<49;i++) w7r[i] = wf[WF_DW7 + c*49 + i];
  float b3 = wf[WF_B3+c], b5 = wf[WF_B5+c], b7 = wf[WF_B7+c];
  __syncthreads();
  #pragma unroll
  for (int k=0;k<10;k++){
    int idx = tid + k*256;
    if (idx < 2432){
      int j = idx >> 6, w = idx & 63;
      xs[j*73 + (w+3)] = v[k];
    }
  }
  __syncthreads();
  float s3=0,q3=0,s5=0,q5=0,s7=0,q7=0;
  float* f3 = feats + ((size_t)b*192 + c) * NL + r0*64;
  float* f5 = f3 + (size_t)64*NL;
  float* f7 = f3 + (size_t)128*NL;
  #pragma unroll
  for (int g=0; g<2; g++){
    int p = g*1024 + tid*4;
    int lh = p >> 6, w0 = p & 63;
    float a3[4], a5[4], a7[4];
    #pragma unroll
    for (int i=0;i<4;i++){ a3[i]=b3; a5[i]=b5; a7[i]=b7; }
    #pragma unroll
    for (int dy=0; dy<7; dy++){
      float s[10];
      #pragma unroll
      for (int j=0;j<10;j++) s[j] = xs[(lh+dy)*73 + w0 + j];
      #pragma unroll
      for (int dx=0;dx<7;dx++){
        float wv = w7r[dy*7+dx];
        #pragma unroll
        for (int i=0;i<4;i++) a7[i] += s[dx+i]*wv;
      }
      if (dy>=1 && dy<=5){
        #pragma unroll
        for (int dx=0;dx<5;dx++){
          float wv = w5r[(dy-1)*5+dx];
          #pragma unroll
          for (int i=0;i<4;i++) a5[i] += s[dx+1+i]*wv;
        }
      }
      if (dy>=2 && dy<=4){
        #pragma unroll
        for (int dx=0;dx<3;dx++){
          float wv = w3r[(dy-2)*3+dx];
          #pragma unroll
          for (int i=0;i<4;i++) a3[i] += s[dx+2+i]*wv;
        }
      }
    }
    *(float4*)(f3+p) = make_float4(a3[0],a3[1],a3[2],a3[3]);
    *(float4*)(f5+p) = make_float4(a5[0],a5[1],a5[2],a5[3]);
    *(float4*)(f7+p) = make_float4(a7[0],a7[1],a7[2],a7[3]);
    #pragma unroll
    for (int i=0;i<4;i++){
      s3+=a3[i]; q3+=a3[i]*a3[i];
      s5+=a5[i]; q5+=a5[i]*a5[i];
      s7+=a7[i]; q7+=a7[i]*a7[i];
    }
  }
  int wid = tid>>6, lane = tid&63;
  float v6[6]={s3,q3,s5,q5,s7,q7};
  #pragma unroll
  for (int j=0;j<6;j++){
    float t = v6[j];
    #pragma unroll
    for (int o=32;o>0;o>>=1) t += __shfl_down(t,o);
    if (!lane) red[wid][j]=t;
  }
  __syncthreads();
  if (tid < 3){
    float su = red[0][tid*2]+red[1][tid*2]+red[2][tid*2]+red[3][tid*2];
    float sq = red[0][tid*2+1]+red[1][tid*2+1]+red[2][tid*2+1]+red[3][tid*2+1];
    size_t k = (size_t)(b*192 + tid*64 + c)*4 + half*2;
    part[k]   = su;
    part[k+1] = sq;
  }
}

// ---------------- K2: fuse 1x1 (192->64). og2 x b8 x pt32 = 512; J=4,P=4 ----------------
__global__ __launch_bounds__(256) void k2_fuse(const float* __restrict__ feats, const float* __restrict__ npart,
                                               const float* __restrict__ wf, float* __restrict__ xf){
  int og = blockIdx.x >> 8, rem = blockIdx.x & 255;
  int b = rem >> 5, pt = rem & 31;
  int jslot = threadIdx.x >> 5, pxslot = threadIdx.x & 31;
  __shared__ float wlds[32][192];
  __shared__ float xs[32][128];
  __shared__ float msl[192], rsl[192];
  for (int i = threadIdx.x; i < 192; i += 256){
    const float* pp = npart + (size_t)(b*192+i)*4;
    float su = pp[0]+pp[2], sq = pp[1]+pp[3];
    float m = su*(1.f/NL);
    msl[i] = m;
    rsl[i] = rsqrtf(sq*(1.f/NL) - m*m + 1e-5f);
  }
  {
    const float4* Wg = (const float4*)(wf + WF_FUSE + og*32*192);
    float4* Wl = (float4*)&wlds[0][0];
    for (int i = threadIdx.x; i < 1536; i += 256) Wl[i] = Wg[i];
  }
  float acc[4][4];
  #pragma unroll
  for (int j=0;j<4;j++)
    #pragma unroll
    for (int p=0;p<4;p++) acc[j][p]=0.f;
  const float* fbase = feats + (size_t)b*192*NL + pt*128;
  for (int ch = 0; ch < 6; ch++){
    __syncthreads();
    for (int i = threadIdx.x; i < 1024; i += 256){
      int r = i >> 5, c4 = i & 31;
      int k = ch*32 + r;
      float4 f = *(const float4*)(fbase + (size_t)k*NL + c4*4);
      float m = msl[k], rs = rsl[k];
      float v0=(f.x-m)*rs, v1=(f.y-m)*rs, v2=(f.z-m)*rs, v3=(f.w-m)*rs;
      v0 = v0>0.f?v0:0.01f*v0; v1 = v1>0.f?v1:0.01f*v1;
      v2 = v2>0.f?v2:0.01f*v2; v3 = v3>0.f?v3:0.01f*v3;
      ((float4*)&xs[r][0])[c4] = make_float4(v0,v1,v2,v3);
    }
    __syncthreads();
    #pragma unroll 1
    for (int c = 0; c < 32; c++){
      float a[4];
      #pragma unroll
      for (int p=0;p<4;p++) a[p] = xs[c][pxslot + 32*p];
      #pragma unroll
      for (int jj=0;jj<4;jj++){
        float w = wlds[jslot*4+jj][ch*32+c];
        #pragma unroll
        for (int p=0;p<4;p++) acc[jj][p] += w*a[p];
      }
    }
  }
  #pragma unroll
  for (int jj=0;jj<4;jj++){
    int o = og*32 + jslot*4 + jj;
    float bias = wf[WF_FUSEB + o];
    float* dp = xf + (size_t)b*64*NL + (size_t)o*NL + pt*128;
    #pragma unroll
    for (int p=0;p<4;p++) dp[pxslot + 32*p] = acc[jj][p] + bias;
  }
}

// ---------------- K3: inorm(xf)+lrelu + x -> x1 ----------------
__global__ __launch_bounds__(256) void k3_norm(const float* __restrict__ xf, const float* __restrict__ x,
                                               float* __restrict__ x1){
  const int tid = threadIdx.x;
  const size_t base = (size_t)blockIdx.x * NL;
  float loc[16]; float s=0.f, q=0.f;
  #pragma unroll
  for (int i=0;i<16;i++){ float v = xf[base + tid + i*256]; loc[i]=v; s+=v; q+=v*v; }
  __shared__ float red[4][2];
  int wid = tid>>6, lane = tid&63;
  #pragma unroll
  for (int o=32;o>0;o>>=1){ s += __shfl_down(s,o); q += __shfl_down(q,o); }
  if (!lane){ red[wid][0]=s; red[wid][1]=q; }
  __syncthreads();
  s = red[0][0]+red[1][0]+red[2][0]+red[3][0];
  q = red[0][1]+red[1][1]+red[2][1]+red[3][1];
  float m = s*(1.f/NL), va = q*(1.f/NL)-m*m, rs = rsqrtf(va+1e-5f);
  #pragma unroll
  for (int i=0;i<16;i++){
    int idx = tid + i*256;
    float v = (loc[i]-m)*rs;
    v = v>0.f ? v : 0.01f*v;
    x1[base+idx] = v + x[base+idx];
  }
}

// ---------------- K4: in_proj (64->256). og4 x b8 x pt32 = 1024; J=8,P=4 ----------------
__global__ __launch_bounds__(256) void k4_inproj(const float* __restrict__ x1, const float* __restrict__ wf,
                                                 float* __restrict__ xmraw, float* __restrict__ z){
  int og = blockIdx.x >> 8, rem = blockIdx.x & 255;
  int b = rem >> 5, pt = rem & 31;
  int jslot = threadIdx.x >> 5, pxslot = threadIdx.x & 31;
  __shared__ float wlds[64][64];
  __shared__ float xs[32][128];
  {
    const float4* Wg = (const float4*)(wf + WF_INPJ + og*64*64);
    float4* Wl = (float4*)&wlds[0][0];
    for (int i = threadIdx.x; i < 1024; i += 256) Wl[i] = Wg[i];
  }
  float acc[8][4];
  #pragma unroll
  for (int j=0;j<8;j++)
    #pragma unroll
    for (int p=0;p<4;p++) acc[j][p]=0.f;
  const float* xbase = x1 + (size_t)b*64*NL + pt*128;
  for (int ch = 0; ch < 2; ch++){
    __syncthreads();
    for (int i = threadIdx.x; i < 1024; i += 256){
      int r = i >> 5, c4 = i & 31;
      ((float4*)&xs[r][0])[c4] = *(const float4*)(xbase + (size_t)(ch*32+r)*NL + c4*4);
    }
    __syncthreads();
    #pragma unroll 1
    for (int c = 0; c < 32; c++){
      float a[4];
      #pragma unroll
      for (int p=0;p<4;p++) a[p] = xs[c][pxslot + 32*p];
      #pragma unroll
      for (int jj=0;jj<8;jj++){
        float w = wlds[jslot*8+jj][ch*32+c];
        #pragma unroll
        for (int p=0;p<4;p++) acc[jj][p] += w*a[p];
      }
    }
  }
  float* dstbase = (og < 2 ? xmraw + (size_t)b*128*NL + (size_t)(og*64)*NL
                           : z     + (size_t)b*128*NL + (size_t)((og-2)*64)*NL) + pt*128;
  #pragma unroll
  for (int jj=0;jj<8;jj++){
    float* dp = dstbase + (size_t)(jslot*8+jj)*NL;
    #pragma unroll
    for (int p=0;p<4;p++) dp[pxslot + 32*p] = acc[jj][p];
  }
}

// ---------------- K5: depthwise 3x3 + silu (stride 69; reg-batched staging) ----------------
__global__ __launch_bounds__(256) void k5_dw3(const float* __restrict__ xmraw, const float* __restrict__ wf,
                                              float* __restrict__ xmc){
  const int d = blockIdx.x & 127;
  const int tid = threadIdx.x;
  __shared__ float xs[66*69];
  for (int i=tid;i<66*69;i+=256) xs[i]=0.f;
  const float* xp = xmraw + (size_t)blockIdx.x * NL;
  float v[16];
  #pragma unroll
  for (int k=0;k<16;k++) v[k] = xp[tid + k*256];
  float wr[9];
  #pragma unroll
  for (int i=0;i<9;i++) wr[i] = wf[WF_C2W + d*9 + i];
  float bb = wf[WF_C2B + d];
  __syncthreads();
  #pragma unroll
  for (int k=0;k<16;k++){
    int i = tid + k*256;
    int h = i>>6, w = i&63;
    xs[(h+1)*69 + (w+1)] = v[k];
  }
  __syncthreads();
  float* op = xmc + (size_t)blockIdx.x * NL;
  #pragma unroll
  for (int g=0; g<4; g++){
    int p = g*1024 + tid*4;
    int h = p>>6, w0 = p&63;
    float a[4];
    #pragma unroll
    for (int i=0;i<4;i++) a[i]=bb;
    #pragma unroll
    for (int dy=0; dy<3; dy++){
      float s[6];
      #pragma unroll
      for (int j=0;j<6;j++) s[j] = xs[(h+dy)*69 + w0 + j];
      #pragma unroll
      for (int dx=0;dx<3;dx++){
        float wv = wr[dy*3+dx];
        #pragma unroll
        for (int i=0;i<4;i++) a[i] += s[dx+i]*wv;
      }
    }
    float4 o;
    o.x = a[0]/(1.f+__expf(-a[0]));
    o.y = a[1]/(1.f+__expf(-a[1]));
    o.z = a[2]/(1.f+__expf(-a[2]));
    o.w = a[3]/(1.f+__expf(-a[3]));
    *(float4*)(op+p) = o;
  }
}

// ---------------- K6 (slim): x_proj (128->36); grid 256; J=9,P=2 ----------------
__global__ __launch_bounds__(256) void k6_xproj(const float* __restrict__ xmc, const float* __restrict__ wf,
                                                float* __restrict__ Bm, float* __restrict__ Cm,
                                                float* __restrict__ dtm){
  int b = blockIdx.x >> 5, pt = blockIdx.x & 31;
  int jslot = threadIdx.x >> 6, pxslot = threadIdx.x & 63;
  __shared__ float wlds[36][128];
  __shared__ float xs[32][128];
  {
    const float4* Wg = (const float4*)(wf + WF_XPW);
    float4* Wl = (float4*)&wlds[0][0];
    for (int i = threadIdx.x; i < 1152; i += 256) Wl[i] = Wg[i];
  }
  float acc[9][2];
  #pragma unroll
  for (int j=0;j<9;j++){ acc[j][0]=0.f; acc[j][1]=0.f; }
  const float* ubase = xmc + (size_t)b*128*NL + pt*128;
  for (int ch = 0; ch < 4; ch++){
    __syncthreads();
    for (int i = threadIdx.x; i < 1024; i += 256){
      int r = i >> 5, c4 = i & 31;
      ((float4*)&xs[r][0])[c4] = *(const float4*)(ubase + (size_t)(ch*32+r)*NL + c4*4);
    }
    __syncthreads();
    #pragma unroll 1
    for (int c = 0; c < 32; c++){
      float a0 = xs[c][pxslot];
      float a1 = xs[c][pxslot + 64];
      #pragma unroll
      for (int j=0;j<9;j++){
        float w = wlds[jslot*9+j][ch*32+c];
        acc[j][0] += w*a0;
        acc[j][1] += w*a1;
      }
    }
  }
  #pragma unroll
  for (int j=0;j<9;j++){
    int o = jslot*9 + j;
    float* dp;
    if (o < 4)       dp = dtm + ((size_t)b*4 + o)*NL;
    else if (o < 20) dp = Bm  + ((size_t)b*16 + (o-4))*NL;
    else             dp = Cm  + ((size_t)b*16 + (o-20))*NL;
    dp[pt*128 + pxslot]      = acc[j][0];
    dp[pt*128 + pxslot + 64] = acc[j][1];
  }
}

// ---------------- K7: scan pass1 — pixel-major B/dt in LDS (float4 broadcast reads) ----------------
__global__ __launch_bounds__(128) void k7_scan1(const float* __restrict__ xmc, const float* __restrict__ Bm,
                                                const float* __restrict__ dtm, const float* __restrict__ wf,
                                                float* __restrict__ Ac, float* __restrict__ Bc){
  int k = blockIdx.x & (NKCH-1), b = blockIdx.x >> 7;
  int d = threadIdx.x;
  int l0 = k*CHUNK;
  __shared__ float xs[128*33];
  __shared__ float Bl2[32*20];      // [l][n], stride 20 (float4-aligned)
  __shared__ float dtl2[32*4];      // [l][n]
  float vx[32], vb[4], vd;
  #pragma unroll
  for (int j=0;j<32;j++){
    int i = d + 128*j;
    int ch = i >> 5, px = i & 31;
    vx[j] = xmc[((size_t)b*128+ch)*NL + l0 + px];
  }
  #pragma unroll
  for (int j=0;j<4;j++){
    int i = d + 128*j;
    int n = i >> 5, li = i & 31;
    vb[j] = Bm[((size_t)b*16+n)*NL + l0 + li];
  }
  { int n = d >> 5, li = d & 31; vd = dtm[((size_t)b*4+n)*NL + l0 + li]; }
  #pragma unroll
  for (int j=0;j<32;j++){
    int i = d + 128*j;
    int ch = i >> 5, px = i & 31;
    xs[ch*33+px] = vx[j];
  }
  #pragma unroll
  for (int j=0;j<4;j++){
    int i = d + 128*j;
    int n = i >> 5, li = i & 31;
    Bl2[li*20+n] = vb[j];
  }
  { int n = d >> 5, li = d & 31; dtl2[li*4+n] = vd; }
  float A[16], P[16], Q[16];
  const float* Af = wf + WF_A + d*16;
  #pragma unroll
  for (int n=0;n<16;n++){ A[n]=Af[n]; P[n]=1.f; Q[n]=0.f; }
  float w0 = wf[WF_DTW+d*4], w1 = wf[WF_DTW+d*4+1], w2 = wf[WF_DTW+d*4+2], w3 = wf[WF_DTW+d*4+3];
  float db2 = 2.f*wf[WF_DTB+d];
  __syncthreads();
  for (int l=0; l<CHUNK; l++){
    float4 dt4 = ((const float4*)dtl2)[l];
    float tt = w0*dt4.x + w1*dt4.y + w2*dt4.z + w3*dt4.w + db2;
    float de = tt > 20.f ? tt : __logf(1.f+__expf(tt));
    float du = de * xs[d*33+l];
    const float4* bp = (const float4*)(Bl2 + l*20);
    float4 b0 = bp[0], b1 = bp[1], b2 = bp[2], b3 = bp[3];
    float bb[16] = {b0.x,b0.y,b0.z,b0.w, b1.x,b1.y,b1.z,b1.w,
                    b2.x,b2.y,b2.z,b2.w, b3.x,b3.y,b3.z,b3.w};
    #pragma unroll
    for (int n=0;n<16;n++){
      float a = __expf(de*A[n]);
      P[n] *= a;
      Q[n] = a*Q[n] + du*bb[n];
    }
  }
  size_t base = (((size_t)k*NB + b)*128 + d)*16;
  #pragma unroll
  for (int i=0;i<4;i++){
    ((float4*)(Ac+base))[i] = make_float4(P[i*4],P[i*4+1],P[i*4+2],P[i*4+3]);
    ((float4*)(Bc+base))[i] = make_float4(Q[i*4],Q[i*4+1],Q[i*4+2],Q[i*4+3]);
  }
}

// ---------------- K8: middle scan ----------------
__global__ __launch_bounds__(256) void k8_mid(const float* __restrict__ Ac, const float* __restrict__ Bc,
                                              float* __restrict__ Hi){
  int idx = blockIdx.x*256 + threadIdx.x;
  float h = 0.f;
  for (int k0=0;k0<NKCH;k0+=16){
    float av[16], bv[16];
    #pragma unroll
    for (int j=0;j<16;j++){
      size_t o = (size_t)(k0+j)*16384 + idx;
      av[j]=Ac[o]; bv[j]=Bc[o];
    }
    #pragma unroll
    for (int j=0;j<16;j++){
      size_t o = (size_t)(k0+j)*16384 + idx;
      Hi[o] = h;
      h = av[j]*h + bv[j];
    }
  }
}

// ---------------- K9: scan pass2 + fused LN*silu(z); pixel-major B/C/dt in LDS ----------------
__global__ __launch_bounds__(128) void k9_scan2(const float* __restrict__ xmc, const float* __restrict__ Bm,
                                                const float* __restrict__ Cm, const float* __restrict__ dtm,
                                                const float* __restrict__ z, const float* __restrict__ wf,
                                                const float* __restrict__ Hi, float* __restrict__ G){
  int k = blockIdx.x & (NKCH-1), b = blockIdx.x >> 7;
  int d = threadIdx.x;
  int l0 = k*CHUNK;
  __shared__ float xs[128*33];
  __shared__ float Bl2[32*20], Cl2[32*20];
  __shared__ float dtl2[32*4];
  __shared__ float red[4][32][2];
  __shared__ float mstat[32], rstat[32];
  float vx[32], vb[4], vc[4], vd;
  #pragma unroll
  for (int j=0;j<32;j++){
    int i = d + 128*j;
    int ch = i >> 5, px = i & 31;
    vx[j] = xmc[((size_t)b*128+ch)*NL + l0 + px];
  }
  #pragma unroll
  for (int j=0;j<4;j++){
    int i = d + 128*j;
    int n = i >> 5, li = i & 31;
    vb[j] = Bm[((size_t)b*16+n)*NL + l0 + li];
    vc[j] = Cm[((size_t)b*16+n)*NL + l0 + li];
  }
  { int n = d >> 5, li = d & 31; vd = dtm[((size_t)b*4+n)*NL + l0 + li]; }
  float A[16], h[16];
  const float* Af = wf + WF_A + d*16;
  size_t hb = (((size_t)k*NB + b)*128 + d)*16;
  #pragma unroll
  for (int n=0;n<16;n++){ A[n]=Af[n]; h[n]=Hi[hb+n]; }
  #pragma unroll
  for (int j=0;j<32;j++){
    int i = d + 128*j;
    int ch = i >> 5, px = i & 31;
    xs[ch*33+px] = vx[j];
  }
  #pragma unroll
  for (int j=0;j<4;j++){
    int i = d + 128*j;
    int n = i >> 5, li = i & 31;
    Bl2[li*20+n] = vb[j];
    Cl2[li*20+n] = vc[j];
  }
  { int n = d >> 5, li = d & 31; dtl2[li*4+n] = vd; }
  float Dv = wf[WF_DP + d];
  float w0 = wf[WF_DTW+d*4], w1 = wf[WF_DTW+d*4+1], w2 = wf[WF_DTW+d*4+2], w3 = wf[WF_DTW+d*4+3];
  float db2 = 2.f*wf[WF_DTB+d];
  __syncthreads();
  for (int l=0; l<CHUNK; l++){
    float4 dt4 = ((const float4*)dtl2)[l];
    float tt = w0*dt4.x + w1*dt4.y + w2*dt4.z + w3*dt4.w + db2;
    float de = tt > 20.f ? tt : __logf(1.f+__expf(tt));
    float uu = xs[d*33+l];
    float du = de * uu;
    float yv = uu * Dv;
    const float4* bp = (const float4*)(Bl2 + l*20);
    const float4* cp = (const float4*)(Cl2 + l*20);
    float4 b0 = bp[0], b1 = bp[1], b2 = bp[2], b3 = bp[3];
    float4 c0 = cp[0], c1 = cp[1], c2 = cp[2], c3 = cp[3];
    float bb[16] = {b0.x,b0.y,b0.z,b0.w, b1.x,b1.y,b1.z,b1.w,
                    b2.x,b2.y,b2.z,b2.w, b3.x,b3.y,b3.z,b3.w};
    float cc[16] = {c0.x,c0.y,c0.z,c0.w, c1.x,c1.y,c1.z,c1.w,
                    c2.x,c2.y,c2.z,c2.w, c3.x,c3.y,c3.z,c3.w};
    #pragma unroll
    for (int n=0;n<16;n++){
      float a = __expf(de*A[n]);
      h[n] = a*h[n] + du*bb[n];
      yv  += h[n]*cc[n];
    }
    xs[d*33+l] = yv;
  }
  __syncthreads();
  {
    int px = d & 31, q = d >> 5;
    float s=0.f, qq=0.f;
    #pragma unroll
    for (int j=0;j<32;j++){ float v = xs[(q*32+j)*33+px]; s+=v; qq+=v*v; }
    red[q][px][0]=s; red[q][px][1]=qq;
  }
  __syncthreads();
  if (d < 32){
    float ss = red[0][d][0]+red[1][d][0]+red[2][d][0]+red[3][d][0];
    float sq = red[0][d][1]+red[1][d][1]+red[2][d][1]+red[3][d][1];
    float m = ss*(1.f/128.f);
    mstat[d] = m;
    rstat[d] = rsqrtf(sq*(1.f/128.f) - m*m + 1e-5f);
  }
  __syncthreads();
  float ow = wf[WF_ONW+d], ob = wf[WF_ONB+d];
  const float* zp = z + ((size_t)b*128+d)*NL + l0;
  float* gp = G + ((size_t)b*128+d)*NL + l0;
  #pragma unroll
  for (int l4=0; l4<CHUNK/4; l4++){
    float4 zv4 = ((const float4*)zp)[l4];
    float zv[4] = {zv4.x, zv4.y, zv4.z, zv4.w};
    float out[4];
    #pragma unroll
    for (int j=0;j<4;j++){
      int l = l4*4+j;
      float t = (xs[d*33+l]-mstat[l])*rstat[l]*ow + ob;
      out[j] = t * (zv[j]/(1.f+__expf(-zv[j])));
    }
    ((float4*)gp)[l4] = make_float4(out[0],out[1],out[2],out[3]);
  }
}

// ---------------- K11A: yc = W_comb @ G + cf_b. og2 x b8 x pt32 = 512; J=4,P=4; + stats ----------------
__global__ __launch_bounds__(256) void k11A_proj(const float* __restrict__ G, const float* __restrict__ wf,
                                                 const float* __restrict__ wcomb,
                                                 float* __restrict__ yc, float* __restrict__ part){
  int og = blockIdx.x >> 8, rem = blockIdx.x & 255;
  int b = rem >> 5, pt = rem & 31;
  int jslot = threadIdx.x >> 5, pxslot = threadIdx.x & 31;
  __shared__ float wlds[32][128];
  __shared__ float xs[32][128];
  {
    const float4* Wg = (const float4*)(wcomb + og*32*128);
    float4* Wl = (float4*)&wlds[0][0];
    for (int i = threadIdx.x; i < 1024; i += 256) Wl[i] = Wg[i];
  }
  float acc[4][4];
  #pragma unroll
  for (int j=0;j<4;j++)
    #pragma unroll
    for (int p=0;p<4;p++) acc[j][p]=0.f;
  const float* gbase = G + (size_t)b*128*NL + pt*128;
  for (int ch = 0; ch < 4; ch++){
    __syncthreads();
    for (int i = threadIdx.x; i < 1024; i += 256){
      int r = i >> 5, c4 = i & 31;
      ((float4*)&xs[r][0])[c4] = *(const float4*)(gbase + (size_t)(ch*32+r)*NL + c4*4);
    }
    __syncthreads();
    #pragma unroll 1
    for (int c = 0; c < 32; c++){
      float a[4];
      #pragma unroll
      for (int p=0;p<4;p++) a[p] = xs[c][pxslot + 32*p];
      #pragma unroll
      for (int jj=0;jj<4;jj++){
        float w = wlds[jslot*4+jj][ch*32+c];
        #pragma unroll
        for (int p=0;p<4;p++) acc[jj][p] += w*a[p];
      }
    }
  }
  #pragma unroll
  for (int jj=0;jj<4;jj++){
    int cc = og*32 + jslot*4 + jj;
    float bias = wf[WF_CFB + cc];
    float* dp = yc + (size_t)b*64*NL + (size_t)cc*NL + pt*128;
    float sv = 0.f, qv = 0.f;
    #pragma unroll
    for (int p=0;p<4;p++){
      float t = acc[jj][p] + bias;
      dp[pxslot + 32*p] = t;
      sv += t; qv += t*t;
    }
    #pragma unroll
    for (int o=16;o>0;o>>=1){ sv += __shfl_xor(sv,o); qv += __shfl_xor(qv,o); }
    if (pxslot == 0){
      size_t pidx = (((size_t)b*64 + cc)*32 + pt)*2;
      part[pidx] = sv; part[pidx+1] = qv;
    }
  }
}

// ---------------- K11b: finalize per-(b,c) mean/rsqrt (32 partials each) ----------------
__global__ __launch_bounds__(256) void k11b_stats(const float* __restrict__ part, float* __restrict__ stats){
  int i = blockIdx.x*256 + threadIdx.x;
  if (i >= 512) return;
  float s=0.f, q=0.f;
  #pragma unroll
  for (int t2=0;t2<32;t2++){ s += part[((size_t)i*32+t2)*2]; q += part[((size_t)i*32+t2)*2+1]; }
  float m = s*(1.f/NL), va = q*(1.f/NL) - m*m;
  stats[i*2] = m; stats[i*2+1] = rsqrtf(va+1e-5f);
}

// ---------------- K11c: out = x1 + inorm(yc) ----------------
__global__ __launch_bounds__(256) void k11c_final(const float* __restrict__ yc, const float* __restrict__ stats,
                                                  const float* __restrict__ x1, float* __restrict__ out){
  int bc = blockIdx.x;
  float m = stats[bc*2], rs = stats[bc*2+1];
  size_t base = (size_t)bc*NL;
  for (int i=threadIdx.x;i<NL;i+=256){
    float v = (yc[base+i]-m)*rs;
    out[base+i] = x1[base+i] + v;
  }
}

// ---------------- host ----------------
extern "C" void kernel_launch(void* const* d_in, const int* in_sizes, int n_in,
                              void* d_out, int out_size, void* d_ws, size_t ws_size,
                              hipStream_t stream) {
  if (ws_size < WS_NEED_FLOATS * sizeof(float)) return;
  const float* x     = (const float*)d_in[0];
  const float* dw3w  = (const float*)d_in[1];
  const float* dw3b  = (const float*)d_in[2];
  const float* dw5w  = (const float*)d_in[3];
  const float* dw5b  = (const float*)d_in[4];
  const float* dw7w  = (const float*)d_in[5];
  const float* dw7b  = (const float*)d_in[6];
  const float* fusew = (const float*)d_in[7];
  const float* fuseb = (const float*)d_in[8];
  const float* inpjw = (const float*)d_in[9];
  const float* c2w   = (const float*)d_in[10];
  const float* c2b   = (const float*)d_in[11];
  const float* xpw   = (const float*)d_in[12];
  const float* dtw   = (const float*)d_in[13];
  const float* dtb   = (const float*)d_in[14];
  const float* alog  = (const float*)d_in[15];
  const float* dpv   = (const float*)d_in[16];
  const float* onw   = (const float*)d_in[17];
  const float* onb   = (const float*)d_in[18];
  const float* opw   = (const float*)d_in[19];
  const float* cfw   = (const float*)d_in[20];
  const float* cfb   = (const float*)d_in[21];

  float* ws    = (float*)d_ws;
  float* wf    = ws + OFF_WF;
  float* wcomb = ws + OFF_WCOMB;
  float* feats = ws + OFF_FEATS;
  float* xf    = ws + OFF_XF;
  float* x1    = ws + OFF_X1;
  float* xmraw = ws + OFF_XMRAW;
  float* z     = ws + OFF_Z;
  float* xmc   = ws + OFF_XMC;
  float* Bmw   = ws + OFF_BMAT;
  float* Cmw   = ws + OFF_CMAT;
  float* dtm   = ws + OFF_DTM;
  float* Acb   = ws + OFF_AC;
  float* Bcb   = ws + OFF_BC;
  float* Hi    = ws + OFF_HINIT;
  float* G     = ws + OFF_G;
  float* yc    = ws + OFF_YC;
  float* part  = ws + OFF_PART;
  float* stats = ws + OFF_STATS;

  CvtArgs ca; int ns = 0;
  auto add = [&](const float* s, int off, int n, int op){
    ca.d[ns].src = s; ca.d[ns].dst = wf + off; ca.d[ns].n = n; ca.d[ns].op = op; ns++;
  };
  add(dw3w, WF_DW3, 576, 0);   add(dw5w, WF_DW5, 1600, 0);  add(dw7w, WF_DW7, 3136, 0);
  add(dw3b, WF_B3, 64, 0);     add(dw5b, WF_B5, 64, 0);     add(dw7b, WF_B7, 64, 0);
  add(fusew, WF_FUSE, 12288, 0); add(fuseb, WF_FUSEB, 64, 0);
  add(c2w, WF_C2W, 1152, 0);   add(c2b, WF_C2B, 128, 0);
  add(xpw, WF_XPW, 4608, 0);   add(dtw, WF_DTW, 512, 0);    add(dtb, WF_DTB, 128, 0);
  add(alog, WF_A, 2048, 1);    // A = -exp(A_log)
  add(dpv, WF_DP, 128, 0);
  add(onw, WF_ONW, 128, 0);    add(onb, WF_ONB, 128, 0);
  add(opw, WF_OPW, 8192, 0);
  add(cfw, WF_CFW, 4096, 0);   add(cfb, WF_CFB, 64, 0);
  add(inpjw, WF_INPJ, 16384, 0);
  ca.ncvt = ns; ca.cfw = cfw; ca.opw = opw; ca.wcomb = wcomb;

  k0_cvt<<<ns + 32, 256, 0, stream>>>(ca);
  k1_dw<<<1024, 256, 0, stream>>>(x, wf, feats, part);
  k2_fuse<<<512, 256, 0, stream>>>(feats, part, wf, xf);
  k3_norm<<<512, 256, 0, stream>>>(xf, x, x1);
  k4_inproj<<<1024, 256, 0, stream>>>(x1, wf, xmraw, z);
  k5_dw3<<<1024, 256, 0, stream>>>(xmraw, wf, xmc);
  k6_xproj<<<256, 256, 0, stream>>>(xmc, wf, Bmw, Cmw, dtm);
  k7_scan1<<<1024, 128, 0, stream>>>(xmc, Bmw, dtm, wf, Acb, Bcb);
  k8_mid<<<64, 256, 0, stream>>>(Acb, Bcb, Hi);
  k9_scan2<<<1024, 128, 0, stream>>>(xmc, Bmw, Cmw, dtm, z, wf, Hi, G);
  k11A_proj<<<512, 256, 0, stream>>>(G, wf, wcomb, yc, part);
  k11b_stats<<<2, 256, 0, stream>>>(part, stats);
  k11c_final<<<512, 256, 0, stream>>>(yc, stats, x1, (float*)d_out);
}

// Round 13
// 212.699 us; speedup vs baseline: 3.2021x; 1.0042x over previous
//
#include <hip/hip_runtime.h>
#include <math.h>

#define NB 8
#define NC 64
#define NL 4096
#define NDI 128
#define NN 16
#define CHUNK 32
#define NKCH 128   // NL / CHUNK

// ---------------- workspace layout (float offsets) ----------------
#define OFF_FEATS 0ull
#define OFF_AC    0ull
#define OFF_BC    2097152ull
#define OFF_HINIT 4194304ull
#define OFF_XF    6291456ull
#define OFF_BMAT  6291456ull
#define OFF_CMAT  6815744ull
#define OFF_X1    8388608ull
#define OFF_XMRAW 10485760ull
#define OFF_G     10485760ull
#define OFF_Z     14680064ull
#define OFF_YC    14680064ull
#define OFF_PART  16777216ull
#define OFF_STATS 16809984ull
#define OFF_XMC   18874368ull
#define OFF_DTM   23068672ull   // 131072
#define OFF_SEGP  23199744ull   // 131072
#define OFF_SEGQ  23330816ull   // 131072
#define OFF_SEGH  23461888ull   // 131072
#define OFF_WF    27262976ull
#define OFF_NSTAT (OFF_WF + 55552ull)
#define OFF_WCOMB (OFF_WF + 58624ull)
#define WS_NEED_FLOATS (OFF_WF + 66816ull)

// weight sub-offsets inside WF (floats)
#define WF_DW3    0
#define WF_DW5    576
#define WF_DW7    2176
#define WF_B3     5312
#define WF_B5     5376
#define WF_B7     5440
#define WF_FUSE   5504
#define WF_FUSEB  17792
#define WF_C2W    17856
#define WF_C2B    19008
#define WF_XPW    19136
#define WF_DTW    23744
#define WF_DTB    24256
#define WF_A      24384
#define WF_DP     26432
#define WF_ONW    26560
#define WF_ONB    26688
#define WF_OPW    26816
#define WF_CFW    35008
#define WF_CFB    39104
#define WF_INPJ   39168

// ---------------- K0 ----------------
struct Cvt { const float* src; float* dst; int n; int op; };
struct CvtArgs { Cvt d[22]; int ncvt; const float* cfw; const float* opw; float* wcomb; };

__global__ __launch_bounds__(256) void k0_cvt(CvtArgs a){
  if ((int)blockIdx.x < a.ncvt){
    Cvt c = a.d[blockIdx.x];
    for (int i = threadIdx.x; i < c.n; i += 256){
      float v = c.src[i];
      c.dst[i] = c.op ? -expf(v) : v;
    }
  } else {
    int idx = (blockIdx.x - a.ncvt)*256 + threadIdx.x;
    int c = idx >> 7, kk = idx & 127;
    float s = 0.f;
    #pragma unroll
    for (int j=0;j<64;j++) s += a.cfw[c*64+j] * a.opw[j*128+kk];
    a.wcomb[idx] = s;
  }
}

// ---------------- K1: dw convs, 2 row-halves per plane; grid 1024; reg-batched staging ----------------
__global__ __launch_bounds__(256) void k1_dw(const float* __restrict__ x, const float* __restrict__ wf,
                                             float* __restrict__ feats, float* __restrict__ part){
  const int half = blockIdx.x & 1, c = (blockIdx.x >> 1) & 63, b = blockIdx.x >> 7;
  const int tid = threadIdx.x;
  const int r0 = half*32;
  __shared__ float xs[38*73];
  __shared__ float red[4][6];
  for (int i = tid; i < 38*73; i += 256) xs[i] = 0.f;
  const float* xp = x + ((size_t)b*64 + c)*NL;
  float v[10];
  #pragma unroll
  for (int k=0;k<10;k++){
    int idx = tid + k*256;
    int j = idx >> 6, w = idx & 63;
    int gr = r0 - 3 + j;
    bool ok = (idx < 2432) && (gr >= 0) && (gr < 64);
    v[k] = ok ? xp[gr*64 + w] : 0.f;
  }
  float w3r[9], w5r[25], w7r[49];
  #pragma unroll
  for (int i=0;i<9;i++)  w3r[i] = wf[WF_DW3 + c*9 + i];
  #pragma unroll
  for (int i=0;i<25;i++) w5r[i] = wf[WF_DW5 + c*25 + i];
  #pragma unroll
  for (int i=0;i<49;i++) w7r[i] = wf[WF_DW7 + c*49 + i];
  float b3 = wf[WF_B3+c], b5 = wf[WF_B5+c], b7 = wf[WF_B7+c];
  __syncthreads();
  #pragma unroll
  for (int k=0;k<10;k++){
    int idx = tid + k*256;
    if (idx < 2432){
      int j = idx >> 6, w = idx & 63;
      xs[j*73 + (w+3)] = v[k];
    }
  }
  __syncthreads();
  float s3=0,q3=0,s5=0,q5=0,s7=0,q7=0;
  float* f3 = feats + ((size_t)b*192 + c) * NL + r0*64;
  float* f5 = f3 + (size_t)64*NL;
  float* f7 = f3 + (size_t)128*NL;
  #pragma unroll
  for (int g=0; g<2; g++){
    int p = g*1024 + tid*4;
    int lh = p >> 6, w0 = p & 63;
    float a3[4], a5[4], a7[4];
    #pragma unroll
    for (int i=0;i<4;i++){ a3[i]=b3; a5[i]=b5; a7[i]=b7; }
    #pragma unroll
    for (int dy=0; dy<7; dy++){
      float s[10];
      #pragma unroll
      for (int j=0;j<10;j++) s[j] = xs[(lh+dy)*73 + w0 + j];
      #pragma unroll
      for (int dx=0;dx<7;dx++){
        float wv = w7r[dy*7+dx];
        #pragma unroll
        for (int i=0;i<4;i++) a7[i] += s[dx+i]*wv;
      }
      if (dy>=1 && dy<=5){
        #pragma unroll
        for (int dx=0;dx<5;dx++){
          float wv = w5r[(dy-1)*5+dx];
          #pragma unroll
          for (int i=0;i<4;i++) a5[i] += s[dx+1+i]*wv;
        }
      }
      if (dy>=2 && dy<=4){
        #pragma unroll
        for (int dx=0;dx<3;dx++){
          float wv = w3r[(dy-2)*3+dx];
          #pragma unroll
          for (int i=0;i<4;i++) a3[i] += s[dx+2+i]*wv;
        }
      }
    }
    *(float4*)(f3+p) = make_float4(a3[0],a3[1],a3[2],a3[3]);
    *(float4*)(f5+p) = make_float4(a5[0],a5[1],a5[2],a5[3]);
    *(float4*)(f7+p) = make_float4(a7[0],a7[1],a7[2],a7[3]);
    #pragma unroll
    for (int i=0;i<4;i++){
      s3+=a3[i]; q3+=a3[i]*a3[i];
      s5+=a5[i]; q5+=a5[i]*a5[i];
      s7+=a7[i]; q7+=a7[i]*a7[i];
    }
  }
  int wid = tid>>6, lane = tid&63;
  float v6[6]={s3,q3,s5,q5,s7,q7};
  #pragma unroll
  for (int j=0;j<6;j++){
    float t = v6[j];
    #pragma unroll
    for (int o=32;o>0;o>>=1) t += __shfl_down(t,o);
    if (!lane) red[wid][j]=t;
  }
  __syncthreads();
  if (tid < 3){
    float su = red[0][tid*2]+red[1][tid*2]+red[2][tid*2]+red[3][tid*2];
    float sq = red[0][tid*2+1]+red[1][tid*2+1]+red[2][tid*2+1]+red[3][tid*2+1];
    size_t k = (size_t)(b*192 + tid*64 + c)*4 + half*2;
    part[k]   = su;
    part[k+1] = sq;
  }
}

// ---------------- K2: fuse 1x1 (192->64). og2 x b8 x pt32 = 512; transposed weights [k][o] ----------------
__global__ __launch_bounds__(256) void k2_fuse(const float* __restrict__ feats, const float* __restrict__ npart,
                                               const float* __restrict__ wf, float* __restrict__ xf){
  int og = blockIdx.x >> 8, rem = blockIdx.x & 255;
  int b = rem >> 5, pt = rem & 31;
  int jslot = threadIdx.x >> 5, pxslot = threadIdx.x & 31;
  __shared__ float wlds2[192][44];   // [k][o], 33.8 KB
  __shared__ float xs[32][128];
  __shared__ float msl[192], rsl[192];
  for (int i = threadIdx.x; i < 192; i += 256){
    const float* pp = npart + (size_t)(b*192+i)*4;
    float su = pp[0]+pp[2], sq = pp[1]+pp[3];
    float m = su*(1.f/NL);
    msl[i] = m;
    rsl[i] = rsqrtf(sq*(1.f/NL) - m*m + 1e-5f);
  }
  {
    const float* Wg = wf + WF_FUSE + og*32*192;
    for (int i = threadIdx.x; i < 6144; i += 256){
      int o = i / 192, k = i % 192;
      wlds2[k][o] = Wg[i];
    }
  }
  float acc[4][4];
  #pragma unroll
  for (int j=0;j<4;j++)
    #pragma unroll
    for (int p=0;p<4;p++) acc[j][p]=0.f;
  const float* fbase = feats + (size_t)b*192*NL + pt*128;
  for (int ch = 0; ch < 6; ch++){
    __syncthreads();
    for (int i = threadIdx.x; i < 1024; i += 256){
      int r = i >> 5, c4 = i & 31;
      int k = ch*32 + r;
      float4 f = *(const float4*)(fbase + (size_t)k*NL + c4*4);
      float m = msl[k], rs = rsl[k];
      float v0=(f.x-m)*rs, v1=(f.y-m)*rs, v2=(f.z-m)*rs, v3=(f.w-m)*rs;
      v0 = v0>0.f?v0:0.01f*v0; v1 = v1>0.f?v1:0.01f*v1;
      v2 = v2>0.f?v2:0.01f*v2; v3 = v3>0.f?v3:0.01f*v3;
      ((float4*)&xs[r][0])[c4] = make_float4(v0,v1,v2,v3);
    }
    __syncthreads();
    #pragma unroll 1
    for (int c = 0; c < 32; c++){
      float a[4];
      #pragma unroll
      for (int p=0;p<4;p++) a[p] = xs[c][pxslot + 32*p];
      float4 w4 = *(const float4*)&wlds2[ch*32+c][jslot*4];
      float wv[4] = {w4.x, w4.y, w4.z, w4.w};
      #pragma unroll
      for (int jj=0;jj<4;jj++)
        #pragma unroll
        for (int p=0;p<4;p++) acc[jj][p] += wv[jj]*a[p];
    }
  }
  #pragma unroll
  for (int jj=0;jj<4;jj++){
    int o = og*32 + jslot*4 + jj;
    float bias = wf[WF_FUSEB + o];
    float* dp = xf + (size_t)b*64*NL + (size_t)o*NL + pt*128;
    #pragma unroll
    for (int p=0;p<4;p++) dp[pxslot + 32*p] = acc[jj][p] + bias;
  }
}

// ---------------- K3: inorm(xf)+lrelu + x -> x1 ----------------
__global__ __launch_bounds__(256) void k3_norm(const float* __restrict__ xf, const float* __restrict__ x,
                                               float* __restrict__ x1){
  const int tid = threadIdx.x;
  const size_t base = (size_t)blockIdx.x * NL;
  float loc[16]; float s=0.f, q=0.f;
  #pragma unroll
  for (int i=0;i<16;i++){ float v = xf[base + tid + i*256]; loc[i]=v; s+=v; q+=v*v; }
  __shared__ float red[4][2];
  int wid = tid>>6, lane = tid&63;
  #pragma unroll
  for (int o=32;o>0;o>>=1){ s += __shfl_down(s,o); q += __shfl_down(q,o); }
  if (!lane){ red[wid][0]=s; red[wid][1]=q; }
  __syncthreads();
  s = red[0][0]+red[1][0]+red[2][0]+red[3][0];
  q = red[0][1]+red[1][1]+red[2][1]+red[3][1];
  float m = s*(1.f/NL), va = q*(1.f/NL)-m*m, rs = rsqrtf(va+1e-5f);
  #pragma unroll
  for (int i=0;i<16;i++){
    int idx = tid + i*256;
    float v = (loc[i]-m)*rs;
    v = v>0.f ? v : 0.01f*v;
    x1[base+idx] = v + x[base+idx];
  }
}

// ---------------- K4: in_proj (64->256). og4 x b8 x pt32 = 1024; transposed weights ----------------
__global__ __launch_bounds__(256) void k4_inproj(const float* __restrict__ x1, const float* __restrict__ wf,
                                                 float* __restrict__ xmraw, float* __restrict__ z){
  int og = blockIdx.x >> 8, rem = blockIdx.x & 255;
  int b = rem >> 5, pt = rem & 31;
  int jslot = threadIdx.x >> 5, pxslot = threadIdx.x & 31;
  __shared__ float wlds2[64][76];   // [k][o], 19.5 KB
  __shared__ float xs[32][128];
  {
    const float* Wg = wf + WF_INPJ + og*64*64;
    for (int i = threadIdx.x; i < 4096; i += 256){
      int o = i >> 6, k = i & 63;
      wlds2[k][o] = Wg[i];
    }
  }
  float acc[8][4];
  #pragma unroll
  for (int j=0;j<8;j++)
    #pragma unroll
    for (int p=0;p<4;p++) acc[j][p]=0.f;
  const float* xbase = x1 + (size_t)b*64*NL + pt*128;
  for (int ch = 0; ch < 2; ch++){
    __syncthreads();
    for (int i = threadIdx.x; i < 1024; i += 256){
      int r = i >> 5, c4 = i & 31;
      ((float4*)&xs[r][0])[c4] = *(const float4*)(xbase + (size_t)(ch*32+r)*NL + c4*4);
    }
    __syncthreads();
    #pragma unroll 1
    for (int c = 0; c < 32; c++){
      float a[4];
      #pragma unroll
      for (int p=0;p<4;p++) a[p] = xs[c][pxslot + 32*p];
      const float4* wp = (const float4*)&wlds2[ch*32+c][jslot*8];
      float4 w0 = wp[0], w1 = wp[1];
      float wv[8] = {w0.x,w0.y,w0.z,w0.w, w1.x,w1.y,w1.z,w1.w};
      #pragma unroll
      for (int jj=0;jj<8;jj++)
        #pragma unroll
        for (int p=0;p<4;p++) acc[jj][p] += wv[jj]*a[p];
    }
  }
  float* dstbase = (og < 2 ? xmraw + (size_t)b*128*NL + (size_t)(og*64)*NL
                           : z     + (size_t)b*128*NL + (size_t)((og-2)*64)*NL) + pt*128;
  #pragma unroll
  for (int jj=0;jj<8;jj++){
    float* dp = dstbase + (size_t)(jslot*8+jj)*NL;
    #pragma unroll
    for (int p=0;p<4;p++) dp[pxslot + 32*p] = acc[jj][p];
  }
}

// ---------------- K5: depthwise 3x3 + silu (stride 69; reg-batched staging) ----------------
__global__ __launch_bounds__(256) void k5_dw3(const float* __restrict__ xmraw, const float* __restrict__ wf,
                                              float* __restrict__ xmc){
  const int d = blockIdx.x & 127;
  const int tid = threadIdx.x;
  __shared__ float xs[66*69];
  for (int i=tid;i<66*69;i+=256) xs[i]=0.f;
  const float* xp = xmraw + (size_t)blockIdx.x * NL;
  float v[16];
  #pragma unroll
  for (int k=0;k<16;k++) v[k] = xp[tid + k*256];
  float wr[9];
  #pragma unroll
  for (int i=0;i<9;i++) wr[i] = wf[WF_C2W + d*9 + i];
  float bb = wf[WF_C2B + d];
  __syncthreads();
  #pragma unroll
  for (int k=0;k<16;k++){
    int i = tid + k*256;
    int h = i>>6, w = i&63;
    xs[(h+1)*69 + (w+1)] = v[k];
  }
  __syncthreads();
  float* op = xmc + (size_t)blockIdx.x * NL;
  #pragma unroll
  for (int g=0; g<4; g++){
    int p = g*1024 + tid*4;
    int h = p>>6, w0 = p&63;
    float a[4];
    #pragma unroll
    for (int i=0;i<4;i++) a[i]=bb;
    #pragma unroll
    for (int dy=0; dy<3; dy++){
      float s[6];
      #pragma unroll
      for (int j=0;j<6;j++) s[j] = xs[(h+dy)*69 + w0 + j];
      #pragma unroll
      for (int dx=0;dx<3;dx++){
        float wv = wr[dy*3+dx];
        #pragma unroll
        for (int i=0;i<4;i++) a[i] += s[dx+i]*wv;
      }
    }
    float4 o;
    o.x = a[0]/(1.f+__expf(-a[0]));
    o.y = a[1]/(1.f+__expf(-a[1]));
    o.z = a[2]/(1.f+__expf(-a[2]));
    o.w = a[3]/(1.f+__expf(-a[3]));
    *(float4*)(op+p) = o;
  }
}

// ---------------- K6 (slim): x_proj (128->36); grid 256; transposed weights, slot-padded ----------------
__global__ __launch_bounds__(256) void k6_xproj(const float* __restrict__ xmc, const float* __restrict__ wf,
                                                float* __restrict__ Bm, float* __restrict__ Cm,
                                                float* __restrict__ dtm){
  int b = blockIdx.x >> 5, pt = blockIdx.x & 31;
  int jslot = threadIdx.x >> 6, pxslot = threadIdx.x & 63;
  __shared__ float wlds2[128][52];   // [k][slot*12 + j], 26.6 KB
  __shared__ float xs[32][128];
  {
    const float* Wg = wf + WF_XPW;
    for (int i = threadIdx.x; i < 4608; i += 256){
      int o = i >> 7, k = i & 127;
      wlds2[k][(o/9)*12 + (o%9)] = Wg[i];
    }
  }
  float acc[9][2];
  #pragma unroll
  for (int j=0;j<9;j++){ acc[j][0]=0.f; acc[j][1]=0.f; }
  const float* ubase = xmc + (size_t)b*128*NL + pt*128;
  for (int ch = 0; ch < 4; ch++){
    __syncthreads();
    for (int i = threadIdx.x; i < 1024; i += 256){
      int r = i >> 5, c4 = i & 31;
      ((float4*)&xs[r][0])[c4] = *(const float4*)(ubase + (size_t)(ch*32+r)*NL + c4*4);
    }
    __syncthreads();
    #pragma unroll 1
    for (int c = 0; c < 32; c++){
      float a0 = xs[c][pxslot];
      float a1 = xs[c][pxslot + 64];
      const float* wr = &wlds2[ch*32+c][jslot*12];
      float4 wa = *(const float4*)wr;
      float4 wb = *(const float4*)(wr+4);
      float w8 = wr[8];
      float wv[9] = {wa.x,wa.y,wa.z,wa.w, wb.x,wb.y,wb.z,wb.w, w8};
      #pragma unroll
      for (int j=0;j<9;j++){
        acc[j][0] += wv[j]*a0;
        acc[j][1] += wv[j]*a1;
      }
    }
  }
  #pragma unroll
  for (int j=0;j<9;j++){
    int o = jslot*9 + j;
    float* dp;
    if (o < 4)       dp = dtm + ((size_t)b*4 + o)*NL;
    else if (o < 20) dp = Bm  + ((size_t)b*16 + (o-4))*NL;
    else             dp = Cm  + ((size_t)b*16 + (o-20))*NL;
    dp[pt*128 + pxslot]      = acc[j][0];
    dp[pt*128 + pxslot + 64] = acc[j][1];
  }
}

// ---------------- K7: scan pass1 — pixel-major B/dt in LDS ----------------
__global__ __launch_bounds__(128) void k7_scan1(const float* __restrict__ xmc, const float* __restrict__ Bm,
                                                const float* __restrict__ dtm, const float* __restrict__ wf,
                                                float* __restrict__ Ac, float* __restrict__ Bc){
  int k = blockIdx.x & (NKCH-1), b = blockIdx.x >> 7;
  int d = threadIdx.x;
  int l0 = k*CHUNK;
  __shared__ float xs[128*33];
  __shared__ float Bl2[32*20];
  __shared__ float dtl2[32*4];
  float vx[32], vb[4], vd;
  #pragma unroll
  for (int j=0;j<32;j++){
    int i = d + 128*j;
    int ch = i >> 5, px = i & 31;
    vx[j] = xmc[((size_t)b*128+ch)*NL + l0 + px];
  }
  #pragma unroll
  for (int j=0;j<4;j++){
    int i = d + 128*j;
    int n = i >> 5, li = i & 31;
    vb[j] = Bm[((size_t)b*16+n)*NL + l0 + li];
  }
  { int n = d >> 5, li = d & 31; vd = dtm[((size_t)b*4+n)*NL + l0 + li]; }
  #pragma unroll
  for (int j=0;j<32;j++){
    int i = d + 128*j;
    int ch = i >> 5, px = i & 31;
    xs[ch*33+px] = vx[j];
  }
  #pragma unroll
  for (int j=0;j<4;j++){
    int i = d + 128*j;
    int n = i >> 5, li = i & 31;
    Bl2[li*20+n] = vb[j];
  }
  { int n = d >> 5, li = d & 31; dtl2[li*4+n] = vd; }
  float A[16], P[16], Q[16];
  const float* Af = wf + WF_A + d*16;
  #pragma unroll
  for (int n=0;n<16;n++){ A[n]=Af[n]; P[n]=1.f; Q[n]=0.f; }
  float w0 = wf[WF_DTW+d*4], w1 = wf[WF_DTW+d*4+1], w2 = wf[WF_DTW+d*4+2], w3 = wf[WF_DTW+d*4+3];
  float db2 = 2.f*wf[WF_DTB+d];
  __syncthreads();
  for (int l=0; l<CHUNK; l++){
    float4 dt4 = ((const float4*)dtl2)[l];
    float tt = w0*dt4.x + w1*dt4.y + w2*dt4.z + w3*dt4.w + db2;
    float de = tt > 20.f ? tt : __logf(1.f+__expf(tt));
    float du = de * xs[d*33+l];
    const float4* bp = (const float4*)(Bl2 + l*20);
    float4 b0 = bp[0], b1 = bp[1], b2 = bp[2], b3 = bp[3];
    float bb[16] = {b0.x,b0.y,b0.z,b0.w, b1.x,b1.y,b1.z,b1.w,
                    b2.x,b2.y,b2.z,b2.w, b3.x,b3.y,b3.z,b3.w};
    #pragma unroll
    for (int n=0;n<16;n++){
      float a = __expf(de*A[n]);
      P[n] *= a;
      Q[n] = a*Q[n] + du*bb[n];
    }
  }
  size_t base = (((size_t)k*NB + b)*128 + d)*16;
  #pragma unroll
  for (int i=0;i<4;i++){
    ((float4*)(Ac+base))[i] = make_float4(P[i*4],P[i*4+1],P[i*4+2],P[i*4+3]);
    ((float4*)(Bc+base))[i] = make_float4(Q[i*4],Q[i*4+1],Q[i*4+2],Q[i*4+3]);
  }
}

// ---------------- K8a: per-segment reduce (8 segs x 16 chunks); grid 512 ----------------
__global__ __launch_bounds__(256) void k8a_seg(const float* __restrict__ Ac, const float* __restrict__ Bc,
                                               float* __restrict__ segP, float* __restrict__ segQ){
  int idx = (blockIdx.x & 63)*256 + threadIdx.x;
  int seg = blockIdx.x >> 6;
  float av[16], bv[16];
  #pragma unroll
  for (int j=0;j<16;j++){
    size_t o = (size_t)(seg*16+j)*16384 + idx;
    av[j]=Ac[o]; bv[j]=Bc[o];
  }
  float P = 1.f, Q = 0.f;
  #pragma unroll
  for (int j=0;j<16;j++){ Q = av[j]*Q + bv[j]; P *= av[j]; }
  segP[seg*16384+idx]=P; segQ[seg*16384+idx]=Q;
}

// ---------------- K8b: scan over 8 segments; grid 64 (short) ----------------
__global__ __launch_bounds__(256) void k8b_mid(const float* __restrict__ segP, const float* __restrict__ segQ,
                                               float* __restrict__ segH){
  int idx = blockIdx.x*256 + threadIdx.x;
  float p[8], q[8];
  #pragma unroll
  for (int s=0;s<8;s++){ p[s]=segP[s*16384+idx]; q[s]=segQ[s*16384+idx]; }
  float h = 0.f;
  #pragma unroll
  for (int s=0;s<8;s++){ segH[s*16384+idx]=h; h = p[s]*h + q[s]; }
}

// ---------------- K8c: emit chunk-entry states Hi; grid 512 ----------------
__global__ __launch_bounds__(256) void k8c_emit(const float* __restrict__ Ac, const float* __restrict__ Bc,
                                                const float* __restrict__ segH, float* __restrict__ Hi){
  int idx = (blockIdx.x & 63)*256 + threadIdx.x;
  int seg = blockIdx.x >> 6;
  float av[16], bv[16];
  #pragma unroll
  for (int j=0;j<16;j++){
    size_t o = (size_t)(seg*16+j)*16384 + idx;
    av[j]=Ac[o]; bv[j]=Bc[o];
  }
  float h = segH[seg*16384+idx];
  #pragma unroll
  for (int j=0;j<16;j++){
    size_t o = (size_t)(seg*16+j)*16384 + idx;
    Hi[o] = h;
    h = av[j]*h + bv[j];
  }
}

// ---------------- K9: scan pass2 + fused LN*silu(z); pixel-major B/C/dt in LDS ----------------
__global__ __launch_bounds__(128) void k9_scan2(const float* __restrict__ xmc, const float* __restrict__ Bm,
                                                const float* __restrict__ Cm, const float* __restrict__ dtm,
                                                const float* __restrict__ z, const float* __restrict__ wf,
                                                const float* __restrict__ Hi, float* __restrict__ G){
  int k = blockIdx.x & (NKCH-1), b = blockIdx.x >> 7;
  int d = threadIdx.x;
  int l0 = k*CHUNK;
  __shared__ float xs[128*33];
  __shared__ float Bl2[32*20], Cl2[32*20];
  __shared__ float dtl2[32*4];
  __shared__ float red[4][32][2];
  __shared__ float mstat[32], rstat[32];
  float vx[32], vb[4], vc[4], vd;
  #pragma unroll
  for (int j=0;j<32;j++){
    int i = d + 128*j;
    int ch = i >> 5, px = i & 31;
    vx[j] = xmc[((size_t)b*128+ch)*NL + l0 + px];
  }
  #pragma unroll
  for (int j=0;j<4;j++){
    int i = d + 128*j;
    int n = i >> 5, li = i & 31;
    vb[j] = Bm[((size_t)b*16+n)*NL + l0 + li];
    vc[j] = Cm[((size_t)b*16+n)*NL + l0 + li];
  }
  { int n = d >> 5, li = d & 31; vd = dtm[((size_t)b*4+n)*NL + l0 + li]; }
  float A[16], h[16];
  const float* Af = wf + WF_A + d*16;
  size_t hb = (((size_t)k*NB + b)*128 + d)*16;
  #pragma unroll
  for (int n=0;n<16;n++){ A[n]=Af[n]; h[n]=Hi[hb+n]; }
  #pragma unroll
  for (int j=0;j<32;j++){
    int i = d + 128*j;
    int ch = i >> 5, px = i & 31;
    xs[ch*33+px] = vx[j];
  }
  #pragma unroll
  for (int j=0;j<4;j++){
    int i = d + 128*j;
    int n = i >> 5, li = i & 31;
    Bl2[li*20+n] = vb[j];
    Cl2[li*20+n] = vc[j];
  }
  { int n = d >> 5, li = d & 31; dtl2[li*4+n] = vd; }
  float Dv = wf[WF_DP + d];
  float w0 = wf[WF_DTW+d*4], w1 = wf[WF_DTW+d*4+1], w2 = wf[WF_DTW+d*4+2], w3 = wf[WF_DTW+d*4+3];
  float db2 = 2.f*wf[WF_DTB+d];
  __syncthreads();
  for (int l=0; l<CHUNK; l++){
    float4 dt4 = ((const float4*)dtl2)[l];
    float tt = w0*dt4.x + w1*dt4.y + w2*dt4.z + w3*dt4.w + db2;
    float de = tt > 20.f ? tt : __logf(1.f+__expf(tt));
    float uu = xs[d*33+l];
    float du = de * uu;
    float yv = uu * Dv;
    const float4* bp = (const float4*)(Bl2 + l*20);
    const float4* cp = (const float4*)(Cl2 + l*20);
    float4 b0 = bp[0], b1 = bp[1], b2 = bp[2], b3 = bp[3];
    float4 c0 = cp[0], c1 = cp[1], c2 = cp[2], c3 = cp[3];
    float bb[16] = {b0.x,b0.y,b0.z,b0.w, b1.x,b1.y,b1.z,b1.w,
                    b2.x,b2.y,b2.z,b2.w, b3.x,b3.y,b3.z,b3.w};
    float cc[16] = {c0.x,c0.y,c0.z,c0.w, c1.x,c1.y,c1.z,c1.w,
                    c2.x,c2.y,c2.z,c2.w, c3.x,c3.y,c3.z,c3.w};
    #pragma unroll
    for (int n=0;n<16;n++){
      float a = __expf(de*A[n]);
      h[n] = a*h[n] + du*bb[n];
      yv  += h[n]*cc[n];
    }
    xs[d*33+l] = yv;
  }
  __syncthreads();
  {
    int px = d & 31, q = d >> 5;
    float s=0.f, qq=0.f;
    #pragma unroll
    for (int j=0;j<32;j++){ float v = xs[(q*32+j)*33+px]; s+=v; qq+=v*v; }
    red[q][px][0]=s; red[q][px][1]=qq;
  }
  __syncthreads();
  if (d < 32){
    float ss = red[0][d][0]+red[1][d][0]+red[2][d][0]+red[3][d][0];
    float sq = red[0][d][1]+red[1][d][1]+red[2][d][1]+red[3][d][1];
    float m = ss*(1.f/128.f);
    mstat[d] = m;
    rstat[d] = rsqrtf(sq*(1.f/128.f) - m*m + 1e-5f);
  }
  __syncthreads();
  float ow = wf[WF_ONW+d], ob = wf[WF_ONB+d];
  const float* zp = z + ((size_t)b*128+d)*NL + l0;
  float* gp = G + ((size_t)b*128+d)*NL + l0;
  #pragma unroll
  for (int l4=0; l4<CHUNK/4; l4++){
    float4 zv4 = ((const float4*)zp)[l4];
    float zv[4] = {zv4.x, zv4.y, zv4.z, zv4.w};
    float out[4];
    #pragma unroll
    for (int j=0;j<4;j++){
      int l = l4*4+j;
      float t = (xs[d*33+l]-mstat[l])*rstat[l]*ow + ob;
      out[j] = t * (zv[j]/(1.f+__expf(-zv[j])));
    }
    ((float4*)gp)[l4] = make_float4(out[0],out[1],out[2],out[3]);
  }
}

// ---------------- K11A: yc = W_comb @ G + cf_b. og2 x b8 x pt32 = 512; transposed weights; + stats ----------------
__global__ __launch_bounds__(256) void k11A_proj(const float* __restrict__ G, const float* __restrict__ wf,
                                                 const float* __restrict__ wcomb,
                                                 float* __restrict__ yc, float* __restrict__ part){
  int og = blockIdx.x >> 8, rem = blockIdx.x & 255;
  int b = rem >> 5, pt = rem & 31;
  int jslot = threadIdx.x >> 5, pxslot = threadIdx.x & 31;
  __shared__ float wlds2[128][44];   // [k][o], 22.5 KB
  __shared__ float xs[32][128];
  {
    const float* Wg = wcomb + og*32*128;
    for (int i = threadIdx.x; i < 4096; i += 256){
      int o = i >> 7, k = i & 127;
      wlds2[k][o] = Wg[i];
    }
  }
  float acc[4][4];
  #pragma unroll
  for (int j=0;j<4;j++)
    #pragma unroll
    for (int p=0;p<4;p++) acc[j][p]=0.f;
  const float* gbase = G + (size_t)b*128*NL + pt*128;
  for (int ch = 0; ch < 4; ch++){
    __syncthreads();
    for (int i = threadIdx.x; i < 1024; i += 256){
      int r = i >> 5, c4 = i & 31;
      ((float4*)&xs[r][0])[c4] = *(const float4*)(gbase + (size_t)(ch*32+r)*NL + c4*4);
    }
    __syncthreads();
    #pragma unroll 1
    for (int c = 0; c < 32; c++){
      float a[4];
      #pragma unroll
      for (int p=0;p<4;p++) a[p] = xs[c][pxslot + 32*p];
      float4 w4 = *(const float4*)&wlds2[ch*32+c][jslot*4];
      float wv[4] = {w4.x, w4.y, w4.z, w4.w};
      #pragma unroll
      for (int jj=0;jj<4;jj++)
        #pragma unroll
        for (int p=0;p<4;p++) acc[jj][p] += wv[jj]*a[p];
    }
  }
  #pragma unroll
  for (int jj=0;jj<4;jj++){
    int cc = og*32 + jslot*4 + jj;
    float bias = wf[WF_CFB + cc];
    float* dp = yc + (size_t)b*64*NL + (size_t)cc*NL + pt*128;
    float sv = 0.f, qv = 0.f;
    #pragma unroll
    for (int p=0;p<4;p++){
      float t = acc[jj][p] + bias;
      dp[pxslot + 32*p] = t;
      sv += t; qv += t*t;
    }
    #pragma unroll
    for (int o=16;o>0;o>>=1){ sv += __shfl_xor(sv,o); qv += __shfl_xor(qv,o); }
    if (pxslot == 0){
      size_t pidx = (((size_t)b*64 + cc)*32 + pt)*2;
      part[pidx] = sv; part[pidx+1] = qv;
    }
  }
}

// ---------------- K11b: finalize per-(b,c) mean/rsqrt (32 partials each) ----------------
__global__ __launch_bounds__(256) void k11b_stats(const float* __restrict__ part, float* __restrict__ stats){
  int i = blockIdx.x*256 + threadIdx.x;
  if (i >= 512) return;
  float s=0.f, q=0.f;
  #pragma unroll
  for (int t2=0;t2<32;t2++){ s += part[((size_t)i*32+t2)*2]; q += part[((size_t)i*32+t2)*2+1]; }
  float m = s*(1.f/NL), va = q*(1.f/NL) - m*m;
  stats[i*2] = m; stats[i*2+1] = rsqrtf(va+1e-5f);
}

// ---------------- K11c: out = x1 + inorm(yc) ----------------
__global__ __launch_bounds__(256) void k11c_final(const float* __restrict__ yc, const float* __restrict__ stats,
                                                  const float* __restrict__ x1, float* __restrict__ out){
  int bc = blockIdx.x;
  float m = stats[bc*2], rs = stats[bc*2+1];
  size_t base = (size_t)bc*NL;
  for (int i=threadIdx.x;i<NL;i+=256){
    float v = (yc[base+i]-m)*rs;
    out[base+i] = x1[base+i] + v;
  }
}

// ---------------- host ----------------
extern "C" void kernel_launch(void* const* d_in, const int* in_sizes, int n_in,
                              void* d_out, int out_size, void* d_ws, size_t ws_size,
                              hipStream_t stream) {
  if (ws_size < WS_NEED_FLOATS * sizeof(float)) return;
  const float* x     = (const float*)d_in[0];
  const float* dw3w  = (const float*)d_in[1];
  const float* dw3b  = (const float*)d_in[2];
  const float* dw5w  = (const float*)d_in[3];
  const float* dw5b  = (const float*)d_in[4];
  const float* dw7w  = (const float*)d_in[5];
  const float* dw7b  = (const float*)d_in[6];
  const float* fusew = (const float*)d_in[7];
  const float* fuseb = (const float*)d_in[8];
  const float* inpjw = (const float*)d_in[9];
  const float* c2w   = (const float*)d_in[10];
  const float* c2b   = (const float*)d_in[11];
  const float* xpw   = (const float*)d_in[12];
  const float* dtw   = (const float*)d_in[13];
  const float* dtb   = (const float*)d_in[14];
  const float* alog  = (const float*)d_in[15];
  const float* dpv   = (const float*)d_in[16];
  const float* onw   = (const float*)d_in[17];
  const float* onb   = (const float*)d_in[18];
  const float* opw   = (const float*)d_in[19];
  const float* cfw   = (const float*)d_in[20];
  const float* cfb   = (const float*)d_in[21];

  float* ws    = (float*)d_ws;
  float* wf    = ws + OFF_WF;
  float* wcomb = ws + OFF_WCOMB;
  float* feats = ws + OFF_FEATS;
  float* xf    = ws + OFF_XF;
  float* x1    = ws + OFF_X1;
  float* xmraw = ws + OFF_XMRAW;
  float* z     = ws + OFF_Z;
  float* xmc   = ws + OFF_XMC;
  float* Bmw   = ws + OFF_BMAT;
  float* Cmw   = ws + OFF_CMAT;
  float* dtm   = ws + OFF_DTM;
  float* Acb   = ws + OFF_AC;
  float* Bcb   = ws + OFF_BC;
  float* Hi    = ws + OFF_HINIT;
  float* segP  = ws + OFF_SEGP;
  float* segQ  = ws + OFF_SEGQ;
  float* segH  = ws + OFF_SEGH;
  float* G     = ws + OFF_G;
  float* yc    = ws + OFF_YC;
  float* part  = ws + OFF_PART;
  float* stats = ws + OFF_STATS;

  CvtArgs ca; int ns = 0;
  auto add = [&](const float* s, int off, int n, int op){
    ca.d[ns].src = s; ca.d[ns].dst = wf + off; ca.d[ns].n = n; ca.d[ns].op = op; ns++;
  };
  add(dw3w, WF_DW3, 576, 0);   add(dw5w, WF_DW5, 1600, 0);  add(dw7w, WF_DW7, 3136, 0);
  add(dw3b, WF_B3, 64, 0);     add(dw5b, WF_B5, 64, 0);     add(dw7b, WF_B7, 64, 0);
  add(fusew, WF_FUSE, 12288, 0); add(fuseb, WF_FUSEB, 64, 0);
  add(c2w, WF_C2W, 1152, 0);   add(c2b, WF_C2B, 128, 0);
  add(xpw, WF_XPW, 4608, 0);   add(dtw, WF_DTW, 512, 0);    add(dtb, WF_DTB, 128, 0);
  add(alog, WF_A, 2048, 1);    // A = -exp(A_log)
  add(dpv, WF_DP, 128, 0);
  add(onw, WF_ONW, 128, 0);    add(onb, WF_ONB, 128, 0);
  add(opw, WF_OPW, 8192, 0);
  add(cfw, WF_CFW, 4096, 0);   add(cfb, WF_CFB, 64, 0);
  add(inpjw, WF_INPJ, 16384, 0);
  ca.ncvt = ns; ca.cfw = cfw; ca.opw = opw; ca.wcomb = wcomb;

  k0_cvt<<<ns + 32, 256, 0, stream>>>(ca);
  k1_dw<<<1024, 256, 0, stream>>>(x, wf, feats, part);
  k2_fuse<<<512, 256, 0, stream>>>(feats, part, wf, xf);
  k3_norm<<<512, 256, 0, stream>>>(xf, x, x1);
  k4_inproj<<<1024, 256, 0, stream>>>(x1, wf, xmraw, z);
  k5_dw3<<<1024, 256, 0, stream>>>(xmraw, wf, xmc);
  k6_xproj<<<256, 256, 0, stream>>>(xmc, wf, Bmw, Cmw, dtm);
  k7_scan1<<<1024, 128, 0, stream>>>(xmc, Bmw, dtm, wf, Acb, Bcb);
  k8a_seg<<<512, 256, 0, stream>>>(Acb, Bcb, segP, segQ);
  k8b_mid<<<64, 256, 0, stream>>>(segP, segQ, segH);
  k8c_emit<<<512, 256, 0, stream>>>(Acb, Bcb, segH, Hi);
  k9_scan2<<<1024, 128, 0, stream>>>(xmc, Bmw, Cmw, dtm, z, wf, Hi, G);
  k11A_proj<<<512, 256, 0, stream>>>(G, wf, wcomb, yc, part);
  k11b_stats<<<2, 256, 0, stream>>>(part, stats);
  k11c_final<<<512, 256, 0, stream>>>(yc, stats, x1, (float*)d_out);
}

// Round 14
// 209.923 us; speedup vs baseline: 3.2444x; 1.0132x over previous
//
#include <hip/hip_runtime.h>
#include <math.h>

#define NB 8
#define NC 64
#define NL 4096
#define NDI 128
#define NN 16
#define CHUNK 32
#define NKCH 128   // NL / CHUNK

// ---------------- workspace layout (float offsets) ----------------
#define OFF_FEATS 0ull
#define OFF_AC    0ull
#define OFF_BC    2097152ull
#define OFF_HINIT 4194304ull
#define OFF_XF    6291456ull
#define OFF_BMAT  6291456ull
#define OFF_CMAT  6815744ull
#define OFF_X1    8388608ull
#define OFF_XMRAW 10485760ull
#define OFF_G     10485760ull
#define OFF_Z     14680064ull
#define OFF_YC    14680064ull
#define OFF_PART  16777216ull
#define OFF_STATS 16809984ull
#define OFF_XMC   18874368ull
#define OFF_DTM   23068672ull
#define OFF_WF    27262976ull
#define OFF_NSTAT (OFF_WF + 55552ull)
#define OFF_WCOMB (OFF_WF + 58624ull)
#define WS_NEED_FLOATS (OFF_WF + 66816ull)

// weight sub-offsets inside WF (floats)
#define WF_DW3    0
#define WF_DW5    576
#define WF_DW7    2176
#define WF_B3     5312
#define WF_B5     5376
#define WF_B7     5440
#define WF_FUSE   5504
#define WF_FUSEB  17792
#define WF_C2W    17856
#define WF_C2B    19008
#define WF_XPW    19136
#define WF_DTW    23744
#define WF_DTB    24256
#define WF_A      24384
#define WF_DP     26432
#define WF_ONW    26560
#define WF_ONB    26688
#define WF_OPW    26816
#define WF_CFW    35008
#define WF_CFB    39104
#define WF_INPJ   39168

// ---------------- K0 ----------------
struct Cvt { const float* src; float* dst; int n; int op; };
struct CvtArgs { Cvt d[22]; int ncvt; const float* cfw; const float* opw; float* wcomb; };

__global__ __launch_bounds__(256) void k0_cvt(CvtArgs a){
  if ((int)blockIdx.x < a.ncvt){
    Cvt c = a.d[blockIdx.x];
    for (int i = threadIdx.x; i < c.n; i += 256){
      float v = c.src[i];
      c.dst[i] = c.op ? -expf(v) : v;
    }
  } else {
    int idx = (blockIdx.x - a.ncvt)*256 + threadIdx.x;
    int c = idx >> 7, kk = idx & 127;
    float s = 0.f;
    #pragma unroll
    for (int j=0;j<64;j++) s += a.cfw[c*64+j] * a.opw[j*128+kk];
    a.wcomb[idx] = s;
  }
}

// ---------------- K1: dw convs, 4 row-quarters per plane; grid 2048 ----------------
__global__ __launch_bounds__(256) void k1_dw(const float* __restrict__ x, const float* __restrict__ wf,
                                             float* __restrict__ feats, float* __restrict__ part){
  const int quar = blockIdx.x & 3, c = (blockIdx.x >> 2) & 63, b = blockIdx.x >> 8;
  const int tid = threadIdx.x;
  const int r0 = quar*16;
  __shared__ float xs[22*73];          // rows r0-3..r0+18, stride 73
  __shared__ float red[4][6];
  for (int i = tid; i < 22*73; i += 256) xs[i] = 0.f;
  const float* xp = x + ((size_t)b*64 + c)*NL;
  float v[6];
  #pragma unroll
  for (int k=0;k<6;k++){
    int idx = tid + k*256;
    int j = idx >> 6, w = idx & 63;
    int gr = r0 - 3 + j;
    bool ok = (idx < 1408) && (gr >= 0) && (gr < 64);
    v[k] = ok ? xp[gr*64 + w] : 0.f;
  }
  float w3r[9], w5r[25], w7r[49];
  #pragma unroll
  for (int i=0;i<9;i++)  w3r[i] = wf[WF_DW3 + c*9 + i];
  #pragma unroll
  for (int i=0;i<25;i++) w5r[i] = wf[WF_DW5 + c*25 + i];
  #pragma unroll
  for (int i=0;i<49;i++) w7r[i] = wf[WF_DW7 + c*49 + i];
  float b3 = wf[WF_B3+c], b5 = wf[WF_B5+c], b7 = wf[WF_B7+c];
  __syncthreads();
  #pragma unroll
  for (int k=0;k<6;k++){
    int idx = tid + k*256;
    if (idx < 1408){
      int j = idx >> 6, w = idx & 63;
      xs[j*73 + (w+3)] = v[k];
    }
  }
  __syncthreads();
  float s3=0,q3=0,s5=0,q5=0,s7=0,q7=0;
  float* f3 = feats + ((size_t)b*192 + c) * NL + r0*64;
  float* f5 = f3 + (size_t)64*NL;
  float* f7 = f3 + (size_t)128*NL;
  {
    int p = tid*4;
    int lh = p >> 6, w0 = p & 63;       // local row 0..15
    float a3[4], a5[4], a7[4];
    #pragma unroll
    for (int i=0;i<4;i++){ a3[i]=b3; a5[i]=b5; a7[i]=b7; }
    #pragma unroll
    for (int dy=0; dy<7; dy++){
      float s[10];
      #pragma unroll
      for (int j=0;j<10;j++) s[j] = xs[(lh+dy)*73 + w0 + j];
      #pragma unroll
      for (int dx=0;dx<7;dx++){
        float wv = w7r[dy*7+dx];
        #pragma unroll
        for (int i=0;i<4;i++) a7[i] += s[dx+i]*wv;
      }
      if (dy>=1 && dy<=5){
        #pragma unroll
        for (int dx=0;dx<5;dx++){
          float wv = w5r[(dy-1)*5+dx];
          #pragma unroll
          for (int i=0;i<4;i++) a5[i] += s[dx+1+i]*wv;
        }
      }
      if (dy>=2 && dy<=4){
        #pragma unroll
        for (int dx=0;dx<3;dx++){
          float wv = w3r[(dy-2)*3+dx];
          #pragma unroll
          for (int i=0;i<4;i++) a3[i] += s[dx+2+i]*wv;
        }
      }
    }
    *(float4*)(f3+p) = make_float4(a3[0],a3[1],a3[2],a3[3]);
    *(float4*)(f5+p) = make_float4(a5[0],a5[1],a5[2],a5[3]);
    *(float4*)(f7+p) = make_float4(a7[0],a7[1],a7[2],a7[3]);
    #pragma unroll
    for (int i=0;i<4;i++){
      s3+=a3[i]; q3+=a3[i]*a3[i];
      s5+=a5[i]; q5+=a5[i]*a5[i];
      s7+=a7[i]; q7+=a7[i]*a7[i];
    }
  }
  int wid = tid>>6, lane = tid&63;
  float v6[6]={s3,q3,s5,q5,s7,q7};
  #pragma unroll
  for (int j=0;j<6;j++){
    float t = v6[j];
    #pragma unroll
    for (int o=32;o>0;o>>=1) t += __shfl_down(t,o);
    if (!lane) red[wid][j]=t;
  }
  __syncthreads();
  if (tid < 3){
    float su = red[0][tid*2]+red[1][tid*2]+red[2][tid*2]+red[3][tid*2];
    float sq = red[0][tid*2+1]+red[1][tid*2+1]+red[2][tid*2+1]+red[3][tid*2+1];
    size_t k = (size_t)(b*192 + tid*64 + c)*8 + quar*2;
    part[k]   = su;
    part[k+1] = sq;
  }
}

// ---------------- K2: fuse 1x1 (192->64). og2 x b8 x pt32 = 512; transposed weights [k][o] ----------------
__global__ __launch_bounds__(256) void k2_fuse(const float* __restrict__ feats, const float* __restrict__ npart,
                                               const float* __restrict__ wf, float* __restrict__ xf){
  int og = blockIdx.x >> 8, rem = blockIdx.x & 255;
  int b = rem >> 5, pt = rem & 31;
  int jslot = threadIdx.x >> 5, pxslot = threadIdx.x & 31;
  __shared__ float wlds2[192][44];
  __shared__ float xs[32][128];
  __shared__ float msl[192], rsl[192];
  for (int i = threadIdx.x; i < 192; i += 256){
    const float* pp = npart + (size_t)(b*192+i)*8;
    float su = pp[0]+pp[2]+pp[4]+pp[6], sq = pp[1]+pp[3]+pp[5]+pp[7];
    float m = su*(1.f/NL);
    msl[i] = m;
    rsl[i] = rsqrtf(sq*(1.f/NL) - m*m + 1e-5f);
  }
  {
    const float* Wg = wf + WF_FUSE + og*32*192;
    for (int i = threadIdx.x; i < 6144; i += 256){
      int o = i / 192, k = i % 192;
      wlds2[k][o] = Wg[i];
    }
  }
  float acc[4][4];
  #pragma unroll
  for (int j=0;j<4;j++)
    #pragma unroll
    for (int p=0;p<4;p++) acc[j][p]=0.f;
  const float* fbase = feats + (size_t)b*192*NL + pt*128;
  for (int ch = 0; ch < 6; ch++){
    __syncthreads();
    for (int i = threadIdx.x; i < 1024; i += 256){
      int r = i >> 5, c4 = i & 31;
      int k = ch*32 + r;
      float4 f = *(const float4*)(fbase + (size_t)k*NL + c4*4);
      float m = msl[k], rs = rsl[k];
      float v0=(f.x-m)*rs, v1=(f.y-m)*rs, v2=(f.z-m)*rs, v3=(f.w-m)*rs;
      v0 = v0>0.f?v0:0.01f*v0; v1 = v1>0.f?v1:0.01f*v1;
      v2 = v2>0.f?v2:0.01f*v2; v3 = v3>0.f?v3:0.01f*v3;
      ((float4*)&xs[r][0])[c4] = make_float4(v0,v1,v2,v3);
    }
    __syncthreads();
    #pragma unroll 1
    for (int c = 0; c < 32; c++){
      float a[4];
      #pragma unroll
      for (int p=0;p<4;p++) a[p] = xs[c][pxslot + 32*p];
      float4 w4 = *(const float4*)&wlds2[ch*32+c][jslot*4];
      float wv[4] = {w4.x, w4.y, w4.z, w4.w};
      #pragma unroll
      for (int jj=0;jj<4;jj++)
        #pragma unroll
        for (int p=0;p<4;p++) acc[jj][p] += wv[jj]*a[p];
    }
  }
  #pragma unroll
  for (int jj=0;jj<4;jj++){
    int o = og*32 + jslot*4 + jj;
    float bias = wf[WF_FUSEB + o];
    float* dp = xf + (size_t)b*64*NL + (size_t)o*NL + pt*128;
    #pragma unroll
    for (int p=0;p<4;p++) dp[pxslot + 32*p] = acc[jj][p] + bias;
  }
}

// ---------------- K3: inorm(xf)+lrelu + x -> x1 ----------------
__global__ __launch_bounds__(256) void k3_norm(const float* __restrict__ xf, const float* __restrict__ x,
                                               float* __restrict__ x1){
  const int tid = threadIdx.x;
  const size_t base = (size_t)blockIdx.x * NL;
  float loc[16]; float s=0.f, q=0.f;
  #pragma unroll
  for (int i=0;i<16;i++){ float v = xf[base + tid + i*256]; loc[i]=v; s+=v; q+=v*v; }
  __shared__ float red[4][2];
  int wid = tid>>6, lane = tid&63;
  #pragma unroll
  for (int o=32;o>0;o>>=1){ s += __shfl_down(s,o); q += __shfl_down(q,o); }
  if (!lane){ red[wid][0]=s; red[wid][1]=q; }
  __syncthreads();
  s = red[0][0]+red[1][0]+red[2][0]+red[3][0];
  q = red[0][1]+red[1][1]+red[2][1]+red[3][1];
  float m = s*(1.f/NL), va = q*(1.f/NL)-m*m, rs = rsqrtf(va+1e-5f);
  #pragma unroll
  for (int i=0;i<16;i++){
    int idx = tid + i*256;
    float v = (loc[i]-m)*rs;
    v = v>0.f ? v : 0.01f*v;
    x1[base+idx] = v + x[base+idx];
  }
}

// ---------------- K4: in_proj (64->256). og4 x b8 x pt32 = 1024; transposed weights ----------------
__global__ __launch_bounds__(256) void k4_inproj(const float* __restrict__ x1, const float* __restrict__ wf,
                                                 float* __restrict__ xmraw, float* __restrict__ z){
  int og = blockIdx.x >> 8, rem = blockIdx.x & 255;
  int b = rem >> 5, pt = rem & 31;
  int jslot = threadIdx.x >> 5, pxslot = threadIdx.x & 31;
  __shared__ float wlds2[64][76];
  __shared__ float xs[32][128];
  {
    const float* Wg = wf + WF_INPJ + og*64*64;
    for (int i = threadIdx.x; i < 4096; i += 256){
      int o = i >> 6, k = i & 63;
      wlds2[k][o] = Wg[i];
    }
  }
  float acc[8][4];
  #pragma unroll
  for (int j=0;j<8;j++)
    #pragma unroll
    for (int p=0;p<4;p++) acc[j][p]=0.f;
  const float* xbase = x1 + (size_t)b*64*NL + pt*128;
  for (int ch = 0; ch < 2; ch++){
    __syncthreads();
    for (int i = threadIdx.x; i < 1024; i += 256){
      int r = i >> 5, c4 = i & 31;
      ((float4*)&xs[r][0])[c4] = *(const float4*)(xbase + (size_t)(ch*32+r)*NL + c4*4);
    }
    __syncthreads();
    #pragma unroll 1
    for (int c = 0; c < 32; c++){
      float a[4];
      #pragma unroll
      for (int p=0;p<4;p++) a[p] = xs[c][pxslot + 32*p];
      const float4* wp = (const float4*)&wlds2[ch*32+c][jslot*8];
      float4 w0 = wp[0], w1 = wp[1];
      float wv[8] = {w0.x,w0.y,w0.z,w0.w, w1.x,w1.y,w1.z,w1.w};
      #pragma unroll
      for (int jj=0;jj<8;jj++)
        #pragma unroll
        for (int p=0;p<4;p++) acc[jj][p] += wv[jj]*a[p];
    }
  }
  float* dstbase = (og < 2 ? xmraw + (size_t)b*128*NL + (size_t)(og*64)*NL
                           : z     + (size_t)b*128*NL + (size_t)((og-2)*64)*NL) + pt*128;
  #pragma unroll
  for (int jj=0;jj<8;jj++){
    float* dp = dstbase + (size_t)(jslot*8+jj)*NL;
    #pragma unroll
    for (int p=0;p<4;p++) dp[pxslot + 32*p] = acc[jj][p];
  }
}

// ---------------- K5: depthwise 3x3 + silu; 2 row-halves per plane; grid 2048 ----------------
__global__ __launch_bounds__(256) void k5_dw3(const float* __restrict__ xmraw, const float* __restrict__ wf,
                                              float* __restrict__ xmc){
  const int half = blockIdx.x & 1;
  const int d = (blockIdx.x >> 1) & 127;
  const int bd = blockIdx.x >> 1;
  const int tid = threadIdx.x;
  const int r0 = half*32;
  __shared__ float xs[34*69];         // rows r0-1..r0+32, stride 69
  for (int i=tid;i<34*69;i+=256) xs[i]=0.f;
  const float* xp = xmraw + (size_t)bd * NL;
  float v[9];
  #pragma unroll
  for (int k=0;k<9;k++){
    int idx = tid + k*256;
    int j = idx >> 6, w = idx & 63;
    int gr = r0 - 1 + j;
    bool ok = (idx < 2176) && (gr >= 0) && (gr < 64);
    v[k] = ok ? xp[gr*64 + w] : 0.f;
  }
  float wr[9];
  #pragma unroll
  for (int i=0;i<9;i++) wr[i] = wf[WF_C2W + d*9 + i];
  float bb = wf[WF_C2B + d];
  __syncthreads();
  #pragma unroll
  for (int k=0;k<9;k++){
    int idx = tid + k*256;
    if (idx < 2176){
      int j = idx >> 6, w = idx & 63;
      xs[j*69 + (w+1)] = v[k];
    }
  }
  __syncthreads();
  float* op = xmc + (size_t)bd * NL + r0*64;
  #pragma unroll
  for (int g=0; g<2; g++){
    int p = g*1024 + tid*4;
    int lh = p>>6, w0 = p&63;
    float a[4];
    #pragma unroll
    for (int i=0;i<4;i++) a[i]=bb;
    #pragma unroll
    for (int dy=0; dy<3; dy++){
      float s[6];
      #pragma unroll
      for (int j=0;j<6;j++) s[j] = xs[(lh+dy)*69 + w0 + j];
      #pragma unroll
      for (int dx=0;dx<3;dx++){
        float wv = wr[dy*3+dx];
        #pragma unroll
        for (int i=0;i<4;i++) a[i] += s[dx+i]*wv;
      }
    }
    float4 o;
    o.x = a[0]/(1.f+__expf(-a[0]));
    o.y = a[1]/(1.f+__expf(-a[1]));
    o.z = a[2]/(1.f+__expf(-a[2]));
    o.w = a[3]/(1.f+__expf(-a[3]));
    *(float4*)(op+p) = o;
  }
}

// ---------------- K6 (slim): x_proj (128->36); grid 256; transposed weights, slot-padded ----------------
__global__ __launch_bounds__(256) void k6_xproj(const float* __restrict__ xmc, const float* __restrict__ wf,
                                                float* __restrict__ Bm, float* __restrict__ Cm,
                                                float* __restrict__ dtm){
  int b = blockIdx.x >> 5, pt = blockIdx.x & 31;
  int jslot = threadIdx.x >> 6, pxslot = threadIdx.x & 63;
  __shared__ float wlds2[128][52];
  __shared__ float xs[32][128];
  {
    const float* Wg = wf + WF_XPW;
    for (int i = threadIdx.x; i < 4608; i += 256){
      int o = i >> 7, k = i & 127;
      wlds2[k][(o/9)*12 + (o%9)] = Wg[i];
    }
  }
  float acc[9][2];
  #pragma unroll
  for (int j=0;j<9;j++){ acc[j][0]=0.f; acc[j][1]=0.f; }
  const float* ubase = xmc + (size_t)b*128*NL + pt*128;
  for (int ch = 0; ch < 4; ch++){
    __syncthreads();
    for (int i = threadIdx.x; i < 1024; i += 256){
      int r = i >> 5, c4 = i & 31;
      ((float4*)&xs[r][0])[c4] = *(const float4*)(ubase + (size_t)(ch*32+r)*NL + c4*4);
    }
    __syncthreads();
    #pragma unroll 1
    for (int c = 0; c < 32; c++){
      float a0 = xs[c][pxslot];
      float a1 = xs[c][pxslot + 64];
      const float* wr = &wlds2[ch*32+c][jslot*12];
      float4 wa = *(const float4*)wr;
      float4 wb = *(const float4*)(wr+4);
      float w8 = wr[8];
      float wv[9] = {wa.x,wa.y,wa.z,wa.w, wb.x,wb.y,wb.z,wb.w, w8};
      #pragma unroll
      for (int j=0;j<9;j++){
        acc[j][0] += wv[j]*a0;
        acc[j][1] += wv[j]*a1;
      }
    }
  }
  #pragma unroll
  for (int j=0;j<9;j++){
    int o = jslot*9 + j;
    float* dp;
    if (o < 4)       dp = dtm + ((size_t)b*4 + o)*NL;
    else if (o < 20) dp = Bm  + ((size_t)b*16 + (o-4))*NL;
    else             dp = Cm  + ((size_t)b*16 + (o-20))*NL;
    dp[pt*128 + pxslot]      = acc[j][0];
    dp[pt*128 + pxslot + 64] = acc[j][1];
  }
}

// ---------------- K7: scan pass1 — pixel-major B/dt in LDS ----------------
__global__ __launch_bounds__(128) void k7_scan1(const float* __restrict__ xmc, const float* __restrict__ Bm,
                                                const float* __restrict__ dtm, const float* __restrict__ wf,
                                                float* __restrict__ Ac, float* __restrict__ Bc){
  int k = blockIdx.x & (NKCH-1), b = blockIdx.x >> 7;
  int d = threadIdx.x;
  int l0 = k*CHUNK;
  __shared__ float xs[128*33];
  __shared__ float Bl2[32*20];
  __shared__ float dtl2[32*4];
  float vx[32], vb[4], vd;
  #pragma unroll
  for (int j=0;j<32;j++){
    int i = d + 128*j;
    int ch = i >> 5, px = i & 31;
    vx[j] = xmc[((size_t)b*128+ch)*NL + l0 + px];
  }
  #pragma unroll
  for (int j=0;j<4;j++){
    int i = d + 128*j;
    int n = i >> 5, li = i & 31;
    vb[j] = Bm[((size_t)b*16+n)*NL + l0 + li];
  }
  { int n = d >> 5, li = d & 31; vd = dtm[((size_t)b*4+n)*NL + l0 + li]; }
  #pragma unroll
  for (int j=0;j<32;j++){
    int i = d + 128*j;
    int ch = i >> 5, px = i & 31;
    xs[ch*33+px] = vx[j];
  }
  #pragma unroll
  for (int j=0;j<4;j++){
    int i = d + 128*j;
    int n = i >> 5, li = i & 31;
    Bl2[li*20+n] = vb[j];
  }
  { int n = d >> 5, li = d & 31; dtl2[li*4+n] = vd; }
  float A[16], P[16], Q[16];
  const float* Af = wf + WF_A + d*16;
  #pragma unroll
  for (int n=0;n<16;n++){ A[n]=Af[n]; P[n]=1.f; Q[n]=0.f; }
  float w0 = wf[WF_DTW+d*4], w1 = wf[WF_DTW+d*4+1], w2 = wf[WF_DTW+d*4+2], w3 = wf[WF_DTW+d*4+3];
  float db2 = 2.f*wf[WF_DTB+d];
  __syncthreads();
  for (int l=0; l<CHUNK; l++){
    float4 dt4 = ((const float4*)dtl2)[l];
    float tt = w0*dt4.x + w1*dt4.y + w2*dt4.z + w3*dt4.w + db2;
    float de = tt > 20.f ? tt : __logf(1.f+__expf(tt));
    float du = de * xs[d*33+l];
    const float4* bp = (const float4*)(Bl2 + l*20);
    float4 b0 = bp[0], b1 = bp[1], b2 = bp[2], b3 = bp[3];
    float bb[16] = {b0.x,b0.y,b0.z,b0.w, b1.x,b1.y,b1.z,b1.w,
                    b2.x,b2.y,b2.z,b2.w, b3.x,b3.y,b3.z,b3.w};
    #pragma unroll
    for (int n=0;n<16;n++){
      float a = __expf(de*A[n]);
      P[n] *= a;
      Q[n] = a*Q[n] + du*bb[n];
    }
  }
  size_t base = (((size_t)k*NB + b)*128 + d)*16;
  #pragma unroll
  for (int i=0;i<4;i++){
    ((float4*)(Ac+base))[i] = make_float4(P[i*4],P[i*4+1],P[i*4+2],P[i*4+3]);
    ((float4*)(Bc+base))[i] = make_float4(Q[i*4],Q[i*4+1],Q[i*4+2],Q[i*4+3]);
  }
}

// ---------------- K8: middle scan over chunk aggregates; unroll 16 for load ILP ----------------
__global__ __launch_bounds__(256) void k8_mid(const float* __restrict__ Ac, const float* __restrict__ Bc,
                                              float* __restrict__ Hi){
  int idx = blockIdx.x*256 + threadIdx.x;
  float h = 0.f;
  for (int k0=0;k0<NKCH;k0+=16){
    float av[16], bv[16];
    #pragma unroll
    for (int j=0;j<16;j++){
      size_t o = (size_t)(k0+j)*16384 + idx;
      av[j]=Ac[o]; bv[j]=Bc[o];
    }
    #pragma unroll
    for (int j=0;j<16;j++){
      size_t o = (size_t)(k0+j)*16384 + idx;
      Hi[o] = h;
      h = av[j]*h + bv[j];
    }
  }
}

// ---------------- K9: scan pass2 + fused LN*silu(z); pixel-major B/C/dt in LDS ----------------
__global__ __launch_bounds__(128) void k9_scan2(const float* __restrict__ xmc, const float* __restrict__ Bm,
                                                const float* __restrict__ Cm, const float* __restrict__ dtm,
                                                const float* __restrict__ z, const float* __restrict__ wf,
                                                const float* __restrict__ Hi, float* __restrict__ G){
  int k = blockIdx.x & (NKCH-1), b = blockIdx.x >> 7;
  int d = threadIdx.x;
  int l0 = k*CHUNK;
  __shared__ float xs[128*33];
  __shared__ float Bl2[32*20], Cl2[32*20];
  __shared__ float dtl2[32*4];
  __shared__ float red[4][32][2];
  __shared__ float mstat[32], rstat[32];
  float vx[32], vb[4], vc[4], vd;
  #pragma unroll
  for (int j=0;j<32;j++){
    int i = d + 128*j;
    int ch = i >> 5, px = i & 31;
    vx[j] = xmc[((size_t)b*128+ch)*NL + l0 + px];
  }
  #pragma unroll
  for (int j=0;j<4;j++){
    int i = d + 128*j;
    int n = i >> 5, li = i & 31;
    vb[j] = Bm[((size_t)b*16+n)*NL + l0 + li];
    vc[j] = Cm[((size_t)b*16+n)*NL + l0 + li];
  }
  { int n = d >> 5, li = d & 31; vd = dtm[((size_t)b*4+n)*NL + l0 + li]; }
  float A[16], h[16];
  const float* Af = wf + WF_A + d*16;
  size_t hb = (((size_t)k*NB + b)*128 + d)*16;
  #pragma unroll
  for (int n=0;n<16;n++){ A[n]=Af[n]; h[n]=Hi[hb+n]; }
  #pragma unroll
  for (int j=0;j<32;j++){
    int i = d + 128*j;
    int ch = i >> 5, px = i & 31;
    xs[ch*33+px] = vx[j];
  }
  #pragma unroll
  for (int j=0;j<4;j++){
    int i = d + 128*j;
    int n = i >> 5, li = i & 31;
    Bl2[li*20+n] = vb[j];
    Cl2[li*20+n] = vc[j];
  }
  { int n = d >> 5, li = d & 31; dtl2[li*4+n] = vd; }
  float Dv = wf[WF_DP + d];
  float w0 = wf[WF_DTW+d*4], w1 = wf[WF_DTW+d*4+1], w2 = wf[WF_DTW+d*4+2], w3 = wf[WF_DTW+d*4+3];
  float db2 = 2.f*wf[WF_DTB+d];
  __syncthreads();
  for (int l=0; l<CHUNK; l++){
    float4 dt4 = ((const float4*)dtl2)[l];
    float tt = w0*dt4.x + w1*dt4.y + w2*dt4.z + w3*dt4.w + db2;
    float de = tt > 20.f ? tt : __logf(1.f+__expf(tt));
    float uu = xs[d*33+l];
    float du = de * uu;
    float yv = uu * Dv;
    const float4* bp = (const float4*)(Bl2 + l*20);
    const float4* cp = (const float4*)(Cl2 + l*20);
    float4 b0 = bp[0], b1 = bp[1], b2 = bp[2], b3 = bp[3];
    float4 c0 = cp[0], c1 = cp[1], c2 = cp[2], c3 = cp[3];
    float bb[16] = {b0.x,b0.y,b0.z,b0.w, b1.x,b1.y,b1.z,b1.w,
                    b2.x,b2.y,b2.z,b2.w, b3.x,b3.y,b3.z,b3.w};
    float cc[16] = {c0.x,c0.y,c0.z,c0.w, c1.x,c1.y,c1.z,c1.w,
                    c2.x,c2.y,c2.z,c2.w, c3.x,c3.y,c3.z,c3.w};
    #pragma unroll
    for (int n=0;n<16;n++){
      float a = __expf(de*A[n]);
      h[n] = a*h[n] + du*bb[n];
      yv  += h[n]*cc[n];
    }
    xs[d*33+l] = yv;
  }
  __syncthreads();
  {
    int px = d & 31, q = d >> 5;
    float s=0.f, qq=0.f;
    #pragma unroll
    for (int j=0;j<32;j++){ float v = xs[(q*32+j)*33+px]; s+=v; qq+=v*v; }
    red[q][px][0]=s; red[q][px][1]=qq;
  }
  __syncthreads();
  if (d < 32){
    float ss = red[0][d][0]+red[1][d][0]+red[2][d][0]+red[3][d][0];
    float sq = red[0][d][1]+red[1][d][1]+red[2][d][1]+red[3][d][1];
    float m = ss*(1.f/128.f);
    mstat[d] = m;
    rstat[d] = rsqrtf(sq*(1.f/128.f) - m*m + 1e-5f);
  }
  __syncthreads();
  float ow = wf[WF_ONW+d], ob = wf[WF_ONB+d];
  const float* zp = z + ((size_t)b*128+d)*NL + l0;
  float* gp = G + ((size_t)b*128+d)*NL + l0;
  #pragma unroll
  for (int l4=0; l4<CHUNK/4; l4++){
    float4 zv4 = ((const float4*)zp)[l4];
    float zv[4] = {zv4.x, zv4.y, zv4.z, zv4.w};
    float out[4];
    #pragma unroll
    for (int j=0;j<4;j++){
      int l = l4*4+j;
      float t = (xs[d*33+l]-mstat[l])*rstat[l]*ow + ob;
      out[j] = t * (zv[j]/(1.f+__expf(-zv[j])));
    }
    ((float4*)gp)[l4] = make_float4(out[0],out[1],out[2],out[3]);
  }
}

// ---------------- K11A: yc = W_comb @ G + cf_b. og2 x b8 x pt32 = 512; transposed weights; + stats ----------------
__global__ __launch_bounds__(256) void k11A_proj(const float* __restrict__ G, const float* __restrict__ wf,
                                                 const float* __restrict__ wcomb,
                                                 float* __restrict__ yc, float* __restrict__ part){
  int og = blockIdx.x >> 8, rem = blockIdx.x & 255;
  int b = rem >> 5, pt = rem & 31;
  int jslot = threadIdx.x >> 5, pxslot = threadIdx.x & 31;
  __shared__ float wlds2[128][44];
  __shared__ float xs[32][128];
  {
    const float* Wg = wcomb + og*32*128;
    for (int i = threadIdx.x; i < 4096; i += 256){
      int o = i >> 7, k = i & 127;
      wlds2[k][o] = Wg[i];
    }
  }
  float acc[4][4];
  #pragma unroll
  for (int j=0;j<4;j++)
    #pragma unroll
    for (int p=0;p<4;p++) acc[j][p]=0.f;
  const float* gbase = G + (size_t)b*128*NL + pt*128;
  for (int ch = 0; ch < 4; ch++){
    __syncthreads();
    for (int i = threadIdx.x; i < 1024; i += 256){
      int r = i >> 5, c4 = i & 31;
      ((float4*)&xs[r][0])[c4] = *(const float4*)(gbase + (size_t)(ch*32+r)*NL + c4*4);
    }
    __syncthreads();
    #pragma unroll 1
    for (int c = 0; c < 32; c++){
      float a[4];
      #pragma unroll
      for (int p=0;p<4;p++) a[p] = xs[c][pxslot + 32*p];
      float4 w4 = *(const float4*)&wlds2[ch*32+c][jslot*4];
      float wv[4] = {w4.x, w4.y, w4.z, w4.w};
      #pragma unroll
      for (int jj=0;jj<4;jj++)
        #pragma unroll
        for (int p=0;p<4;p++) acc[jj][p] += wv[jj]*a[p];
    }
  }
  #pragma unroll
  for (int jj=0;jj<4;jj++){
    int cc = og*32 + jslot*4 + jj;
    float bias = wf[WF_CFB + cc];
    float* dp = yc + (size_t)b*64*NL + (size_t)cc*NL + pt*128;
    float sv = 0.f, qv = 0.f;
    #pragma unroll
    for (int p=0;p<4;p++){
      float t = acc[jj][p] + bias;
      dp[pxslot + 32*p] = t;
      sv += t; qv += t*t;
    }
    #pragma unroll
    for (int o=16;o>0;o>>=1){ sv += __shfl_xor(sv,o); qv += __shfl_xor(qv,o); }
    if (pxslot == 0){
      size_t pidx = (((size_t)b*64 + cc)*32 + pt)*2;
      part[pidx] = sv; part[pidx+1] = qv;
    }
  }
}

// ---------------- K11c: out = x1 + inorm(yc); stats reduced in-block from 32 partials ----------------
__global__ __launch_bounds__(256) void k11c_final(const float* __restrict__ yc, const float* __restrict__ part,
                                                  const float* __restrict__ x1, float* __restrict__ out){
  int bc = blockIdx.x;
  __shared__ float sm, sr;
  if (threadIdx.x == 0){
    float s=0.f, q=0.f;
    #pragma unroll
    for (int t2=0;t2<32;t2++){ s += part[((size_t)bc*32+t2)*2]; q += part[((size_t)bc*32+t2)*2+1]; }
    float m = s*(1.f/NL);
    sm = m; sr = rsqrtf(q*(1.f/NL) - m*m + 1e-5f);
  }
  __syncthreads();
  float m = sm, rs = sr;
  size_t base = (size_t)bc*NL;
  for (int i=threadIdx.x;i<NL;i+=256){
    float v = (yc[base+i]-m)*rs;
    out[base+i] = x1[base+i] + v;
  }
}

// ---------------- host ----------------
extern "C" void kernel_launch(void* const* d_in, const int* in_sizes, int n_in,
                              void* d_out, int out_size, void* d_ws, size_t ws_size,
                              hipStream_t stream) {
  if (ws_size < WS_NEED_FLOATS * sizeof(float)) return;
  const float* x     = (const float*)d_in[0];
  const float* dw3w  = (const float*)d_in[1];
  const float* dw3b  = (const float*)d_in[2];
  const float* dw5w  = (const float*)d_in[3];
  const float* dw5b  = (const float*)d_in[4];
  const float* dw7w  = (const float*)d_in[5];
  const float* dw7b  = (const float*)d_in[6];
  const float* fusew = (const float*)d_in[7];
  const float* fuseb = (const float*)d_in[8];
  const float* inpjw = (const float*)d_in[9];
  const float* c2w   = (const float*)d_in[10];
  const float* c2b   = (const float*)d_in[11];
  const float* xpw   = (const float*)d_in[12];
  const float* dtw   = (const float*)d_in[13];
  const float* dtb   = (const float*)d_in[14];
  const float* alog  = (const float*)d_in[15];
  const float* dpv   = (const float*)d_in[16];
  const float* onw   = (const float*)d_in[17];
  const float* onb   = (const float*)d_in[18];
  const float* opw   = (const float*)d_in[19];
  const float* cfw   = (const float*)d_in[20];
  const float* cfb   = (const float*)d_in[21];

  float* ws    = (float*)d_ws;
  float* wf    = ws + OFF_WF;
  float* wcomb = ws + OFF_WCOMB;
  float* feats = ws + OFF_FEATS;
  float* xf    = ws + OFF_XF;
  float* x1    = ws + OFF_X1;
  float* xmraw = ws + OFF_XMRAW;
  float* z     = ws + OFF_Z;
  float* xmc   = ws + OFF_XMC;
  float* Bmw   = ws + OFF_BMAT;
  float* Cmw   = ws + OFF_CMAT;
  float* dtm   = ws + OFF_DTM;
  float* Acb   = ws + OFF_AC;
  float* Bcb   = ws + OFF_BC;
  float* Hi    = ws + OFF_HINIT;
  float* G     = ws + OFF_G;
  float* yc    = ws + OFF_YC;
  float* part  = ws + OFF_PART;

  CvtArgs ca; int ns = 0;
  auto add = [&](const float* s, int off, int n, int op){
    ca.d[ns].src = s; ca.d[ns].dst = wf + off; ca.d[ns].n = n; ca.d[ns].op = op; ns++;
  };
  add(dw3w, WF_DW3, 576, 0);   add(dw5w, WF_DW5, 1600, 0);  add(dw7w, WF_DW7, 3136, 0);
  add(dw3b, WF_B3, 64, 0);     add(dw5b, WF_B5, 64, 0);     add(dw7b, WF_B7, 64, 0);
  add(fusew, WF_FUSE, 12288, 0); add(fuseb, WF_FUSEB, 64, 0);
  add(c2w, WF_C2W, 1152, 0);   add(c2b, WF_C2B, 128, 0);
  add(xpw, WF_XPW, 4608, 0);   add(dtw, WF_DTW, 512, 0);    add(dtb, WF_DTB, 128, 0);
  add(alog, WF_A, 2048, 1);    // A = -exp(A_log)
  add(dpv, WF_DP, 128, 0);
  add(onw, WF_ONW, 128, 0);    add(onb, WF_ONB, 128, 0);
  add(opw, WF_OPW, 8192, 0);
  add(cfw, WF_CFW, 4096, 0);   add(cfb, WF_CFB, 64, 0);
  add(inpjw, WF_INPJ, 16384, 0);
  ca.ncvt = ns; ca.cfw = cfw; ca.opw = opw; ca.wcomb = wcomb;

  k0_cvt<<<ns + 32, 256, 0, stream>>>(ca);
  k1_dw<<<2048, 256, 0, stream>>>(x, wf, feats, part);
  k2_fuse<<<512, 256, 0, stream>>>(feats, part, wf, xf);
  k3_norm<<<512, 256, 0, stream>>>(xf, x, x1);
  k4_inproj<<<1024, 256, 0, stream>>>(x1, wf, xmraw, z);
  k5_dw3<<<2048, 256, 0, stream>>>(xmraw, wf, xmc);
  k6_xproj<<<256, 256, 0, stream>>>(xmc, wf, Bmw, Cmw, dtm);
  k7_scan1<<<1024, 128, 0, stream>>>(xmc, Bmw, dtm, wf, Acb, Bcb);
  k8_mid<<<64, 256, 0, stream>>>(Acb, Bcb, Hi);
  k9_scan2<<<1024, 128, 0, stream>>>(xmc, Bmw, Cmw, dtm, z, wf, Hi, G);
  k11A_proj<<<512, 256, 0, stream>>>(G, wf, wcomb, yc, part);
  k11c_final<<<512, 256, 0, stream>>>(yc, part, x1, (float*)d_out);
}

// Round 15
// 207.347 us; speedup vs baseline: 3.2847x; 1.0124x over previous
//
#include <hip/hip_runtime.h>
#include <math.h>

#define NB 8
#define NC 64
#define NL 4096
#define NDI 128
#define NN 16
#define CHUNK 32
#define NKCH 128   // NL / CHUNK

// ---------------- workspace layout (float offsets) ----------------
#define OFF_FEATS 0ull
#define OFF_AC    0ull
#define OFF_BC    2097152ull
#define OFF_HINIT 4194304ull
#define OFF_XF    6291456ull
#define OFF_BMAT  6291456ull
#define OFF_CMAT  6815744ull
#define OFF_X1    8388608ull
#define OFF_XMRAW 10485760ull
#define OFF_G     10485760ull
#define OFF_Z     14680064ull
#define OFF_YC    14680064ull
#define OFF_PART  16777216ull
#define OFF_XMC   18874368ull
#define OFF_DTM   23068672ull
#define OFF_WF    27262976ull
#define OFF_WCOMB (OFF_WF + 58624ull)
#define WS_NEED_FLOATS (OFF_WF + 66816ull)

// weight sub-offsets inside WF (floats)
#define WF_DW3    0
#define WF_DW5    576
#define WF_DW7    2176
#define WF_B3     5312
#define WF_B5     5376
#define WF_B7     5440
#define WF_FUSE   5504
#define WF_FUSEB  17792
#define WF_C2W    17856
#define WF_C2B    19008
#define WF_XPW    19136
#define WF_DTW    23744
#define WF_DTB    24256
#define WF_A      24384
#define WF_DP     26432
#define WF_ONW    26560
#define WF_ONB    26688
#define WF_OPW    26816
#define WF_CFW    35008
#define WF_CFB    39104
#define WF_INPJ   39168

// ---------------- K0 ----------------
struct Cvt { const float* src; float* dst; int n; int op; };
struct CvtArgs { Cvt d[22]; int ncvt; const float* cfw; const float* opw; float* wcomb; };

__global__ __launch_bounds__(256) void k0_cvt(CvtArgs a){
  if ((int)blockIdx.x < a.ncvt){
    Cvt c = a.d[blockIdx.x];
    for (int i = threadIdx.x; i < c.n; i += 256){
      float v = c.src[i];
      c.dst[i] = c.op ? -expf(v) : v;
    }
  } else {
    int idx = (blockIdx.x - a.ncvt)*256 + threadIdx.x;
    int c = idx >> 7, kk = idx & 127;
    float s = 0.f;
    #pragma unroll
    for (int j=0;j<64;j++) s += a.cfw[c*64+j] * a.opw[j*128+kk];
    a.wcomb[idx] = s;
  }
}

// ---------------- K1: dw convs, 4 row-quarters per plane; grid 2048; (256,4) -> 128 VGPR budget ----------------
__global__ __launch_bounds__(256, 4) void k1_dw(const float* __restrict__ x, const float* __restrict__ wf,
                                                float* __restrict__ feats, float* __restrict__ part){
  const int quar = blockIdx.x & 3, c = (blockIdx.x >> 2) & 63, b = blockIdx.x >> 8;
  const int tid = threadIdx.x;
  const int r0 = quar*16;
  __shared__ float xs[22*73];
  __shared__ float red[4][6];
  for (int i = tid; i < 22*73; i += 256) xs[i] = 0.f;
  const float* xp = x + ((size_t)b*64 + c)*NL;
  float v[6];
  #pragma unroll
  for (int k=0;k<6;k++){
    int idx = tid + k*256;
    int j = idx >> 6, w = idx & 63;
    int gr = r0 - 3 + j;
    bool ok = (idx < 1408) && (gr >= 0) && (gr < 64);
    v[k] = ok ? xp[gr*64 + w] : 0.f;
  }
  float w3r[9], w5r[25], w7r[49];
  #pragma unroll
  for (int i=0;i<9;i++)  w3r[i] = wf[WF_DW3 + c*9 + i];
  #pragma unroll
  for (int i=0;i<25;i++) w5r[i] = wf[WF_DW5 + c*25 + i];
  #pragma unroll
  for (int i=0;i<49;i++) w7r[i] = wf[WF_DW7 + c*49 + i];
  float b3 = wf[WF_B3+c], b5 = wf[WF_B5+c], b7 = wf[WF_B7+c];
  __syncthreads();
  #pragma unroll
  for (int k=0;k<6;k++){
    int idx = tid + k*256;
    if (idx < 1408){
      int j = idx >> 6, w = idx & 63;
      xs[j*73 + (w+3)] = v[k];
    }
  }
  __syncthreads();
  float s3=0,q3=0,s5=0,q5=0,s7=0,q7=0;
  float* f3 = feats + ((size_t)b*192 + c) * NL + r0*64;
  float* f5 = f3 + (size_t)64*NL;
  float* f7 = f3 + (size_t)128*NL;
  {
    int p = tid*4;
    int lh = p >> 6, w0 = p & 63;
    float a3[4], a5[4], a7[4];
    #pragma unroll
    for (int i=0;i<4;i++){ a3[i]=b3; a5[i]=b5; a7[i]=b7; }
    #pragma unroll
    for (int dy=0; dy<7; dy++){
      float s[10];
      #pragma unroll
      for (int j=0;j<10;j++) s[j] = xs[(lh+dy)*73 + w0 + j];
      #pragma unroll
      for (int dx=0;dx<7;dx++){
        float wv = w7r[dy*7+dx];
        #pragma unroll
        for (int i=0;i<4;i++) a7[i] += s[dx+i]*wv;
      }
      if (dy>=1 && dy<=5){
        #pragma unroll
        for (int dx=0;dx<5;dx++){
          float wv = w5r[(dy-1)*5+dx];
          #pragma unroll
          for (int i=0;i<4;i++) a5[i] += s[dx+1+i]*wv;
        }
      }
      if (dy>=2 && dy<=4){
        #pragma unroll
        for (int dx=0;dx<3;dx++){
          float wv = w3r[(dy-2)*3+dx];
          #pragma unroll
          for (int i=0;i<4;i++) a3[i] += s[dx+2+i]*wv;
        }
      }
    }
    *(float4*)(f3+p) = make_float4(a3[0],a3[1],a3[2],a3[3]);
    *(float4*)(f5+p) = make_float4(a5[0],a5[1],a5[2],a5[3]);
    *(float4*)(f7+p) = make_float4(a7[0],a7[1],a7[2],a7[3]);
    #pragma unroll
    for (int i=0;i<4;i++){
      s3+=a3[i]; q3+=a3[i]*a3[i];
      s5+=a5[i]; q5+=a5[i]*a5[i];
      s7+=a7[i]; q7+=a7[i]*a7[i];
    }
  }
  int wid = tid>>6, lane = tid&63;
  float v6[6]={s3,q3,s5,q5,s7,q7};
  #pragma unroll
  for (int j=0;j<6;j++){
    float t = v6[j];
    #pragma unroll
    for (int o=32;o>0;o>>=1) t += __shfl_down(t,o);
    if (!lane) red[wid][j]=t;
  }
  __syncthreads();
  if (tid < 3){
    float su = red[0][tid*2]+red[1][tid*2]+red[2][tid*2]+red[3][tid*2];
    float sq = red[0][tid*2+1]+red[1][tid*2+1]+red[2][tid*2+1]+red[3][tid*2+1];
    size_t k = (size_t)(b*192 + tid*64 + c)*8 + quar*2;
    part[k]   = su;
    part[k+1] = sq;
  }
}

// ---------------- K2: fuse 1x1 (192->64). og2 x b8 x pt32 = 512; (256,3) ----------------
__global__ __launch_bounds__(256, 3) void k2_fuse(const float* __restrict__ feats, const float* __restrict__ npart,
                                                  const float* __restrict__ wf, float* __restrict__ xf){
  int og = blockIdx.x >> 8, rem = blockIdx.x & 255;
  int b = rem >> 5, pt = rem & 31;
  int jslot = threadIdx.x >> 5, pxslot = threadIdx.x & 31;
  __shared__ float wlds2[192][44];
  __shared__ float xs[32][128];
  __shared__ float msl[192], rsl[192];
  for (int i = threadIdx.x; i < 192; i += 256){
    const float* pp = npart + (size_t)(b*192+i)*8;
    float su = pp[0]+pp[2]+pp[4]+pp[6], sq = pp[1]+pp[3]+pp[5]+pp[7];
    float m = su*(1.f/NL);
    msl[i] = m;
    rsl[i] = rsqrtf(sq*(1.f/NL) - m*m + 1e-5f);
  }
  {
    const float* Wg = wf + WF_FUSE + og*32*192;
    for (int i = threadIdx.x; i < 6144; i += 256){
      int o = i / 192, k = i % 192;
      wlds2[k][o] = Wg[i];
    }
  }
  float acc[4][4];
  #pragma unroll
  for (int j=0;j<4;j++)
    #pragma unroll
    for (int p=0;p<4;p++) acc[j][p]=0.f;
  const float* fbase = feats + (size_t)b*192*NL + pt*128;
  for (int ch = 0; ch < 6; ch++){
    __syncthreads();
    for (int i = threadIdx.x; i < 1024; i += 256){
      int r = i >> 5, c4 = i & 31;
      int k = ch*32 + r;
      float4 f = *(const float4*)(fbase + (size_t)k*NL + c4*4);
      float m = msl[k], rs = rsl[k];
      float v0=(f.x-m)*rs, v1=(f.y-m)*rs, v2=(f.z-m)*rs, v3=(f.w-m)*rs;
      v0 = v0>0.f?v0:0.01f*v0; v1 = v1>0.f?v1:0.01f*v1;
      v2 = v2>0.f?v2:0.01f*v2; v3 = v3>0.f?v3:0.01f*v3;
      ((float4*)&xs[r][0])[c4] = make_float4(v0,v1,v2,v3);
    }
    __syncthreads();
    #pragma unroll 1
    for (int c = 0; c < 32; c++){
      float a[4];
      #pragma unroll
      for (int p=0;p<4;p++) a[p] = xs[c][pxslot + 32*p];
      float4 w4 = *(const float4*)&wlds2[ch*32+c][jslot*4];
      float wv[4] = {w4.x, w4.y, w4.z, w4.w};
      #pragma unroll
      for (int jj=0;jj<4;jj++)
        #pragma unroll
        for (int p=0;p<4;p++) acc[jj][p] += wv[jj]*a[p];
    }
  }
  #pragma unroll
  for (int jj=0;jj<4;jj++){
    int o = og*32 + jslot*4 + jj;
    float bias = wf[WF_FUSEB + o];
    float* dp = xf + (size_t)b*64*NL + (size_t)o*NL + pt*128;
    #pragma unroll
    for (int p=0;p<4;p++) dp[pxslot + 32*p] = acc[jj][p] + bias;
  }
}

// ---------------- K3: inorm(xf)+lrelu + x -> x1 ----------------
__global__ __launch_bounds__(256) void k3_norm(const float* __restrict__ xf, const float* __restrict__ x,
                                               float* __restrict__ x1){
  const int tid = threadIdx.x;
  const size_t base = (size_t)blockIdx.x * NL;
  float loc[16]; float s=0.f, q=0.f;
  #pragma unroll
  for (int i=0;i<16;i++){ float v = xf[base + tid + i*256]; loc[i]=v; s+=v; q+=v*v; }
  __shared__ float red[4][2];
  int wid = tid>>6, lane = tid&63;
  #pragma unroll
  for (int o=32;o>0;o>>=1){ s += __shfl_down(s,o); q += __shfl_down(q,o); }
  if (!lane){ red[wid][0]=s; red[wid][1]=q; }
  __syncthreads();
  s = red[0][0]+red[1][0]+red[2][0]+red[3][0];
  q = red[0][1]+red[1][1]+red[2][1]+red[3][1];
  float m = s*(1.f/NL), va = q*(1.f/NL)-m*m, rs = rsqrtf(va+1e-5f);
  #pragma unroll
  for (int i=0;i<16;i++){
    int idx = tid + i*256;
    float v = (loc[i]-m)*rs;
    v = v>0.f ? v : 0.01f*v;
    x1[base+idx] = v + x[base+idx];
  }
}

// ---------------- K4: in_proj (64->256). og4 x b8 x pt32 = 1024; (256,4) ----------------
__global__ __launch_bounds__(256, 4) void k4_inproj(const float* __restrict__ x1, const float* __restrict__ wf,
                                                    float* __restrict__ xmraw, float* __restrict__ z){
  int og = blockIdx.x >> 8, rem = blockIdx.x & 255;
  int b = rem >> 5, pt = rem & 31;
  int jslot = threadIdx.x >> 5, pxslot = threadIdx.x & 31;
  __shared__ float wlds2[64][76];
  __shared__ float xs[32][128];
  {
    const float* Wg = wf + WF_INPJ + og*64*64;
    for (int i = threadIdx.x; i < 4096; i += 256){
      int o = i >> 6, k = i & 63;
      wlds2[k][o] = Wg[i];
    }
  }
  float acc[8][4];
  #pragma unroll
  for (int j=0;j<8;j++)
    #pragma unroll
    for (int p=0;p<4;p++) acc[j][p]=0.f;
  const float* xbase = x1 + (size_t)b*64*NL + pt*128;
  for (int ch = 0; ch < 2; ch++){
    __syncthreads();
    for (int i = threadIdx.x; i < 1024; i += 256){
      int r = i >> 5, c4 = i & 31;
      ((float4*)&xs[r][0])[c4] = *(const float4*)(xbase + (size_t)(ch*32+r)*NL + c4*4);
    }
    __syncthreads();
    #pragma unroll 1
    for (int c = 0; c < 32; c++){
      float a[4];
      #pragma unroll
      for (int p=0;p<4;p++) a[p] = xs[c][pxslot + 32*p];
      const float4* wp = (const float4*)&wlds2[ch*32+c][jslot*8];
      float4 w0 = wp[0], w1 = wp[1];
      float wv[8] = {w0.x,w0.y,w0.z,w0.w, w1.x,w1.y,w1.z,w1.w};
      #pragma unroll
      for (int jj=0;jj<8;jj++)
        #pragma unroll
        for (int p=0;p<4;p++) acc[jj][p] += wv[jj]*a[p];
    }
  }
  float* dstbase = (og < 2 ? xmraw + (size_t)b*128*NL + (size_t)(og*64)*NL
                           : z     + (size_t)b*128*NL + (size_t)((og-2)*64)*NL) + pt*128;
  #pragma unroll
  for (int jj=0;jj<8;jj++){
    float* dp = dstbase + (size_t)(jslot*8+jj)*NL;
    #pragma unroll
    for (int p=0;p<4;p++) dp[pxslot + 32*p] = acc[jj][p];
  }
}

// ---------------- K5: depthwise 3x3 + silu; 2 row-halves per plane; grid 2048; (256,4) ----------------
__global__ __launch_bounds__(256, 4) void k5_dw3(const float* __restrict__ xmraw, const float* __restrict__ wf,
                                                 float* __restrict__ xmc){
  const int half = blockIdx.x & 1;
  const int d = (blockIdx.x >> 1) & 127;
  const int bd = blockIdx.x >> 1;
  const int tid = threadIdx.x;
  const int r0 = half*32;
  __shared__ float xs[34*69];
  for (int i=tid;i<34*69;i+=256) xs[i]=0.f;
  const float* xp = xmraw + (size_t)bd * NL;
  float v[9];
  #pragma unroll
  for (int k=0;k<9;k++){
    int idx = tid + k*256;
    int j = idx >> 6, w = idx & 63;
    int gr = r0 - 1 + j;
    bool ok = (idx < 2176) && (gr >= 0) && (gr < 64);
    v[k] = ok ? xp[gr*64 + w] : 0.f;
  }
  float wr[9];
  #pragma unroll
  for (int i=0;i<9;i++) wr[i] = wf[WF_C2W + d*9 + i];
  float bb = wf[WF_C2B + d];
  __syncthreads();
  #pragma unroll
  for (int k=0;k<9;k++){
    int idx = tid + k*256;
    if (idx < 2176){
      int j = idx >> 6, w = idx & 63;
      xs[j*69 + (w+1)] = v[k];
    }
  }
  __syncthreads();
  float* op = xmc + (size_t)bd * NL + r0*64;
  #pragma unroll
  for (int g=0; g<2; g++){
    int p = g*1024 + tid*4;
    int lh = p>>6, w0 = p&63;
    float a[4];
    #pragma unroll
    for (int i=0;i<4;i++) a[i]=bb;
    #pragma unroll
    for (int dy=0; dy<3; dy++){
      float s[6];
      #pragma unroll
      for (int j=0;j<6;j++) s[j] = xs[(lh+dy)*69 + w0 + j];
      #pragma unroll
      for (int dx=0;dx<3;dx++){
        float wv = wr[dy*3+dx];
        #pragma unroll
        for (int i=0;i<4;i++) a[i] += s[dx+i]*wv;
      }
    }
    float4 o;
    o.x = a[0]/(1.f+__expf(-a[0]));
    o.y = a[1]/(1.f+__expf(-a[1]));
    o.z = a[2]/(1.f+__expf(-a[2]));
    o.w = a[3]/(1.f+__expf(-a[3]));
    *(float4*)(op+p) = o;
  }
}

// ---------------- K6 (slim): x_proj (128->36); grid 256; (256,3) ----------------
__global__ __launch_bounds__(256, 3) void k6_xproj(const float* __restrict__ xmc, const float* __restrict__ wf,
                                                   float* __restrict__ Bm, float* __restrict__ Cm,
                                                   float* __restrict__ dtm){
  int b = blockIdx.x >> 5, pt = blockIdx.x & 31;
  int jslot = threadIdx.x >> 6, pxslot = threadIdx.x & 63;
  __shared__ float wlds2[128][52];
  __shared__ float xs[32][128];
  {
    const float* Wg = wf + WF_XPW;
    for (int i = threadIdx.x; i < 4608; i += 256){
      int o = i >> 7, k = i & 127;
      wlds2[k][(o/9)*12 + (o%9)] = Wg[i];
    }
  }
  float acc[9][2];
  #pragma unroll
  for (int j=0;j<9;j++){ acc[j][0]=0.f; acc[j][1]=0.f; }
  const float* ubase = xmc + (size_t)b*128*NL + pt*128;
  for (int ch = 0; ch < 4; ch++){
    __syncthreads();
    for (int i = threadIdx.x; i < 1024; i += 256){
      int r = i >> 5, c4 = i & 31;
      ((float4*)&xs[r][0])[c4] = *(const float4*)(ubase + (size_t)(ch*32+r)*NL + c4*4);
    }
    __syncthreads();
    #pragma unroll 1
    for (int c = 0; c < 32; c++){
      float a0 = xs[c][pxslot];
      float a1 = xs[c][pxslot + 64];
      const float* wr = &wlds2[ch*32+c][jslot*12];
      float4 wa = *(const float4*)wr;
      float4 wb = *(const float4*)(wr+4);
      float w8 = wr[8];
      float wv[9] = {wa.x,wa.y,wa.z,wa.w, wb.x,wb.y,wb.z,wb.w, w8};
      #pragma unroll
      for (int j=0;j<9;j++){
        acc[j][0] += wv[j]*a0;
        acc[j][1] += wv[j]*a1;
      }
    }
  }
  #pragma unroll
  for (int j=0;j<9;j++){
    int o = jslot*9 + j;
    float* dp;
    if (o < 4)       dp = dtm + ((size_t)b*4 + o)*NL;
    else if (o < 20) dp = Bm  + ((size_t)b*16 + (o-4))*NL;
    else             dp = Cm  + ((size_t)b*16 + (o-20))*NL;
    dp[pt*128 + pxslot]      = acc[j][0];
    dp[pt*128 + pxslot + 64] = acc[j][1];
  }
}

// ---------------- K7: scan pass1; (128,2) -> 256 VGPR budget keeps staging batched ----------------
__global__ __launch_bounds__(128, 2) void k7_scan1(const float* __restrict__ xmc, const float* __restrict__ Bm,
                                                   const float* __restrict__ dtm, const float* __restrict__ wf,
                                                   float* __restrict__ Ac, float* __restrict__ Bc){
  int k = blockIdx.x & (NKCH-1), b = blockIdx.x >> 7;
  int d = threadIdx.x;
  int l0 = k*CHUNK;
  __shared__ float xs[128*33];
  __shared__ float Bl2[32*20];
  __shared__ float dtl2[32*4];
  float vx[32], vb[4], vd;
  #pragma unroll
  for (int j=0;j<32;j++){
    int i = d + 128*j;
    int ch = i >> 5, px = i & 31;
    vx[j] = xmc[((size_t)b*128+ch)*NL + l0 + px];
  }
  #pragma unroll
  for (int j=0;j<4;j++){
    int i = d + 128*j;
    int n = i >> 5, li = i & 31;
    vb[j] = Bm[((size_t)b*16+n)*NL + l0 + li];
  }
  { int n = d >> 5, li = d & 31; vd = dtm[((size_t)b*4+n)*NL + l0 + li]; }
  #pragma unroll
  for (int j=0;j<32;j++){
    int i = d + 128*j;
    int ch = i >> 5, px = i & 31;
    xs[ch*33+px] = vx[j];
  }
  #pragma unroll
  for (int j=0;j<4;j++){
    int i = d + 128*j;
    int n = i >> 5, li = i & 31;
    Bl2[li*20+n] = vb[j];
  }
  { int n = d >> 5, li = d & 31; dtl2[li*4+n] = vd; }
  float A[16], P[16], Q[16];
  const float* Af = wf + WF_A + d*16;
  #pragma unroll
  for (int n=0;n<16;n++){ A[n]=Af[n]; P[n]=1.f; Q[n]=0.f; }
  float w0 = wf[WF_DTW+d*4], w1 = wf[WF_DTW+d*4+1], w2 = wf[WF_DTW+d*4+2], w3 = wf[WF_DTW+d*4+3];
  float db2 = 2.f*wf[WF_DTB+d];
  __syncthreads();
  for (int l=0; l<CHUNK; l++){
    float4 dt4 = ((const float4*)dtl2)[l];
    float tt = w0*dt4.x + w1*dt4.y + w2*dt4.z + w3*dt4.w + db2;
    float de = tt > 20.f ? tt : __logf(1.f+__expf(tt));
    float du = de * xs[d*33+l];
    const float4* bp = (const float4*)(Bl2 + l*20);
    float4 b0 = bp[0], b1 = bp[1], b2 = bp[2], b3 = bp[3];
    float bb[16] = {b0.x,b0.y,b0.z,b0.w, b1.x,b1.y,b1.z,b1.w,
                    b2.x,b2.y,b2.z,b2.w, b3.x,b3.y,b3.z,b3.w};
    #pragma unroll
    for (int n=0;n<16;n++){
      float a = __expf(de*A[n]);
      P[n] *= a;
      Q[n] = a*Q[n] + du*bb[n];
    }
  }
  size_t base = (((size_t)k*NB + b)*128 + d)*16;
  #pragma unroll
  for (int i=0;i<4;i++){
    ((float4*)(Ac+base))[i] = make_float4(P[i*4],P[i*4+1],P[i*4+2],P[i*4+3]);
    ((float4*)(Bc+base))[i] = make_float4(Q[i*4],Q[i*4+1],Q[i*4+2],Q[i*4+3]);
  }
}

// ---------------- K8: middle scan; 128 thr x 128 blocks ----------------
__global__ __launch_bounds__(128, 2) void k8_mid(const float* __restrict__ Ac, const float* __restrict__ Bc,
                                                 float* __restrict__ Hi){
  int idx = blockIdx.x*128 + threadIdx.x;
  float h = 0.f;
  for (int k0=0;k0<NKCH;k0+=16){
    float av[16], bv[16];
    #pragma unroll
    for (int j=0;j<16;j++){
      size_t o = (size_t)(k0+j)*16384 + idx;
      av[j]=Ac[o]; bv[j]=Bc[o];
    }
    #pragma unroll
    for (int j=0;j<16;j++){
      size_t o = (size_t)(k0+j)*16384 + idx;
      Hi[o] = h;
      h = av[j]*h + bv[j];
    }
  }
}

// ---------------- K9: scan pass2 + fused LN*silu(z); (128,2) ----------------
__global__ __launch_bounds__(128, 2) void k9_scan2(const float* __restrict__ xmc, const float* __restrict__ Bm,
                                                   const float* __restrict__ Cm, const float* __restrict__ dtm,
                                                   const float* __restrict__ z, const float* __restrict__ wf,
                                                   const float* __restrict__ Hi, float* __restrict__ G){
  int k = blockIdx.x & (NKCH-1), b = blockIdx.x >> 7;
  int d = threadIdx.x;
  int l0 = k*CHUNK;
  __shared__ float xs[128*33];
  __shared__ float Bl2[32*20], Cl2[32*20];
  __shared__ float dtl2[32*4];
  __shared__ float red[4][32][2];
  __shared__ float mstat[32], rstat[32];
  float vx[32], vb[4], vc[4], vd;
  #pragma unroll
  for (int j=0;j<32;j++){
    int i = d + 128*j;
    int ch = i >> 5, px = i & 31;
    vx[j] = xmc[((size_t)b*128+ch)*NL + l0 + px];
  }
  #pragma unroll
  for (int j=0;j<4;j++){
    int i = d + 128*j;
    int n = i >> 5, li = i & 31;
    vb[j] = Bm[((size_t)b*16+n)*NL + l0 + li];
    vc[j] = Cm[((size_t)b*16+n)*NL + l0 + li];
  }
  { int n = d >> 5, li = d & 31; vd = dtm[((size_t)b*4+n)*NL + l0 + li]; }
  float A[16], h[16];
  const float* Af = wf + WF_A + d*16;
  size_t hb = (((size_t)k*NB + b)*128 + d)*16;
  #pragma unroll
  for (int n=0;n<16;n++){ A[n]=Af[n]; h[n]=Hi[hb+n]; }
  #pragma unroll
  for (int j=0;j<32;j++){
    int i = d + 128*j;
    int ch = i >> 5, px = i & 31;
    xs[ch*33+px] = vx[j];
  }
  #pragma unroll
  for (int j=0;j<4;j++){
    int i = d + 128*j;
    int n = i >> 5, li = i & 31;
    Bl2[li*20+n] = vb[j];
    Cl2[li*20+n] = vc[j];
  }
  { int n = d >> 5, li = d & 31; dtl2[li*4+n] = vd; }
  float Dv = wf[WF_DP + d];
  float w0 = wf[WF_DTW+d*4], w1 = wf[WF_DTW+d*4+1], w2 = wf[WF_DTW+d*4+2], w3 = wf[WF_DTW+d*4+3];
  float db2 = 2.f*wf[WF_DTB+d];
  __syncthreads();
  for (int l=0; l<CHUNK; l++){
    float4 dt4 = ((const float4*)dtl2)[l];
    float tt = w0*dt4.x + w1*dt4.y + w2*dt4.z + w3*dt4.w + db2;
    float de = tt > 20.f ? tt : __logf(1.f+__expf(tt));
    float uu = xs[d*33+l];
    float du = de * uu;
    float yv = uu * Dv;
    const float4* bp = (const float4*)(Bl2 + l*20);
    const float4* cp = (const float4*)(Cl2 + l*20);
    float4 b0 = bp[0], b1 = bp[1], b2 = bp[2], b3 = bp[3];
    float4 c0 = cp[0], c1 = cp[1], c2 = cp[2], c3 = cp[3];
    float bb[16] = {b0.x,b0.y,b0.z,b0.w, b1.x,b1.y,b1.z,b1.w,
                    b2.x,b2.y,b2.z,b2.w, b3.x,b3.y,b3.z,b3.w};
    float cc[16] = {c0.x,c0.y,c0.z,c0.w, c1.x,c1.y,c1.z,c1.w,
                    c2.x,c2.y,c2.z,c2.w, c3.x,c3.y,c3.z,c3.w};
    #pragma unroll
    for (int n=0;n<16;n++){
      float a = __expf(de*A[n]);
      h[n] = a*h[n] + du*bb[n];
      yv  += h[n]*cc[n];
    }
    xs[d*33+l] = yv;
  }
  __syncthreads();
  {
    int px = d & 31, q = d >> 5;
    float s=0.f, qq=0.f;
    #pragma unroll
    for (int j=0;j<32;j++){ float v = xs[(q*32+j)*33+px]; s+=v; qq+=v*v; }
    red[q][px][0]=s; red[q][px][1]=qq;
  }
  __syncthreads();
  if (d < 32){
    float ss = red[0][d][0]+red[1][d][0]+red[2][d][0]+red[3][d][0];
    float sq = red[0][d][1]+red[1][d][1]+red[2][d][1]+red[3][d][1];
    float m = ss*(1.f/128.f);
    mstat[d] = m;
    rstat[d] = rsqrtf(sq*(1.f/128.f) - m*m + 1e-5f);
  }
  __syncthreads();
  float ow = wf[WF_ONW+d], ob = wf[WF_ONB+d];
  const float* zp = z + ((size_t)b*128+d)*NL + l0;
  float* gp = G + ((size_t)b*128+d)*NL + l0;
  #pragma unroll
  for (int l4=0; l4<CHUNK/4; l4++){
    float4 zv4 = ((const float4*)zp)[l4];
    float zv[4] = {zv4.x, zv4.y, zv4.z, zv4.w};
    float out[4];
    #pragma unroll
    for (int j=0;j<4;j++){
      int l = l4*4+j;
      float t = (xs[d*33+l]-mstat[l])*rstat[l]*ow + ob;
      out[j] = t * (zv[j]/(1.f+__expf(-zv[j])));
    }
    ((float4*)gp)[l4] = make_float4(out[0],out[1],out[2],out[3]);
  }
}

// ---------------- K11A: yc = W_comb @ G + cf_b. og2 x b8 x pt32 = 512; (256,4); + stats ----------------
__global__ __launch_bounds__(256, 4) void k11A_proj(const float* __restrict__ G, const float* __restrict__ wf,
                                                    const float* __restrict__ wcomb,
                                                    float* __restrict__ yc, float* __restrict__ part){
  int og = blockIdx.x >> 8, rem = blockIdx.x & 255;
  int b = rem >> 5, pt = rem & 31;
  int jslot = threadIdx.x >> 5, pxslot = threadIdx.x & 31;
  __shared__ float wlds2[128][44];
  __shared__ float xs[32][128];
  {
    const float* Wg = wcomb + og*32*128;
    for (int i = threadIdx.x; i < 4096; i += 256){
      int o = i >> 7, k = i & 127;
      wlds2[k][o] = Wg[i];
    }
  }
  float acc[4][4];
  #pragma unroll
  for (int j=0;j<4;j++)
    #pragma unroll
    for (int p=0;p<4;p++) acc[j][p]=0.f;
  const float* gbase = G + (size_t)b*128*NL + pt*128;
  for (int ch = 0; ch < 4; ch++){
    __syncthreads();
    for (int i = threadIdx.x; i < 1024; i += 256){
      int r = i >> 5, c4 = i & 31;
      ((float4*)&xs[r][0])[c4] = *(const float4*)(gbase + (size_t)(ch*32+r)*NL + c4*4);
    }
    __syncthreads();
    #pragma unroll 1
    for (int c = 0; c < 32; c++){
      float a[4];
      #pragma unroll
      for (int p=0;p<4;p++) a[p] = xs[c][pxslot + 32*p];
      float4 w4 = *(const float4*)&wlds2[ch*32+c][jslot*4];
      float wv[4] = {w4.x, w4.y, w4.z, w4.w};
      #pragma unroll
      for (int jj=0;jj<4;jj++)
        #pragma unroll
        for (int p=0;p<4;p++) acc[jj][p] += wv[jj]*a[p];
    }
  }
  #pragma unroll
  for (int jj=0;jj<4;jj++){
    int cc = og*32 + jslot*4 + jj;
    float bias = wf[WF_CFB + cc];
    float* dp = yc + (size_t)b*64*NL + (size_t)cc*NL + pt*128;
    float sv = 0.f, qv = 0.f;
    #pragma unroll
    for (int p=0;p<4;p++){
      float t = acc[jj][p] + bias;
      dp[pxslot + 32*p] = t;
      sv += t; qv += t*t;
    }
    #pragma unroll
    for (int o=16;o>0;o>>=1){ sv += __shfl_xor(sv,o); qv += __shfl_xor(qv,o); }
    if (pxslot == 0){
      size_t pidx = (((size_t)b*64 + cc)*32 + pt)*2;
      part[pidx] = sv; part[pidx+1] = qv;
    }
  }
}

// ---------------- K11c: out = x1 + inorm(yc); stats reduced in-block from 32 partials ----------------
__global__ __launch_bounds__(256) void k11c_final(const float* __restrict__ yc, const float* __restrict__ part,
                                                  const float* __restrict__ x1, float* __restrict__ out){
  int bc = blockIdx.x;
  __shared__ float sm, sr;
  if (threadIdx.x == 0){
    float s=0.f, q=0.f;
    #pragma unroll
    for (int t2=0;t2<32;t2++){ s += part[((size_t)bc*32+t2)*2]; q += part[((size_t)bc*32+t2)*2+1]; }
    float m = s*(1.f/NL);
    sm = m; sr = rsqrtf(q*(1.f/NL) - m*m + 1e-5f);
  }
  __syncthreads();
  float m = sm, rs = sr;
  size_t base = (size_t)bc*NL;
  for (int i=threadIdx.x;i<NL;i+=256){
    float v = (yc[base+i]-m)*rs;
    out[base+i] = x1[base+i] + v;
  }
}

// ---------------- host ----------------
extern "C" void kernel_launch(void* const* d_in, const int* in_sizes, int n_in,
                              void* d_out, int out_size, void* d_ws, size_t ws_size,
                              hipStream_t stream) {
  if (ws_size < WS_NEED_FLOATS * sizeof(float)) return;
  const float* x     = (const float*)d_in[0];
  const float* dw3w  = (const float*)d_in[1];
  const float* dw3b  = (const float*)d_in[2];
  const float* dw5w  = (const float*)d_in[3];
  const float* dw5b  = (const float*)d_in[4];
  const float* dw7w  = (const float*)d_in[5];
  const float* dw7b  = (const float*)d_in[6];
  const float* fusew = (const float*)d_in[7];
  const float* fuseb = (const float*)d_in[8];
  const float* inpjw = (const float*)d_in[9];
  const float* c2w   = (const float*)d_in[10];
  const float* c2b   = (const float*)d_in[11];
  const float* xpw   = (const float*)d_in[12];
  const float* dtw   = (const float*)d_in[13];
  const float* dtb   = (const float*)d_in[14];
  const float* alog  = (const float*)d_in[15];
  const float* dpv   = (const float*)d_in[16];
  const float* onw   = (const float*)d_in[17];
  const float* onb   = (const float*)d_in[18];
  const float* opw   = (const float*)d_in[19];
  const float* cfw   = (const float*)d_in[20];
  const float* cfb   = (const float*)d_in[21];

  float* ws    = (float*)d_ws;
  float* wf    = ws + OFF_WF;
  float* wcomb = ws + OFF_WCOMB;
  float* feats = ws + OFF_FEATS;
  float* xf    = ws + OFF_XF;
  float* x1    = ws + OFF_X1;
  float* xmraw = ws + OFF_XMRAW;
  float* z     = ws + OFF_Z;
  float* xmc   = ws + OFF_XMC;
  float* Bmw   = ws + OFF_BMAT;
  float* Cmw   = ws + OFF_CMAT;
  float* dtm   = ws + OFF_DTM;
  float* Acb   = ws + OFF_AC;
  float* Bcb   = ws + OFF_BC;
  float* Hi    = ws + OFF_HINIT;
  float* G     = ws + OFF_G;
  float* yc    = ws + OFF_YC;
  float* part  = ws + OFF_PART;

  CvtArgs ca; int ns = 0;
  auto add = [&](const float* s, int off, int n, int op){
    ca.d[ns].src = s; ca.d[ns].dst = wf + off; ca.d[ns].n = n; ca.d[ns].op = op; ns++;
  };
  add(dw3w, WF_DW3, 576, 0);   add(dw5w, WF_DW5, 1600, 0);  add(dw7w, WF_DW7, 3136, 0);
  add(dw3b, WF_B3, 64, 0);     add(dw5b, WF_B5, 64, 0);     add(dw7b, WF_B7, 64, 0);
  add(fusew, WF_FUSE, 12288, 0); add(fuseb, WF_FUSEB, 64, 0);
  add(c2w, WF_C2W, 1152, 0);   add(c2b, WF_C2B, 128, 0);
  add(xpw, WF_XPW, 4608, 0);   add(dtw, WF_DTW, 512, 0);    add(dtb, WF_DTB, 128, 0);
  add(alog, WF_A, 2048, 1);    // A = -exp(A_log)
  add(dpv, WF_DP, 128, 0);
  add(onw, WF_ONW, 128, 0);    add(onb, WF_ONB, 128, 0);
  add(opw, WF_OPW, 8192, 0);
  add(cfw, WF_CFW, 4096, 0);   add(cfb, WF_CFB, 64, 0);
  add(inpjw, WF_INPJ, 16384, 0);
  ca.ncvt = ns; ca.cfw = cfw; ca.opw = opw; ca.wcomb = wcomb;

  k0_cvt<<<ns + 32, 256, 0, stream>>>(ca);
  k1_dw<<<2048, 256, 0, stream>>>(x, wf, feats, part);
  k2_fuse<<<512, 256, 0, stream>>>(feats, part, wf, xf);
  k3_norm<<<512, 256, 0, stream>>>(xf, x, x1);
  k4_inproj<<<1024, 256, 0, stream>>>(x1, wf, xmraw, z);
  k5_dw3<<<2048, 256, 0, stream>>>(xmraw, wf, xmc);
  k6_xproj<<<256, 256, 0, stream>>>(xmc, wf, Bmw, Cmw, dtm);
  k7_scan1<<<1024, 128, 0, stream>>>(xmc, Bmw, dtm, wf, Acb, Bcb);
  k8_mid<<<128, 128, 0, stream>>>(Acb, Bcb, Hi);
  k9_scan2<<<1024, 128, 0, stream>>>(xmc, Bmw, Cmw, dtm, z, wf, Hi, G);
  k11A_proj<<<512, 256, 0, stream>>>(G, wf, wcomb, yc, part);
  k11c_final<<<512, 256, 0, stream>>>(yc, part, x1, (float*)d_out);
}

// Round 16
// 207.068 us; speedup vs baseline: 3.2892x; 1.0013x over previous
//
#include <hip/hip_runtime.h>
#include <math.h>

#define NB 8
#define NC 64
#define NL 4096
#define NDI 128
#define NN 16
#define CHUNK 16
#define NKCH 256   // NL / CHUNK

// ---------------- workspace layout (float offsets) ----------------
#define OFF_FEATS 0ull
#define OFF_AC    0ull          // 4194304 (Ac; Hi aliases this after k8)
#define OFF_XF    6291456ull
#define OFF_BMAT  6291456ull
#define OFF_CMAT  6815744ull
#define OFF_X1    8388608ull
#define OFF_XMRAW 10485760ull
#define OFF_BC    10485760ull   // 4194304 (Bc; dead after k8 -> G overwrites)
#define OFF_G     10485760ull
#define OFF_Z     14680064ull
#define OFF_YC    14680064ull
#define OFF_PART  16777216ull
#define OFF_XMC   18874368ull
#define OFF_DTM   23068672ull
#define OFF_WF    27262976ull
#define OFF_WCOMB (OFF_WF + 58624ull)
#define WS_NEED_FLOATS (OFF_WF + 66816ull)

// weight sub-offsets inside WF (floats)
#define WF_DW3    0
#define WF_DW5    576
#define WF_DW7    2176
#define WF_B3     5312
#define WF_B5     5376
#define WF_B7     5440
#define WF_FUSE   5504
#define WF_FUSEB  17792
#define WF_C2W    17856
#define WF_C2B    19008
#define WF_XPW    19136
#define WF_DTW    23744
#define WF_DTB    24256
#define WF_A      24384
#define WF_DP     26432
#define WF_ONW    26560
#define WF_ONB    26688
#define WF_OPW    26816
#define WF_CFW    35008
#define WF_CFB    39104
#define WF_INPJ   39168

// ---------------- K0 ----------------
struct Cvt { const float* src; float* dst; int n; int op; };
struct CvtArgs { Cvt d[22]; int ncvt; const float* cfw; const float* opw; float* wcomb; };

__global__ __launch_bounds__(256) void k0_cvt(CvtArgs a){
  if ((int)blockIdx.x < a.ncvt){
    Cvt c = a.d[blockIdx.x];
    for (int i = threadIdx.x; i < c.n; i += 256){
      float v = c.src[i];
      c.dst[i] = c.op ? -expf(v) : v;
    }
  } else {
    int idx = (blockIdx.x - a.ncvt)*256 + threadIdx.x;
    int c = idx >> 7, kk = idx & 127;
    float s = 0.f;
    #pragma unroll
    for (int j=0;j<64;j++) s += a.cfw[c*64+j] * a.opw[j*128+kk];
    a.wcomb[idx] = s;
  }
}

// ---------------- K1: dw convs, 4 row-quarters per plane; grid 2048 ----------------
__global__ __launch_bounds__(256, 4) void k1_dw(const float* __restrict__ x, const float* __restrict__ wf,
                                                float* __restrict__ feats, float* __restrict__ part){
  const int quar = blockIdx.x & 3, c = (blockIdx.x >> 2) & 63, b = blockIdx.x >> 8;
  const int tid = threadIdx.x;
  const int r0 = quar*16;
  __shared__ float xs[22*73];
  __shared__ float red[4][6];
  for (int i = tid; i < 22*73; i += 256) xs[i] = 0.f;
  const float* xp = x + ((size_t)b*64 + c)*NL;
  float v[6];
  #pragma unroll
  for (int k=0;k<6;k++){
    int idx = tid + k*256;
    int j = idx >> 6, w = idx & 63;
    int gr = r0 - 3 + j;
    bool ok = (idx < 1408) && (gr >= 0) && (gr < 64);
    v[k] = ok ? xp[gr*64 + w] : 0.f;
  }
  float w3r[9], w5r[25], w7r[49];
  #pragma unroll
  for (int i=0;i<9;i++)  w3r[i] = wf[WF_DW3 + c*9 + i];
  #pragma unroll
  for (int i=0;i<25;i++) w5r[i] = wf[WF_DW5 + c*25 + i];
  #pragma unroll
  for (int i=0;i<49;i++) w7r[i] = wf[WF_DW7 + c*49 + i];
  float b3 = wf[WF_B3+c], b5 = wf[WF_B5+c], b7 = wf[WF_B7+c];
  __syncthreads();
  #pragma unroll
  for (int k=0;k<6;k++){
    int idx = tid + k*256;
    if (idx < 1408){
      int j = idx >> 6, w = idx & 63;
      xs[j*73 + (w+3)] = v[k];
    }
  }
  __syncthreads();
  float s3=0,q3=0,s5=0,q5=0,s7=0,q7=0;
  float* f3 = feats + ((size_t)b*192 + c) * NL + r0*64;
  float* f5 = f3 + (size_t)64*NL;
  float* f7 = f3 + (size_t)128*NL;
  {
    int p = tid*4;
    int lh = p >> 6, w0 = p & 63;
    float a3[4], a5[4], a7[4];
    #pragma unroll
    for (int i=0;i<4;i++){ a3[i]=b3; a5[i]=b5; a7[i]=b7; }
    #pragma unroll
    for (int dy=0; dy<7; dy++){
      float s[10];
      #pragma unroll
      for (int j=0;j<10;j++) s[j] = xs[(lh+dy)*73 + w0 + j];
      #pragma unroll
      for (int dx=0;dx<7;dx++){
        float wv = w7r[dy*7+dx];
        #pragma unroll
        for (int i=0;i<4;i++) a7[i] += s[dx+i]*wv;
      }
      if (dy>=1 && dy<=5){
        #pragma unroll
        for (int dx=0;dx<5;dx++){
          float wv = w5r[(dy-1)*5+dx];
          #pragma unroll
          for (int i=0;i<4;i++) a5[i] += s[dx+1+i]*wv;
        }
      }
      if (dy>=2 && dy<=4){
        #pragma unroll
        for (int dx=0;dx<3;dx++){
          float wv = w3r[(dy-2)*3+dx];
          #pragma unroll
          for (int i=0;i<4;i++) a3[i] += s[dx+2+i]*wv;
        }
      }
    }
    *(float4*)(f3+p) = make_float4(a3[0],a3[1],a3[2],a3[3]);
    *(float4*)(f5+p) = make_float4(a5[0],a5[1],a5[2],a5[3]);
    *(float4*)(f7+p) = make_float4(a7[0],a7[1],a7[2],a7[3]);
    #pragma unroll
    for (int i=0;i<4;i++){
      s3+=a3[i]; q3+=a3[i]*a3[i];
      s5+=a5[i]; q5+=a5[i]*a5[i];
      s7+=a7[i]; q7+=a7[i]*a7[i];
    }
  }
  int wid = tid>>6, lane = tid&63;
  float v6[6]={s3,q3,s5,q5,s7,q7};
  #pragma unroll
  for (int j=0;j<6;j++){
    float t = v6[j];
    #pragma unroll
    for (int o=32;o>0;o>>=1) t += __shfl_down(t,o);
    if (!lane) red[wid][j]=t;
  }
  __syncthreads();
  if (tid < 3){
    float su = red[0][tid*2]+red[1][tid*2]+red[2][tid*2]+red[3][tid*2];
    float sq = red[0][tid*2+1]+red[1][tid*2+1]+red[2][tid*2+1]+red[3][tid*2+1];
    size_t k = (size_t)(b*192 + tid*64 + c)*8 + quar*2;
    part[k]   = su;
    part[k+1] = sq;
  }
}

// ---------------- K2: fuse 1x1 (192->64) ----------------
__global__ __launch_bounds__(256, 3) void k2_fuse(const float* __restrict__ feats, const float* __restrict__ npart,
                                                  const float* __restrict__ wf, float* __restrict__ xf){
  int og = blockIdx.x >> 8, rem = blockIdx.x & 255;
  int b = rem >> 5, pt = rem & 31;
  int jslot = threadIdx.x >> 5, pxslot = threadIdx.x & 31;
  __shared__ float wlds2[192][44];
  __shared__ float xs[32][128];
  __shared__ float msl[192], rsl[192];
  for (int i = threadIdx.x; i < 192; i += 256){
    const float* pp = npart + (size_t)(b*192+i)*8;
    float su = pp[0]+pp[2]+pp[4]+pp[6], sq = pp[1]+pp[3]+pp[5]+pp[7];
    float m = su*(1.f/NL);
    msl[i] = m;
    rsl[i] = rsqrtf(sq*(1.f/NL) - m*m + 1e-5f);
  }
  {
    const float* Wg = wf + WF_FUSE + og*32*192;
    for (int i = threadIdx.x; i < 6144; i += 256){
      int o = i / 192, k = i % 192;
      wlds2[k][o] = Wg[i];
    }
  }
  float acc[4][4];
  #pragma unroll
  for (int j=0;j<4;j++)
    #pragma unroll
    for (int p=0;p<4;p++) acc[j][p]=0.f;
  const float* fbase = feats + (size_t)b*192*NL + pt*128;
  for (int ch = 0; ch < 6; ch++){
    __syncthreads();
    for (int i = threadIdx.x; i < 1024; i += 256){
      int r = i >> 5, c4 = i & 31;
      int k = ch*32 + r;
      float4 f = *(const float4*)(fbase + (size_t)k*NL + c4*4);
      float m = msl[k], rs = rsl[k];
      float v0=(f.x-m)*rs, v1=(f.y-m)*rs, v2=(f.z-m)*rs, v3=(f.w-m)*rs;
      v0 = v0>0.f?v0:0.01f*v0; v1 = v1>0.f?v1:0.01f*v1;
      v2 = v2>0.f?v2:0.01f*v2; v3 = v3>0.f?v3:0.01f*v3;
      ((float4*)&xs[r][0])[c4] = make_float4(v0,v1,v2,v3);
    }
    __syncthreads();
    #pragma unroll 1
    for (int c = 0; c < 32; c++){
      float a[4];
      #pragma unroll
      for (int p=0;p<4;p++) a[p] = xs[c][pxslot + 32*p];
      float4 w4 = *(const float4*)&wlds2[ch*32+c][jslot*4];
      float wv[4] = {w4.x, w4.y, w4.z, w4.w};
      #pragma unroll
      for (int jj=0;jj<4;jj++)
        #pragma unroll
        for (int p=0;p<4;p++) acc[jj][p] += wv[jj]*a[p];
    }
  }
  #pragma unroll
  for (int jj=0;jj<4;jj++){
    int o = og*32 + jslot*4 + jj;
    float bias = wf[WF_FUSEB + o];
    float* dp = xf + (size_t)b*64*NL + (size_t)o*NL + pt*128;
    #pragma unroll
    for (int p=0;p<4;p++) dp[pxslot + 32*p] = acc[jj][p] + bias;
  }
}

// ---------------- K3: inorm(xf)+lrelu + x -> x1 ----------------
__global__ __launch_bounds__(256) void k3_norm(const float* __restrict__ xf, const float* __restrict__ x,
                                               float* __restrict__ x1){
  const int tid = threadIdx.x;
  const size_t base = (size_t)blockIdx.x * NL;
  float loc[16]; float s=0.f, q=0.f;
  #pragma unroll
  for (int i=0;i<16;i++){ float v = xf[base + tid + i*256]; loc[i]=v; s+=v; q+=v*v; }
  __shared__ float red[4][2];
  int wid = tid>>6, lane = tid&63;
  #pragma unroll
  for (int o=32;o>0;o>>=1){ s += __shfl_down(s,o); q += __shfl_down(q,o); }
  if (!lane){ red[wid][0]=s; red[wid][1]=q; }
  __syncthreads();
  s = red[0][0]+red[1][0]+red[2][0]+red[3][0];
  q = red[0][1]+red[1][1]+red[2][1]+red[3][1];
  float m = s*(1.f/NL), va = q*(1.f/NL)-m*m, rs = rsqrtf(va+1e-5f);
  #pragma unroll
  for (int i=0;i<16;i++){
    int idx = tid + i*256;
    float v = (loc[i]-m)*rs;
    v = v>0.f ? v : 0.01f*v;
    x1[base+idx] = v + x[base+idx];
  }
}

// ---------------- K4: in_proj (64->256) ----------------
__global__ __launch_bounds__(256, 4) void k4_inproj(const float* __restrict__ x1, const float* __restrict__ wf,
                                                    float* __restrict__ xmraw, float* __restrict__ z){
  int og = blockIdx.x >> 8, rem = blockIdx.x & 255;
  int b = rem >> 5, pt = rem & 31;
  int jslot = threadIdx.x >> 5, pxslot = threadIdx.x & 31;
  __shared__ float wlds2[64][76];
  __shared__ float xs[32][128];
  {
    const float* Wg = wf + WF_INPJ + og*64*64;
    for (int i = threadIdx.x; i < 4096; i += 256){
      int o = i >> 6, k = i & 63;
      wlds2[k][o] = Wg[i];
    }
  }
  float acc[8][4];
  #pragma unroll
  for (int j=0;j<8;j++)
    #pragma unroll
    for (int p=0;p<4;p++) acc[j][p]=0.f;
  const float* xbase = x1 + (size_t)b*64*NL + pt*128;
  for (int ch = 0; ch < 2; ch++){
    __syncthreads();
    for (int i = threadIdx.x; i < 1024; i += 256){
      int r = i >> 5, c4 = i & 31;
      ((float4*)&xs[r][0])[c4] = *(const float4*)(xbase + (size_t)(ch*32+r)*NL + c4*4);
    }
    __syncthreads();
    #pragma unroll 1
    for (int c = 0; c < 32; c++){
      float a[4];
      #pragma unroll
      for (int p=0;p<4;p++) a[p] = xs[c][pxslot + 32*p];
      const float4* wp = (const float4*)&wlds2[ch*32+c][jslot*8];
      float4 w0 = wp[0], w1 = wp[1];
      float wv[8] = {w0.x,w0.y,w0.z,w0.w, w1.x,w1.y,w1.z,w1.w};
      #pragma unroll
      for (int jj=0;jj<8;jj++)
        #pragma unroll
        for (int p=0;p<4;p++) acc[jj][p] += wv[jj]*a[p];
    }
  }
  float* dstbase = (og < 2 ? xmraw + (size_t)b*128*NL + (size_t)(og*64)*NL
                           : z     + (size_t)b*128*NL + (size_t)((og-2)*64)*NL) + pt*128;
  #pragma unroll
  for (int jj=0;jj<8;jj++){
    float* dp = dstbase + (size_t)(jslot*8+jj)*NL;
    #pragma unroll
    for (int p=0;p<4;p++) dp[pxslot + 32*p] = acc[jj][p];
  }
}

// ---------------- K5: depthwise 3x3 + silu; grid 2048 ----------------
__global__ __launch_bounds__(256, 4) void k5_dw3(const float* __restrict__ xmraw, const float* __restrict__ wf,
                                                 float* __restrict__ xmc){
  const int half = blockIdx.x & 1;
  const int d = (blockIdx.x >> 1) & 127;
  const int bd = blockIdx.x >> 1;
  const int tid = threadIdx.x;
  const int r0 = half*32;
  __shared__ float xs[34*69];
  for (int i=tid;i<34*69;i+=256) xs[i]=0.f;
  const float* xp = xmraw + (size_t)bd * NL;
  float v[9];
  #pragma unroll
  for (int k=0;k<9;k++){
    int idx = tid + k*256;
    int j = idx >> 6, w = idx & 63;
    int gr = r0 - 1 + j;
    bool ok = (idx < 2176) && (gr >= 0) && (gr < 64);
    v[k] = ok ? xp[gr*64 + w] : 0.f;
  }
  float wr[9];
  #pragma unroll
  for (int i=0;i<9;i++) wr[i] = wf[WF_C2W + d*9 + i];
  float bb = wf[WF_C2B + d];
  __syncthreads();
  #pragma unroll
  for (int k=0;k<9;k++){
    int idx = tid + k*256;
    if (idx < 2176){
      int j = idx >> 6, w = idx & 63;
      xs[j*69 + (w+1)] = v[k];
    }
  }
  __syncthreads();
  float* op = xmc + (size_t)bd * NL + r0*64;
  #pragma unroll
  for (int g=0; g<2; g++){
    int p = g*1024 + tid*4;
    int lh = p>>6, w0 = p&63;
    float a[4];
    #pragma unroll
    for (int i=0;i<4;i++) a[i]=bb;
    #pragma unroll
    for (int dy=0; dy<3; dy++){
      float s[6];
      #pragma unroll
      for (int j=0;j<6;j++) s[j] = xs[(lh+dy)*69 + w0 + j];
      #pragma unroll
      for (int dx=0;dx<3;dx++){
        float wv = wr[dy*3+dx];
        #pragma unroll
        for (int i=0;i<4;i++) a[i] += s[dx+i]*wv;
      }
    }
    float4 o;
    o.x = a[0]/(1.f+__expf(-a[0]));
    o.y = a[1]/(1.f+__expf(-a[1]));
    o.z = a[2]/(1.f+__expf(-a[2]));
    o.w = a[3]/(1.f+__expf(-a[3]));
    *(float4*)(op+p) = o;
  }
}

// ---------------- K6 (slim): x_proj (128->36) ----------------
__global__ __launch_bounds__(256, 3) void k6_xproj(const float* __restrict__ xmc, const float* __restrict__ wf,
                                                   float* __restrict__ Bm, float* __restrict__ Cm,
                                                   float* __restrict__ dtm){
  int b = blockIdx.x >> 5, pt = blockIdx.x & 31;
  int jslot = threadIdx.x >> 6, pxslot = threadIdx.x & 63;
  __shared__ float wlds2[128][52];
  __shared__ float xs[32][128];
  {
    const float* Wg = wf + WF_XPW;
    for (int i = threadIdx.x; i < 4608; i += 256){
      int o = i >> 7, k = i & 127;
      wlds2[k][(o/9)*12 + (o%9)] = Wg[i];
    }
  }
  float acc[9][2];
  #pragma unroll
  for (int j=0;j<9;j++){ acc[j][0]=0.f; acc[j][1]=0.f; }
  const float* ubase = xmc + (size_t)b*128*NL + pt*128;
  for (int ch = 0; ch < 4; ch++){
    __syncthreads();
    for (int i = threadIdx.x; i < 1024; i += 256){
      int r = i >> 5, c4 = i & 31;
      ((float4*)&xs[r][0])[c4] = *(const float4*)(ubase + (size_t)(ch*32+r)*NL + c4*4);
    }
    __syncthreads();
    #pragma unroll 1
    for (int c = 0; c < 32; c++){
      float a0 = xs[c][pxslot];
      float a1 = xs[c][pxslot + 64];
      const float* wr = &wlds2[ch*32+c][jslot*12];
      float4 wa = *(const float4*)wr;
      float4 wb = *(const float4*)(wr+4);
      float w8 = wr[8];
      float wv[9] = {wa.x,wa.y,wa.z,wa.w, wb.x,wb.y,wb.z,wb.w, w8};
      #pragma unroll
      for (int j=0;j<9;j++){
        acc[j][0] += wv[j]*a0;
        acc[j][1] += wv[j]*a1;
      }
    }
  }
  #pragma unroll
  for (int j=0;j<9;j++){
    int o = jslot*9 + j;
    float* dp;
    if (o < 4)       dp = dtm + ((size_t)b*4 + o)*NL;
    else if (o < 20) dp = Bm  + ((size_t)b*16 + (o-4))*NL;
    else             dp = Cm  + ((size_t)b*16 + (o-20))*NL;
    dp[pt*128 + pxslot]      = acc[j][0];
    dp[pt*128 + pxslot + 64] = acc[j][1];
  }
}

// ---------------- K7: scan pass1; CHUNK=16; grid 2048; power-chain exp ----------------
__global__ __launch_bounds__(128, 4) void k7_scan1(const float* __restrict__ xmc, const float* __restrict__ Bm,
                                                   const float* __restrict__ dtm, const float* __restrict__ wf,
                                                   float* __restrict__ Ac, float* __restrict__ Bc){
  int k = blockIdx.x & (NKCH-1), b = blockIdx.x >> 8;
  int d = threadIdx.x;
  int l0 = k*CHUNK;
  __shared__ float xs[128*17];
  __shared__ float Bl2[16*20];
  __shared__ float dtl2[16*4];
  float vx[16], vb[2], vd = 0.f;
  #pragma unroll
  for (int j=0;j<16;j++){
    int i = d + 128*j;
    int ch = i >> 4, px = i & 15;
    vx[j] = xmc[((size_t)b*128+ch)*NL + l0 + px];
  }
  #pragma unroll
  for (int j=0;j<2;j++){
    int i = d + 128*j;
    int n = i >> 4, li = i & 15;
    vb[j] = Bm[((size_t)b*16+n)*NL + l0 + li];
  }
  if (d < 64){ int n = d >> 4, li = d & 15; vd = dtm[((size_t)b*4+n)*NL + l0 + li]; }
  #pragma unroll
  for (int j=0;j<16;j++){
    int i = d + 128*j;
    int ch = i >> 4, px = i & 15;
    xs[ch*17+px] = vx[j];
  }
  #pragma unroll
  for (int j=0;j<2;j++){
    int i = d + 128*j;
    int n = i >> 4, li = i & 15;
    Bl2[li*20+n] = vb[j];
  }
  if (d < 64){ int n = d >> 4, li = d & 15; dtl2[li*4+n] = vd; }
  float A[16], P[16], Q[16];
  const float* Af = wf + WF_A + d*16;
  bool fastA = true;
  #pragma unroll
  for (int n=0;n<16;n++){
    A[n]=Af[n]; P[n]=1.f; Q[n]=0.f;
    fastA = fastA && (fabsf(A[n] + (float)(n+1)) < 1e-3f);
  }
  float w0 = wf[WF_DTW+d*4], w1 = wf[WF_DTW+d*4+1], w2 = wf[WF_DTW+d*4+2], w3 = wf[WF_DTW+d*4+3];
  float db2 = 2.f*wf[WF_DTB+d];
  __syncthreads();
  for (int l=0; l<CHUNK; l++){
    float4 dt4 = ((const float4*)dtl2)[l];
    float tt = w0*dt4.x + w1*dt4.y + w2*dt4.z + w3*dt4.w + db2;
    float de = tt > 20.f ? tt : __logf(1.f+__expf(tt));
    float du = de * xs[d*17+l];
    const float4* bp = (const float4*)(Bl2 + l*20);
    float4 b0 = bp[0], b1 = bp[1], b2 = bp[2], b3 = bp[3];
    float bb[16] = {b0.x,b0.y,b0.z,b0.w, b1.x,b1.y,b1.z,b1.w,
                    b2.x,b2.y,b2.z,b2.w, b3.x,b3.y,b3.z,b3.w};
    if (fastA){
      float r = __expf(-de);
      float ap = 1.f;
      #pragma unroll
      for (int n=0;n<16;n++){
        ap *= r;
        P[n] *= ap;
        Q[n] = ap*Q[n] + du*bb[n];
      }
    } else {
      #pragma unroll
      for (int n=0;n<16;n++){
        float a = __expf(de*A[n]);
        P[n] *= a;
        Q[n] = a*Q[n] + du*bb[n];
      }
    }
  }
  size_t base = (((size_t)k*NB + b)*128 + d)*16;
  #pragma unroll
  for (int i=0;i<4;i++){
    ((float4*)(Ac+base))[i] = make_float4(P[i*4],P[i*4+1],P[i*4+2],P[i*4+3]);
    ((float4*)(Bc+base))[i] = make_float4(Q[i*4],Q[i*4+1],Q[i*4+2],Q[i*4+3]);
  }
}

// ---------------- K8: middle scan; Hi aliases Ac (in-thread read-then-write) ----------------
__global__ __launch_bounds__(128, 2) void k8_mid(const float* Ac, const float* __restrict__ Bc,
                                                 float* Hi){
  int idx = blockIdx.x*128 + threadIdx.x;
  float h = 0.f;
  for (int k0=0;k0<NKCH;k0+=16){
    float av[16], bv[16];
    #pragma unroll
    for (int j=0;j<16;j++){
      size_t o = (size_t)(k0+j)*16384 + idx;
      av[j]=Ac[o]; bv[j]=Bc[o];
    }
    #pragma unroll
    for (int j=0;j<16;j++){
      size_t o = (size_t)(k0+j)*16384 + idx;
      Hi[o] = h;
      h = av[j]*h + bv[j];
    }
  }
}

// ---------------- K9: scan pass2 + fused LN*silu(z); CHUNK=16; grid 2048; power-chain ----------------
__global__ __launch_bounds__(128, 4) void k9_scan2(const float* __restrict__ xmc, const float* __restrict__ Bm,
                                                   const float* __restrict__ Cm, const float* __restrict__ dtm,
                                                   const float* __restrict__ z, const float* __restrict__ wf,
                                                   const float* __restrict__ Hi, float* __restrict__ G){
  int k = blockIdx.x & (NKCH-1), b = blockIdx.x >> 8;
  int d = threadIdx.x;
  int l0 = k*CHUNK;
  __shared__ float xs[128*17];
  __shared__ float Bl2[16*20], Cl2[16*20];
  __shared__ float dtl2[16*4];
  __shared__ float red[8][16][2];
  __shared__ float mstat[16], rstat[16];
  float vx[16], vb[2], vc[2], vd = 0.f;
  #pragma unroll
  for (int j=0;j<16;j++){
    int i = d + 128*j;
    int ch = i >> 4, px = i & 15;
    vx[j] = xmc[((size_t)b*128+ch)*NL + l0 + px];
  }
  #pragma unroll
  for (int j=0;j<2;j++){
    int i = d + 128*j;
    int n = i >> 4, li = i & 15;
    vb[j] = Bm[((size_t)b*16+n)*NL + l0 + li];
    vc[j] = Cm[((size_t)b*16+n)*NL + l0 + li];
  }
  if (d < 64){ int n = d >> 4, li = d & 15; vd = dtm[((size_t)b*4+n)*NL + l0 + li]; }
  float A[16], h[16];
  const float* Af = wf + WF_A + d*16;
  size_t hb = (((size_t)k*NB + b)*128 + d)*16;
  bool fastA = true;
  #pragma unroll
  for (int n=0;n<16;n++){
    A[n]=Af[n]; h[n]=Hi[hb+n];
    fastA = fastA && (fabsf(A[n] + (float)(n+1)) < 1e-3f);
  }
  #pragma unroll
  for (int j=0;j<16;j++){
    int i = d + 128*j;
    int ch = i >> 4, px = i & 15;
    xs[ch*17+px] = vx[j];
  }
  #pragma unroll
  for (int j=0;j<2;j++){
    int i = d + 128*j;
    int n = i >> 4, li = i & 15;
    Bl2[li*20+n] = vb[j];
    Cl2[li*20+n] = vc[j];
  }
  if (d < 64){ int n = d >> 4, li = d & 15; dtl2[li*4+n] = vd; }
  float Dv = wf[WF_DP + d];
  float w0 = wf[WF_DTW+d*4], w1 = wf[WF_DTW+d*4+1], w2 = wf[WF_DTW+d*4+2], w3 = wf[WF_DTW+d*4+3];
  float db2 = 2.f*wf[WF_DTB+d];
  __syncthreads();
  for (int l=0; l<CHUNK; l++){
    float4 dt4 = ((const float4*)dtl2)[l];
    float tt = w0*dt4.x + w1*dt4.y + w2*dt4.z + w3*dt4.w + db2;
    float de = tt > 20.f ? tt : __logf(1.f+__expf(tt));
    float uu = xs[d*17+l];
    float du = de * uu;
    float yv = uu * Dv;
    const float4* bp = (const float4*)(Bl2 + l*20);
    const float4* cp = (const float4*)(Cl2 + l*20);
    float4 b0 = bp[0], b1 = bp[1], b2 = bp[2], b3 = bp[3];
    float4 c0 = cp[0], c1 = cp[1], c2 = cp[2], c3 = cp[3];
    float bb[16] = {b0.x,b0.y,b0.z,b0.w, b1.x,b1.y,b1.z,b1.w,
                    b2.x,b2.y,b2.z,b2.w, b3.x,b3.y,b3.z,b3.w};
    float cc[16] = {c0.x,c0.y,c0.z,c0.w, c1.x,c1.y,c1.z,c1.w,
                    c2.x,c2.y,c2.z,c2.w, c3.x,c3.y,c3.z,c3.w};
    if (fastA){
      float r = __expf(-de);
      float ap = 1.f;
      #pragma unroll
      for (int n=0;n<16;n++){
        ap *= r;
        h[n] = ap*h[n] + du*bb[n];
        yv  += h[n]*cc[n];
      }
    } else {
      #pragma unroll
      for (int n=0;n<16;n++){
        float a = __expf(de*A[n]);
        h[n] = a*h[n] + du*bb[n];
        yv  += h[n]*cc[n];
      }
    }
    xs[d*17+l] = yv;
  }
  __syncthreads();
  {
    int px = d & 15, q = d >> 4;   // q in 0..7
    float s=0.f, qq=0.f;
    #pragma unroll
    for (int j=0;j<16;j++){ float v = xs[(q*16+j)*17+px]; s+=v; qq+=v*v; }
    red[q][px][0]=s; red[q][px][1]=qq;
  }
  __syncthreads();
  if (d < 16){
    float ss=0.f, sq=0.f;
    #pragma unroll
    for (int q=0;q<8;q++){ ss += red[q][d][0]; sq += red[q][d][1]; }
    float m = ss*(1.f/128.f);
    mstat[d] = m;
    rstat[d] = rsqrtf(sq*(1.f/128.f) - m*m + 1e-5f);
  }
  __syncthreads();
  float ow = wf[WF_ONW+d], ob = wf[WF_ONB+d];
  const float* zp = z + ((size_t)b*128+d)*NL + l0;
  float* gp = G + ((size_t)b*128+d)*NL + l0;
  #pragma unroll
  for (int l4=0; l4<CHUNK/4; l4++){
    float4 zv4 = ((const float4*)zp)[l4];
    float zv[4] = {zv4.x, zv4.y, zv4.z, zv4.w};
    float out[4];
    #pragma unroll
    for (int j=0;j<4;j++){
      int l = l4*4+j;
      float t = (xs[d*17+l]-mstat[l])*rstat[l]*ow + ob;
      out[j] = t * (zv[j]/(1.f+__expf(-zv[j])));
    }
    ((float4*)gp)[l4] = make_float4(out[0],out[1],out[2],out[3]);
  }
}

// ---------------- K11A: yc = W_comb @ G + cf_b; + stats ----------------
__global__ __launch_bounds__(256, 4) void k11A_proj(const float* __restrict__ G, const float* __restrict__ wf,
                                                    const float* __restrict__ wcomb,
                                                    float* __restrict__ yc, float* __restrict__ part){
  int og = blockIdx.x >> 8, rem = blockIdx.x & 255;
  int b = rem >> 5, pt = rem & 31;
  int jslot = threadIdx.x >> 5, pxslot = threadIdx.x & 31;
  __shared__ float wlds2[128][44];
  __shared__ float xs[32][128];
  {
    const float* Wg = wcomb + og*32*128;
    for (int i = threadIdx.x; i < 4096; i += 256){
      int o = i >> 7, k = i & 127;
      wlds2[k][o] = Wg[i];
    }
  }
  float acc[4][4];
  #pragma unroll
  for (int j=0;j<4;j++)
    #pragma unroll
    for (int p=0;p<4;p++) acc[j][p]=0.f;
  const float* gbase = G + (size_t)b*128*NL + pt*128;
  for (int ch = 0; ch < 4; ch++){
    __syncthreads();
    for (int i = threadIdx.x; i < 1024; i += 256){
      int r = i >> 5, c4 = i & 31;
      ((float4*)&xs[r][0])[c4] = *(const float4*)(gbase + (size_t)(ch*32+r)*NL + c4*4);
    }
    __syncthreads();
    #pragma unroll 1
    for (int c = 0; c < 32; c++){
      float a[4];
      #pragma unroll
      for (int p=0;p<4;p++) a[p] = xs[c][pxslot + 32*p];
      float4 w4 = *(const float4*)&wlds2[ch*32+c][jslot*4];
      float wv[4] = {w4.x, w4.y, w4.z, w4.w};
      #pragma unroll
      for (int jj=0;jj<4;jj++)
        #pragma unroll
        for (int p=0;p<4;p++) acc[jj][p] += wv[jj]*a[p];
    }
  }
  #pragma unroll
  for (int jj=0;jj<4;jj++){
    int cc = og*32 + jslot*4 + jj;
    float bias = wf[WF_CFB + cc];
    float* dp = yc + (size_t)b*64*NL + (size_t)cc*NL + pt*128;
    float sv = 0.f, qv = 0.f;
    #pragma unroll
    for (int p=0;p<4;p++){
      float t = acc[jj][p] + bias;
      dp[pxslot + 32*p] = t;
      sv += t; qv += t*t;
    }
    #pragma unroll
    for (int o=16;o>0;o>>=1){ sv += __shfl_xor(sv,o); qv += __shfl_xor(qv,o); }
    if (pxslot == 0){
      size_t pidx = (((size_t)b*64 + cc)*32 + pt)*2;
      part[pidx] = sv; part[pidx+1] = qv;
    }
  }
}

// ---------------- K11c: out = x1 + inorm(yc) ----------------
__global__ __launch_bounds__(256) void k11c_final(const float* __restrict__ yc, const float* __restrict__ part,
                                                  const float* __restrict__ x1, float* __restrict__ out){
  int bc = blockIdx.x;
  __shared__ float sm, sr;
  if (threadIdx.x == 0){
    float s=0.f, q=0.f;
    #pragma unroll
    for (int t2=0;t2<32;t2++){ s += part[((size_t)bc*32+t2)*2]; q += part[((size_t)bc*32+t2)*2+1]; }
    float m = s*(1.f/NL);
    sm = m; sr = rsqrtf(q*(1.f/NL) - m*m + 1e-5f);
  }
  __syncthreads();
  float m = sm, rs = sr;
  size_t base = (size_t)bc*NL;
  for (int i=threadIdx.x;i<NL;i+=256){
    float v = (yc[base+i]-m)*rs;
    out[base+i] = x1[base+i] + v;
  }
}

// ---------------- host ----------------
extern "C" void kernel_launch(void* const* d_in, const int* in_sizes, int n_in,
                              void* d_out, int out_size, void* d_ws, size_t ws_size,
                              hipStream_t stream) {
  if (ws_size < WS_NEED_FLOATS * sizeof(float)) return;
  const float* x     = (const float*)d_in[0];
  const float* dw3w  = (const float*)d_in[1];
  const float* dw3b  = (const float*)d_in[2];
  const float* dw5w  = (const float*)d_in[3];
  const float* dw5b  = (const float*)d_in[4];
  const float* dw7w  = (const float*)d_in[5];
  const float* dw7b  = (const float*)d_in[6];
  const float* fusew = (const float*)d_in[7];
  const float* fuseb = (const float*)d_in[8];
  const float* inpjw = (const float*)d_in[9];
  const float* c2w   = (const float*)d_in[10];
  const float* c2b   = (const float*)d_in[11];
  const float* xpw   = (const float*)d_in[12];
  const float* dtw   = (const float*)d_in[13];
  const float* dtb   = (const float*)d_in[14];
  const float* alog  = (const float*)d_in[15];
  const float* dpv   = (const float*)d_in[16];
  const float* onw   = (const float*)d_in[17];
  const float* onb   = (const float*)d_in[18];
  const float* opw   = (const float*)d_in[19];
  const float* cfw   = (const float*)d_in[20];
  const float* cfb   = (const float*)d_in[21];

  float* ws    = (float*)d_ws;
  float* wf    = ws + OFF_WF;
  float* wcomb = ws + OFF_WCOMB;
  float* feats = ws + OFF_FEATS;
  float* xf    = ws + OFF_XF;
  float* x1    = ws + OFF_X1;
  float* xmraw = ws + OFF_XMRAW;
  float* z     = ws + OFF_Z;
  float* xmc   = ws + OFF_XMC;
  float* Bmw   = ws + OFF_BMAT;
  float* Cmw   = ws + OFF_CMAT;
  float* dtm   = ws + OFF_DTM;
  float* Acb   = ws + OFF_AC;
  float* Bcb   = ws + OFF_BC;
  float* G     = ws + OFF_G;
  float* yc    = ws + OFF_YC;
  float* part  = ws + OFF_PART;

  CvtArgs ca; int ns = 0;
  auto add = [&](const float* s, int off, int n, int op){
    ca.d[ns].src = s; ca.d[ns].dst = wf + off; ca.d[ns].n = n; ca.d[ns].op = op; ns++;
  };
  add(dw3w, WF_DW3, 576, 0);   add(dw5w, WF_DW5, 1600, 0);  add(dw7w, WF_DW7, 3136, 0);
  add(dw3b, WF_B3, 64, 0);     add(dw5b, WF_B5, 64, 0);     add(dw7b, WF_B7, 64, 0);
  add(fusew, WF_FUSE, 12288, 0); add(fuseb, WF_FUSEB, 64, 0);
  add(c2w, WF_C2W, 1152, 0);   add(c2b, WF_C2B, 128, 0);
  add(xpw, WF_XPW, 4608, 0);   add(dtw, WF_DTW, 512, 0);    add(dtb, WF_DTB, 128, 0);
  add(alog, WF_A, 2048, 1);    // A = -exp(A_log)
  add(dpv, WF_DP, 128, 0);
  add(onw, WF_ONW, 128, 0);    add(onb, WF_ONB, 128, 0);
  add(opw, WF_OPW, 8192, 0);
  add(cfw, WF_CFW, 4096, 0);   add(cfb, WF_CFB, 64, 0);
  add(inpjw, WF_INPJ, 16384, 0);
  ca.ncvt = ns; ca.cfw = cfw; ca.opw = opw; ca.wcomb = wcomb;

  k0_cvt<<<ns + 32, 256, 0, stream>>>(ca);
  k1_dw<<<2048, 256, 0, stream>>>(x, wf, feats, part);
  k2_fuse<<<512, 256, 0, stream>>>(feats, part, wf, xf);
  k3_norm<<<512, 256, 0, stream>>>(xf, x, x1);
  k4_inproj<<<1024, 256, 0, stream>>>(x1, wf, xmraw, z);
  k5_dw3<<<2048, 256, 0, stream>>>(xmraw, wf, xmc);
  k6_xproj<<<256, 256, 0, stream>>>(xmc, wf, Bmw, Cmw, dtm);
  k7_scan1<<<2048, 128, 0, stream>>>(xmc, Bmw, dtm, wf, Acb, Bcb);
  k8_mid<<<128, 128, 0, stream>>>(Acb, Bcb, Acb /*Hi aliases Ac*/);
  k9_scan2<<<2048, 128, 0, stream>>>(xmc, Bmw, Cmw, dtm, z, wf, Acb /*Hi*/, G);
  k11A_proj<<<512, 256, 0, stream>>>(G, wf, wcomb, yc, part);
  k11c_final<<<512, 256, 0, stream>>>(yc, part, x1, (float*)d_out);
}